// Round 2
// baseline (795.878 us; speedup 1.0000x reference)
//
#include <hip/hip_runtime.h>

// ---------- CSR construction ----------

__global__ void k_hist(const int* __restrict__ idx, int* __restrict__ deg, int n) {
  int i = blockIdx.x * blockDim.x + threadIdx.x;
  if (i < n) atomicAdd(&deg[idx[i]], 1);
}

// single-block exclusive scan: rowptr[0]=0, rowptr[i+1]=inclusive sum; cursor = copy
__global__ __launch_bounds__(1024) void k_scan(const int* __restrict__ deg, int* __restrict__ rowptr,
                                               int* __restrict__ cursor, int n) {
  __shared__ int wtot[16];
  const int tid = threadIdx.x;
  const int lane = tid & 63;
  const int w = tid >> 6;
  int carry = 0;
  if (tid == 0) { rowptr[0] = 0; cursor[0] = 0; }
  for (int base = 0; base < n; base += 1024) {
    int i = base + tid;
    int v = (i < n) ? deg[i] : 0;
    int incl = v;
#pragma unroll
    for (int off = 1; off < 64; off <<= 1) {
      int t = __shfl_up(incl, off, 64);
      if (lane >= off) incl += t;
    }
    if (lane == 63) wtot[w] = incl;
    __syncthreads();
    if (w == 0) {
      int tv = (lane < 16) ? wtot[lane] : 0;
#pragma unroll
      for (int off = 1; off < 16; off <<= 1) {
        int t = __shfl_up(tv, off, 64);
        if (lane >= off) tv += t;
      }
      if (lane < 16) wtot[lane] = tv;
    }
    __syncthreads();
    int woff = (w == 0) ? 0 : wtot[w - 1];
    int total = wtot[15];
    int out = carry + woff + incl;
    if (i < n) { rowptr[i + 1] = out; cursor[i + 1] = out; }
    carry += total;
    __syncthreads();
  }
}

__global__ void k_scatter_e(const int* __restrict__ ei, int* __restrict__ cursor,
                            int* __restrict__ col, int E) {
  int i = blockIdx.x * blockDim.x + threadIdx.x;
  if (i < E) {
    int d = ei[E + i];  // dst row
    int s = ei[i];      // src row
    int pos = atomicAdd(&cursor[d], 1);
    col[pos] = s;
  }
}

__global__ void k_scatter_n(const int* __restrict__ cluster, int* __restrict__ cursor,
                            int* __restrict__ col, int N) {
  int i = blockIdx.x * blockDim.x + threadIdx.x;
  if (i < N) {
    int c = cluster[i];
    int pos = atomicAdd(&cursor[c], 1);
    col[pos] = i;
  }
}

// ---------- fused per-node MLP: Linear(CIN->64) -> LN -> ReLU -> Linear(64->CIN) ----------
// thread-per-node; weights streamed through one 16 KB LDS buffer in chunks.
// w1: (CIN,64) row-major. w2: (64,CIN) row-major.
template <int CIN>
__global__ __launch_bounds__(256) void k_mlp(const float* __restrict__ xin,
                                             const float* __restrict__ w1, const float* __restrict__ b1,
                                             const float* __restrict__ g, const float* __restrict__ be,
                                             const float* __restrict__ w2, const float* __restrict__ b2,
                                             float* __restrict__ xout, int N) {
  __shared__ float sW[64 * 64];   // 16 KB chunk buffer
  __shared__ float sv[64 * 3];    // b1 | g | be
  __shared__ float sb2[CIN];
  const int tid = threadIdx.x;
  if (tid < 64) {
    sv[tid]       = b1[tid];
    sv[64 + tid]  = g[tid];
    sv[128 + tid] = be[tid];
  }
  for (int i = tid; i < CIN; i += 256) sb2[i] = b2[i];

  const int node = blockIdx.x * 256 + tid;
  const bool act = node < N;
  const float* xr = xin + (size_t)node * CIN;

  float acc[64];
#pragma unroll
  for (int c = 0; c < 64; c++) acc[c] = 0.f;

  // ---- h = x @ W1, in K-chunks of 64 ----
  for (int k0 = 0; k0 < CIN; k0 += 64) {
    __syncthreads();
    for (int i = tid; i < 64 * 64; i += 256) sW[i] = w1[k0 * 64 + i];
    __syncthreads();
    for (int kk = 0; kk < 64; kk += 8) {
      float xk[8];
#pragma unroll
      for (int q = 0; q < 8; q++) xk[q] = act ? xr[k0 + kk + q] : 0.f;
#pragma unroll
      for (int q = 0; q < 8; q++) {
#pragma unroll
        for (int c = 0; c < 64; c++) acc[c] = fmaf(xk[q], sW[(kk + q) * 64 + c], acc[c]);
      }
    }
  }

  // ---- + b1, LayerNorm(64), ReLU ----
  float mu = 0.f;
#pragma unroll
  for (int c = 0; c < 64; c++) { acc[c] += sv[c]; mu += acc[c]; }
  mu *= (1.f / 64.f);
  float var = 0.f;
#pragma unroll
  for (int c = 0; c < 64; c++) { float d = acc[c] - mu; var = fmaf(d, d, var); }
  var *= (1.f / 64.f);
  float rs = rsqrtf(var + 1e-5f);
#pragma unroll
  for (int c = 0; c < 64; c++) {
    float h = (acc[c] - mu) * rs * sv[64 + c] + sv[128 + c];
    acc[c] = fmaxf(h, 0.f);
  }

  // ---- out = h @ W2 + b2, in output-column chunks of 64 ----
  float* orow = xout + (size_t)node * (2 * CIN);
  for (int j0 = 0; j0 < CIN; j0 += 64) {
    __syncthreads();
    for (int i = tid; i < 64 * 64; i += 256) {
      int c = i >> 6, jj = i & 63;
      sW[i] = w2[c * CIN + j0 + jj];   // sW[c*64+jj] = W2[c, j0+jj]
    }
    __syncthreads();
    for (int jj = 0; jj < 64; jj += 4) {
      float o0 = sb2[j0 + jj], o1 = sb2[j0 + jj + 1], o2 = sb2[j0 + jj + 2], o3 = sb2[j0 + jj + 3];
#pragma unroll
      for (int c = 0; c < 64; c++) {
        float h = acc[c];
        const float* wr = &sW[c * 64 + jj];
        o0 = fmaf(h, wr[0], o0);
        o1 = fmaf(h, wr[1], o1);
        o2 = fmaf(h, wr[2], o2);
        o3 = fmaf(h, wr[3], o3);
      }
      if (act) *reinterpret_cast<float4*>(&orow[j0 + jj]) = make_float4(o0, o1, o2, o3);
    }
  }
}

// ---------- scatter-max as CSR gather-max: wave per dst node ----------
template <int CIN>
__global__ __launch_bounds__(256) void k_agg(float* __restrict__ xb, const int* __restrict__ rowptr,
                                             const int* __restrict__ col, int N) {
  constexpr int CPL = CIN / 64;
  const int wid = (blockIdx.x * blockDim.x + threadIdx.x) >> 6;
  const int lane = threadIdx.x & 63;
  if (wid >= N) return;
  const int beg = rowptr[wid], end = rowptr[wid + 1];
  float v[CPL];
#pragma unroll
  for (int q = 0; q < CPL; q++) v[q] = -INFINITY;
  for (int e = beg; e < end; e++) {
    int s = col[e];
    const float* r = xb + (size_t)s * (2 * CIN) + lane * CPL;
    if constexpr (CPL == 1) {
      v[0] = fmaxf(v[0], r[0]);
    } else if constexpr (CPL == 2) {
      float2 t = *reinterpret_cast<const float2*>(r);
      v[0] = fmaxf(v[0], t.x); v[1] = fmaxf(v[1], t.y);
    } else {
      float4 t = *reinterpret_cast<const float4*>(r);
      v[0] = fmaxf(v[0], t.x); v[1] = fmaxf(v[1], t.y);
      v[2] = fmaxf(v[2], t.z); v[3] = fmaxf(v[3], t.w);
    }
  }
  if (beg == end) {
#pragma unroll
    for (int q = 0; q < CPL; q++) v[q] = 0.f;
  }
  float* o = xb + (size_t)wid * (2 * CIN) + CIN + lane * CPL;
  if constexpr (CPL == 1) {
    o[0] = v[0];
  } else if constexpr (CPL == 2) {
    *reinterpret_cast<float2*>(o) = make_float2(v[0], v[1]);
  } else {
    *reinterpret_cast<float4*>(o) = make_float4(v[0], v[1], v[2], v[3]);
  }
}

// ---------- cluster max-pool: wave per cluster, 512 channels ----------
__global__ __launch_bounds__(256) void k_pool(const float* __restrict__ x3, const int* __restrict__ rowptr,
                                              const int* __restrict__ col, float* __restrict__ pooled, int NC) {
  const int wid = (blockIdx.x * blockDim.x + threadIdx.x) >> 6;
  const int lane = threadIdx.x & 63;
  if (wid >= NC) return;
  const int beg = rowptr[wid], end = rowptr[wid + 1];
  float4 a = make_float4(-INFINITY, -INFINITY, -INFINITY, -INFINITY);
  float4 b = a;
  for (int e = beg; e < end; e++) {
    int n = col[e];
    const float4* r = reinterpret_cast<const float4*>(x3 + (size_t)n * 512 + lane * 8);
    float4 ta = r[0], tb = r[1];
    a.x = fmaxf(a.x, ta.x); a.y = fmaxf(a.y, ta.y); a.z = fmaxf(a.z, ta.z); a.w = fmaxf(a.w, ta.w);
    b.x = fmaxf(b.x, tb.x); b.y = fmaxf(b.y, tb.y); b.z = fmaxf(b.z, tb.z); b.w = fmaxf(b.w, tb.w);
  }
  if (beg == end) { a = make_float4(0, 0, 0, 0); b = a; }
  float4* o = reinterpret_cast<float4*>(pooled + (size_t)wid * 512 + lane * 8);
  o[0] = a; o[1] = b;
}

// ---------- per-column sum of squares ----------
__global__ __launch_bounds__(256) void k_norm(const float* __restrict__ pooled, float* __restrict__ normsq, int NC) {
  const int c0 = threadIdx.x;
  const int c1 = threadIdx.x + 256;
  const int rows = (NC + gridDim.x - 1) / gridDim.x;
  float s0 = 0.f, s1 = 0.f;
  for (int rr = 0; rr < rows; rr++) {
    int r = blockIdx.x * rows + rr;
    if (r < NC) {
      float v0 = pooled[(size_t)r * 512 + c0];
      float v1 = pooled[(size_t)r * 512 + c1];
      s0 = fmaf(v0, v0, s0);
      s1 = fmaf(v1, v1, s1);
    }
  }
  atomicAdd(&normsq[c0], s0);
  atomicAdd(&normsq[c1], s1);
}

__global__ void k_final(const float* __restrict__ pooled, const float* __restrict__ normsq,
                        float* __restrict__ out, int n) {
  int i = blockIdx.x * blockDim.x + threadIdx.x;
  if (i >= n) return;
  int c = i & 511;
  out[i] = pooled[i] * rsqrtf(normsq[c]);
}

// ---------- launch ----------
extern "C" void kernel_launch(void* const* d_in, const int* in_sizes, int n_in,
                              void* d_out, int out_size, void* d_ws, size_t ws_size,
                              hipStream_t stream) {
  const int N = in_sizes[0] / 64;
  const int E = in_sizes[1] / 2;
  const int NC = out_size / 512;

  const float* x0 = (const float*)d_in[0];
  const int* ei = (const int*)d_in[1];
  const int* cluster = (const int*)d_in[2];

  const float* W[18];
  for (int k = 0; k < 18; k++) W[k] = (const float*)d_in[5 + k];

  char* p = (char*)d_ws;
  auto alloc = [&](size_t bytes) -> void* {
    void* r = (void*)p;
    p += (bytes + 255) & ~(size_t)255;
    return r;
  };
  float* x1     = (float*)alloc((size_t)N * 128 * 4);
  float* x2     = (float*)alloc((size_t)N * 256 * 4);
  float* x3     = (float*)alloc((size_t)N * 512 * 4);
  float* pooled = (float*)alloc((size_t)NC * 512 * 4);
  float* normsq = (float*)alloc((size_t)512 * 4);
  int* degE     = (int*)alloc((size_t)N * 4);
  int* rowptrE  = (int*)alloc((size_t)(N + 1) * 4);
  int* cursorE  = (int*)alloc((size_t)(N + 1) * 4);
  int* colE     = (int*)alloc((size_t)E * 4);
  int* degC     = (int*)alloc((size_t)NC * 4);
  int* rowptrC  = (int*)alloc((size_t)(NC + 1) * 4);
  int* cursorC  = (int*)alloc((size_t)(NC + 1) * 4);
  int* colC     = (int*)alloc((size_t)N * 4);

  hipMemsetAsync(degE, 0, (size_t)N * 4, stream);
  hipMemsetAsync(degC, 0, (size_t)NC * 4, stream);
  hipMemsetAsync(normsq, 0, (size_t)512 * 4, stream);

  // edge CSR (grouped by dst)
  k_hist<<<(E + 255) / 256, 256, 0, stream>>>(ei + E, degE, E);
  k_scan<<<1, 1024, 0, stream>>>(degE, rowptrE, cursorE, N);
  k_scatter_e<<<(E + 255) / 256, 256, 0, stream>>>(ei, cursorE, colE, E);

  // cluster CSR
  k_hist<<<(N + 255) / 256, 256, 0, stream>>>(cluster, degC, N);
  k_scan<<<1, 1024, 0, stream>>>(degC, rowptrC, cursorC, NC);
  k_scatter_n<<<(N + 255) / 256, 256, 0, stream>>>(cluster, cursorC, colC, N);

  // layer 0: cin=64
  k_mlp<64><<<(N + 255) / 256, 256, 0, stream>>>(x0, W[0], W[1], W[2], W[3], W[4], W[5], x1, N);
  k_agg<64><<<(N * 64 + 255) / 256, 256, 0, stream>>>(x1, rowptrE, colE, N);
  // layer 1: cin=128
  k_mlp<128><<<(N + 255) / 256, 256, 0, stream>>>(x1, W[6], W[7], W[8], W[9], W[10], W[11], x2, N);
  k_agg<128><<<(N * 64 + 255) / 256, 256, 0, stream>>>(x2, rowptrE, colE, N);
  // layer 2: cin=256
  k_mlp<256><<<(N + 255) / 256, 256, 0, stream>>>(x2, W[12], W[13], W[14], W[15], W[16], W[17], x3, N);
  k_agg<256><<<(N * 64 + 255) / 256, 256, 0, stream>>>(x3, rowptrE, colE, N);

  // cluster max-pool + column L2 normalize
  k_pool<<<(NC * 64 + 255) / 256, 256, 0, stream>>>(x3, rowptrC, colC, pooled, NC);
  k_norm<<<128, 256, 0, stream>>>(pooled, normsq, NC);
  k_final<<<(NC * 512 + 255) / 256, 256, 0, stream>>>(pooled, normsq, (float*)d_out, NC * 512);
}

// Round 3
// 662.366 us; speedup vs baseline: 1.2016x; 1.2016x over previous
//
#include <hip/hip_runtime.h>

// ---------- CSR construction ----------

__global__ void k_hist(const int* __restrict__ idx, int* __restrict__ deg, int n) {
  int i = blockIdx.x * blockDim.x + threadIdx.x;
  if (i < n) atomicAdd(&deg[idx[i]], 1);
}

// single-block exclusive scan: rowptr[0]=0, rowptr[i+1]=inclusive sum; cursor = copy
__global__ __launch_bounds__(1024) void k_scan(const int* __restrict__ deg, int* __restrict__ rowptr,
                                               int* __restrict__ cursor, int n) {
  __shared__ int wtot[16];
  const int tid = threadIdx.x;
  const int lane = tid & 63;
  const int w = tid >> 6;
  int carry = 0;
  if (tid == 0) { rowptr[0] = 0; cursor[0] = 0; }
  for (int base = 0; base < n; base += 1024) {
    int i = base + tid;
    int v = (i < n) ? deg[i] : 0;
    int incl = v;
#pragma unroll
    for (int off = 1; off < 64; off <<= 1) {
      int t = __shfl_up(incl, off, 64);
      if (lane >= off) incl += t;
    }
    if (lane == 63) wtot[w] = incl;
    __syncthreads();
    if (w == 0) {
      int tv = (lane < 16) ? wtot[lane] : 0;
#pragma unroll
      for (int off = 1; off < 16; off <<= 1) {
        int t = __shfl_up(tv, off, 64);
        if (lane >= off) tv += t;
      }
      if (lane < 16) wtot[lane] = tv;
    }
    __syncthreads();
    int woff = (w == 0) ? 0 : wtot[w - 1];
    int total = wtot[15];
    int out = carry + woff + incl;
    if (i < n) { rowptr[i + 1] = out; cursor[i + 1] = out; }
    carry += total;
    __syncthreads();
  }
}

__global__ void k_scatter_e(const int* __restrict__ ei, int* __restrict__ cursor,
                            int* __restrict__ col, int E) {
  int i = blockIdx.x * blockDim.x + threadIdx.x;
  if (i < E) {
    int d = ei[E + i];  // dst row
    int s = ei[i];      // src row
    int pos = atomicAdd(&cursor[d], 1);
    col[pos] = s;
  }
}

__global__ void k_scatter_n(const int* __restrict__ cluster, int* __restrict__ cursor,
                            int* __restrict__ col, int N) {
  int i = blockIdx.x * blockDim.x + threadIdx.x;
  if (i < N) {
    int c = cluster[i];
    int pos = atomicAdd(&cursor[c], 1);
    col[pos] = i;
  }
}

// ---------- fused per-64-node-tile MLP: Linear(CIN->64) -> LN -> ReLU -> Linear(64->CIN) ----
// Register-tiled GEMM: block = 64 nodes, 256 threads, thread tile = 4 nodes x 4 channels.
// tn = tid>>4 (node group), tc = tid&15 (channel group) -> LN's 16 channel-owners of a
// node are contiguous lanes within one wave (shfl_xor reduction).
// w1: (CIN,64) row-major. w2: (64,CIN) row-major.
template <int CIN>
__global__ __launch_bounds__(256) void k_mlp(const float* __restrict__ xin,
                                             const float* __restrict__ w1, const float* __restrict__ b1,
                                             const float* __restrict__ g, const float* __restrict__ be,
                                             const float* __restrict__ w2, const float* __restrict__ b2,
                                             float* __restrict__ xout, int N) {
  __shared__ float sX[64 * 64];  // phase1: X^T chunk [k][n]; phase2: H^T [c][n]
  __shared__ float sW[64 * 64];  // weight chunk

  const int tid = threadIdx.x;
  const int tn = tid >> 4;   // 0..15
  const int tc = tid & 15;   // 0..15
  const int nb = blockIdx.x * 64;

  float acc[4][4];
#pragma unroll
  for (int i = 0; i < 4; i++)
#pragma unroll
    for (int j = 0; j < 4; j++) acc[i][j] = 0.f;

  // loader assignment: thread covers node ln, k-range [lk, lk+16)
  const int ln = tid >> 2;
  const int lk = (tid & 3) * 16;
  int gn = nb + ln;
  if (gn >= N) gn = N - 1;  // clamp: duplicate row, results masked on store
  const float* xrow = xin + (size_t)gn * CIN;

  // ---- phase 1: H = X @ W1 ----
  for (int k0 = 0; k0 < CIN; k0 += 64) {
    __syncthreads();
    // stage W1 chunk (contiguous 64x64)
    {
      const float4* src = reinterpret_cast<const float4*>(w1 + (size_t)k0 * 64);
      float4* dst = reinterpret_cast<float4*>(sW);
#pragma unroll
      for (int r = 0; r < 4; r++) dst[tid + r * 256] = src[tid + r * 256];
    }
    // stage X chunk transposed: sX[k][n] = x[nb+n][k0+k]
    {
      float4 v[4];
      const float4* src = reinterpret_cast<const float4*>(xrow + k0 + lk);
#pragma unroll
      for (int f = 0; f < 4; f++) v[f] = src[f];
#pragma unroll
      for (int f = 0; f < 4; f++) {
#pragma unroll
        for (int q = 0; q < 4; q++) sX[(lk + f * 4 + q) * 64 + ln] = (&v[f].x)[q];
      }
    }
    __syncthreads();
#pragma unroll 8
    for (int k = 0; k < 64; k++) {
      float4 xv = *reinterpret_cast<const float4*>(&sX[k * 64 + tn * 4]);
      float4 wv = *reinterpret_cast<const float4*>(&sW[k * 64 + tc * 4]);
#pragma unroll
      for (int i = 0; i < 4; i++) {
        float x = (&xv.x)[i];
        acc[i][0] = fmaf(x, wv.x, acc[i][0]);
        acc[i][1] = fmaf(x, wv.y, acc[i][1]);
        acc[i][2] = fmaf(x, wv.z, acc[i][2]);
        acc[i][3] = fmaf(x, wv.w, acc[i][3]);
      }
    }
  }

  // ---- + b1, LayerNorm(64), *g + be, ReLU ----
  {
    float4 bv = *reinterpret_cast<const float4*>(b1 + tc * 4);
#pragma unroll
    for (int i = 0; i < 4; i++)
#pragma unroll
      for (int j = 0; j < 4; j++) acc[i][j] += (&bv.x)[j];

    float s[4];
#pragma unroll
    for (int i = 0; i < 4; i++) s[i] = acc[i][0] + acc[i][1] + acc[i][2] + acc[i][3];
#pragma unroll
    for (int m = 1; m < 16; m <<= 1) {
#pragma unroll
      for (int i = 0; i < 4; i++) s[i] += __shfl_xor(s[i], m, 64);
    }
    float mu[4];
#pragma unroll
    for (int i = 0; i < 4; i++) mu[i] = s[i] * (1.f / 64.f);

    float t[4];
#pragma unroll
    for (int i = 0; i < 4; i++) {
      float d0 = acc[i][0] - mu[i], d1 = acc[i][1] - mu[i];
      float d2 = acc[i][2] - mu[i], d3 = acc[i][3] - mu[i];
      t[i] = d0 * d0 + d1 * d1 + d2 * d2 + d3 * d3;
    }
#pragma unroll
    for (int m = 1; m < 16; m <<= 1) {
#pragma unroll
      for (int i = 0; i < 4; i++) t[i] += __shfl_xor(t[i], m, 64);
    }
    float rs[4];
#pragma unroll
    for (int i = 0; i < 4; i++) rs[i] = rsqrtf(t[i] * (1.f / 64.f) + 1e-5f);

    float4 gv = *reinterpret_cast<const float4*>(g + tc * 4);
    float4 bev = *reinterpret_cast<const float4*>(be + tc * 4);
#pragma unroll
    for (int i = 0; i < 4; i++)
#pragma unroll
      for (int j = 0; j < 4; j++) {
        float h = (acc[i][j] - mu[i]) * rs[i] * (&gv.x)[j] + (&bev.x)[j];
        acc[i][j] = fmaxf(h, 0.f);
      }
  }

  // ---- write H^T to LDS: sX[c][n], b128 per j (4 consecutive nodes) ----
  __syncthreads();
#pragma unroll
  for (int j = 0; j < 4; j++) {
    float4 hv = make_float4(acc[0][j], acc[1][j], acc[2][j], acc[3][j]);
    *reinterpret_cast<float4*>(&sX[(tc * 4 + j) * 64 + tn * 4]) = hv;
  }

  // ---- phase 2: OUT = H @ W2 + b2, j-chunks of 64 ----
  for (int j0 = 0; j0 < CIN; j0 += 64) {
    __syncthreads();
    // stage W2 chunk: sW[c][jj] = w2[c*CIN + j0+jj]
    {
      const int c = tid >> 2;
      const int jj = (tid & 3) * 16;
      const float4* src = reinterpret_cast<const float4*>(w2 + (size_t)c * CIN + j0 + jj);
      float4* dst = reinterpret_cast<float4*>(&sW[c * 64 + jj]);
#pragma unroll
      for (int f = 0; f < 4; f++) dst[f] = src[f];
    }
    __syncthreads();

    float o[4][4];
    float4 b2v = *reinterpret_cast<const float4*>(b2 + j0 + tc * 4);
#pragma unroll
    for (int i = 0; i < 4; i++)
#pragma unroll
      for (int j = 0; j < 4; j++) o[i][j] = (&b2v.x)[j];

#pragma unroll 8
    for (int c = 0; c < 64; c++) {
      float4 hv = *reinterpret_cast<const float4*>(&sX[c * 64 + tn * 4]);
      float4 wv = *reinterpret_cast<const float4*>(&sW[c * 64 + tc * 4]);
#pragma unroll
      for (int i = 0; i < 4; i++) {
        float h = (&hv.x)[i];
        o[i][0] = fmaf(h, wv.x, o[i][0]);
        o[i][1] = fmaf(h, wv.y, o[i][1]);
        o[i][2] = fmaf(h, wv.z, o[i][2]);
        o[i][3] = fmaf(h, wv.w, o[i][3]);
      }
    }
#pragma unroll
    for (int i = 0; i < 4; i++) {
      int n = nb + tn * 4 + i;
      if (n < N) {
        *reinterpret_cast<float4*>(&xout[(size_t)n * (2 * CIN) + j0 + tc * 4]) =
            make_float4(o[i][0], o[i][1], o[i][2], o[i][3]);
      }
    }
  }
}

// ---------- scatter-max as CSR gather-max: wave per dst node ----------
template <int CIN>
__global__ __launch_bounds__(256) void k_agg(float* __restrict__ xb, const int* __restrict__ rowptr,
                                             const int* __restrict__ col, int N) {
  constexpr int CPL = CIN / 64;
  const int wid = (blockIdx.x * blockDim.x + threadIdx.x) >> 6;
  const int lane = threadIdx.x & 63;
  if (wid >= N) return;
  const int beg = rowptr[wid], end = rowptr[wid + 1];
  float v[CPL];
#pragma unroll
  for (int q = 0; q < CPL; q++) v[q] = -INFINITY;
  for (int e = beg; e < end; e++) {
    int s = col[e];
    const float* r = xb + (size_t)s * (2 * CIN) + lane * CPL;
    if constexpr (CPL == 1) {
      v[0] = fmaxf(v[0], r[0]);
    } else if constexpr (CPL == 2) {
      float2 t = *reinterpret_cast<const float2*>(r);
      v[0] = fmaxf(v[0], t.x); v[1] = fmaxf(v[1], t.y);
    } else {
      float4 t = *reinterpret_cast<const float4*>(r);
      v[0] = fmaxf(v[0], t.x); v[1] = fmaxf(v[1], t.y);
      v[2] = fmaxf(v[2], t.z); v[3] = fmaxf(v[3], t.w);
    }
  }
  if (beg == end) {
#pragma unroll
    for (int q = 0; q < CPL; q++) v[q] = 0.f;
  }
  float* o = xb + (size_t)wid * (2 * CIN) + CIN + lane * CPL;
  if constexpr (CPL == 1) {
    o[0] = v[0];
  } else if constexpr (CPL == 2) {
    *reinterpret_cast<float2*>(o) = make_float2(v[0], v[1]);
  } else {
    *reinterpret_cast<float4*>(o) = make_float4(v[0], v[1], v[2], v[3]);
  }
}

// ---------- cluster max-pool: wave per cluster, 512 channels ----------
__global__ __launch_bounds__(256) void k_pool(const float* __restrict__ x3, const int* __restrict__ rowptr,
                                              const int* __restrict__ col, float* __restrict__ pooled, int NC) {
  const int wid = (blockIdx.x * blockDim.x + threadIdx.x) >> 6;
  const int lane = threadIdx.x & 63;
  if (wid >= NC) return;
  const int beg = rowptr[wid], end = rowptr[wid + 1];
  float4 a = make_float4(-INFINITY, -INFINITY, -INFINITY, -INFINITY);
  float4 b = a;
  for (int e = beg; e < end; e++) {
    int n = col[e];
    const float4* r = reinterpret_cast<const float4*>(x3 + (size_t)n * 512 + lane * 8);
    float4 ta = r[0], tb = r[1];
    a.x = fmaxf(a.x, ta.x); a.y = fmaxf(a.y, ta.y); a.z = fmaxf(a.z, ta.z); a.w = fmaxf(a.w, ta.w);
    b.x = fmaxf(b.x, tb.x); b.y = fmaxf(b.y, tb.y); b.z = fmaxf(b.z, tb.z); b.w = fmaxf(b.w, tb.w);
  }
  if (beg == end) { a = make_float4(0, 0, 0, 0); b = a; }
  float4* o = reinterpret_cast<float4*>(pooled + (size_t)wid * 512 + lane * 8);
  o[0] = a; o[1] = b;
}

// ---------- per-column sum of squares ----------
__global__ __launch_bounds__(256) void k_norm(const float* __restrict__ pooled, float* __restrict__ normsq, int NC) {
  const int c0 = threadIdx.x;
  const int c1 = threadIdx.x + 256;
  const int rows = (NC + gridDim.x - 1) / gridDim.x;
  float s0 = 0.f, s1 = 0.f;
  for (int rr = 0; rr < rows; rr++) {
    int r = blockIdx.x * rows + rr;
    if (r < NC) {
      float v0 = pooled[(size_t)r * 512 + c0];
      float v1 = pooled[(size_t)r * 512 + c1];
      s0 = fmaf(v0, v0, s0);
      s1 = fmaf(v1, v1, s1);
    }
  }
  atomicAdd(&normsq[c0], s0);
  atomicAdd(&normsq[c1], s1);
}

__global__ void k_final(const float* __restrict__ pooled, const float* __restrict__ normsq,
                        float* __restrict__ out, int n) {
  int i = blockIdx.x * blockDim.x + threadIdx.x;
  if (i >= n) return;
  int c = i & 511;
  out[i] = pooled[i] * rsqrtf(normsq[c]);
}

// ---------- launch ----------
extern "C" void kernel_launch(void* const* d_in, const int* in_sizes, int n_in,
                              void* d_out, int out_size, void* d_ws, size_t ws_size,
                              hipStream_t stream) {
  const int N = in_sizes[0] / 64;
  const int E = in_sizes[1] / 2;
  const int NC = out_size / 512;

  const float* x0 = (const float*)d_in[0];
  const int* ei = (const int*)d_in[1];
  const int* cluster = (const int*)d_in[2];

  const float* W[18];
  for (int k = 0; k < 18; k++) W[k] = (const float*)d_in[5 + k];

  char* p = (char*)d_ws;
  auto alloc = [&](size_t bytes) -> void* {
    void* r = (void*)p;
    p += (bytes + 255) & ~(size_t)255;
    return r;
  };
  float* x1     = (float*)alloc((size_t)N * 128 * 4);
  float* x2     = (float*)alloc((size_t)N * 256 * 4);
  float* x3     = (float*)alloc((size_t)N * 512 * 4);
  float* pooled = (float*)alloc((size_t)NC * 512 * 4);
  float* normsq = (float*)alloc((size_t)512 * 4);
  int* degE     = (int*)alloc((size_t)N * 4);
  int* rowptrE  = (int*)alloc((size_t)(N + 1) * 4);
  int* cursorE  = (int*)alloc((size_t)(N + 1) * 4);
  int* colE     = (int*)alloc((size_t)E * 4);
  int* degC     = (int*)alloc((size_t)NC * 4);
  int* rowptrC  = (int*)alloc((size_t)(NC + 1) * 4);
  int* cursorC  = (int*)alloc((size_t)(NC + 1) * 4);
  int* colC     = (int*)alloc((size_t)N * 4);

  hipMemsetAsync(degE, 0, (size_t)N * 4, stream);
  hipMemsetAsync(degC, 0, (size_t)NC * 4, stream);
  hipMemsetAsync(normsq, 0, (size_t)512 * 4, stream);

  // edge CSR (grouped by dst)
  k_hist<<<(E + 255) / 256, 256, 0, stream>>>(ei + E, degE, E);
  k_scan<<<1, 1024, 0, stream>>>(degE, rowptrE, cursorE, N);
  k_scatter_e<<<(E + 255) / 256, 256, 0, stream>>>(ei, cursorE, colE, E);

  // cluster CSR
  k_hist<<<(N + 255) / 256, 256, 0, stream>>>(cluster, degC, N);
  k_scan<<<1, 1024, 0, stream>>>(degC, rowptrC, cursorC, NC);
  k_scatter_n<<<(N + 255) / 256, 256, 0, stream>>>(cluster, cursorC, colC, N);

  const int nblk = (N + 63) / 64;
  // layer 0: cin=64
  k_mlp<64><<<nblk, 256, 0, stream>>>(x0, W[0], W[1], W[2], W[3], W[4], W[5], x1, N);
  k_agg<64><<<(N * 64 + 255) / 256, 256, 0, stream>>>(x1, rowptrE, colE, N);
  // layer 1: cin=128
  k_mlp<128><<<nblk, 256, 0, stream>>>(x1, W[6], W[7], W[8], W[9], W[10], W[11], x2, N);
  k_agg<128><<<(N * 64 + 255) / 256, 256, 0, stream>>>(x2, rowptrE, colE, N);
  // layer 2: cin=256
  k_mlp<256><<<nblk, 256, 0, stream>>>(x2, W[12], W[13], W[14], W[15], W[16], W[17], x3, N);
  k_agg<256><<<(N * 64 + 255) / 256, 256, 0, stream>>>(x3, rowptrE, colE, N);

  // cluster max-pool + column L2 normalize
  k_pool<<<(NC * 64 + 255) / 256, 256, 0, stream>>>(x3, rowptrC, colC, pooled, NC);
  k_norm<<<128, 256, 0, stream>>>(pooled, normsq, NC);
  k_final<<<(NC * 512 + 255) / 256, 256, 0, stream>>>(pooled, normsq, (float*)d_out, NC * 512);
}

// Round 4
// 628.422 us; speedup vs baseline: 1.2665x; 1.0540x over previous
//
#include <hip/hip_runtime.h>
#include <hip/hip_fp16.h>

typedef unsigned short ushort_t;
typedef unsigned int uint_t;

__device__ __forceinline__ float2 h2f2(uint_t u) {
  __half2 h = *reinterpret_cast<__half2*>(&u);
  return __half22float2(h);
}
__device__ __forceinline__ uint_t f2h2(float a, float b) {
  __half2 h = __floats2half2_rn(a, b);
  return *reinterpret_cast<uint_t*>(&h);
}
__device__ __forceinline__ float h2f1(ushort_t u) {
  __half h = *reinterpret_cast<__half*>(&u);
  return __half2float(h);
}
__device__ __forceinline__ ushort_t f2h1(float f) {
  __half h = __float2half_rn(f);
  return *reinterpret_cast<ushort_t*>(&h);
}

// ---------- CSR construction ----------

__global__ void k_hist(const int* __restrict__ idx, int* __restrict__ deg, int n) {
  int i = blockIdx.x * blockDim.x + threadIdx.x;
  if (i < n) atomicAdd(&deg[idx[i]], 1);
}

__global__ __launch_bounds__(1024) void k_scan(const int* __restrict__ deg, int* __restrict__ rowptr,
                                               int* __restrict__ cursor, int n) {
  __shared__ int wtot[16];
  const int tid = threadIdx.x;
  const int lane = tid & 63;
  const int w = tid >> 6;
  int carry = 0;
  if (tid == 0) { rowptr[0] = 0; cursor[0] = 0; }
  for (int base = 0; base < n; base += 1024) {
    int i = base + tid;
    int v = (i < n) ? deg[i] : 0;
    int incl = v;
#pragma unroll
    for (int off = 1; off < 64; off <<= 1) {
      int t = __shfl_up(incl, off, 64);
      if (lane >= off) incl += t;
    }
    if (lane == 63) wtot[w] = incl;
    __syncthreads();
    if (w == 0) {
      int tv = (lane < 16) ? wtot[lane] : 0;
#pragma unroll
      for (int off = 1; off < 16; off <<= 1) {
        int t = __shfl_up(tv, off, 64);
        if (lane >= off) tv += t;
      }
      if (lane < 16) wtot[lane] = tv;
    }
    __syncthreads();
    int woff = (w == 0) ? 0 : wtot[w - 1];
    int total = wtot[15];
    int out = carry + woff + incl;
    if (i < n) { rowptr[i + 1] = out; cursor[i + 1] = out; }
    carry += total;
    __syncthreads();
  }
}

__global__ void k_scatter_e(const int* __restrict__ ei, int* __restrict__ cursor,
                            int* __restrict__ col, int E) {
  int i = blockIdx.x * blockDim.x + threadIdx.x;
  if (i < E) {
    int d = ei[E + i];
    int s = ei[i];
    int pos = atomicAdd(&cursor[d], 1);
    col[pos] = s;
  }
}

__global__ void k_scatter_n(const int* __restrict__ cluster, int* __restrict__ cursor,
                            int* __restrict__ col, int N) {
  int i = blockIdx.x * blockDim.x + threadIdx.x;
  if (i < N) {
    int c = cluster[i];
    int pos = atomicAdd(&cursor[c], 1);
    col[pos] = i;
  }
}

// ---------- fused per-64-node-tile MLP (fp32 math, f16 storage out) ----------
// block = 64 nodes, 256 threads, thread tile = 4 nodes x 4 channels.
// TIN = float (layer 0 input) or ushort_t (f16 intermediate input).
template <int CIN, typename TIN>
__global__ __launch_bounds__(256) void k_mlp(const TIN* __restrict__ xin,
                                             const float* __restrict__ w1, const float* __restrict__ b1,
                                             const float* __restrict__ g, const float* __restrict__ be,
                                             const float* __restrict__ w2, const float* __restrict__ b2,
                                             ushort_t* __restrict__ xout, int N) {
  __shared__ float sX[64 * 64];  // phase1: X^T chunk [k][n]; phase2: H^T [c][n]
  __shared__ float sW[64 * 64];

  const int tid = threadIdx.x;
  const int tn = tid >> 4;
  const int tc = tid & 15;
  const int nb = blockIdx.x * 64;

  float acc[4][4];
#pragma unroll
  for (int i = 0; i < 4; i++)
#pragma unroll
    for (int j = 0; j < 4; j++) acc[i][j] = 0.f;

  const int ln = tid >> 2;
  const int lk = (tid & 3) * 16;
  int gn = nb + ln;
  if (gn >= N) gn = N - 1;
  const TIN* xrow = xin + (size_t)gn * CIN;

  // ---- phase 1: H = X @ W1 ----
  for (int k0 = 0; k0 < CIN; k0 += 64) {
    __syncthreads();
    {
      const float4* src = reinterpret_cast<const float4*>(w1 + (size_t)k0 * 64);
      float4* dst = reinterpret_cast<float4*>(sW);
#pragma unroll
      for (int r = 0; r < 4; r++) dst[tid + r * 256] = src[tid + r * 256];
    }
    if constexpr (sizeof(TIN) == 4) {
      float4 v[4];
      const float4* src = reinterpret_cast<const float4*>(xrow + k0 + lk);
#pragma unroll
      for (int f = 0; f < 4; f++) v[f] = src[f];
#pragma unroll
      for (int f = 0; f < 4; f++) {
#pragma unroll
        for (int q = 0; q < 4; q++) sX[(lk + f * 4 + q) * 64 + ln] = (&v[f].x)[q];
      }
    } else {
      uint4 a = *reinterpret_cast<const uint4*>(xrow + k0 + lk);
      uint4 b = *reinterpret_cast<const uint4*>(xrow + k0 + lk + 8);
      uint_t ua[8] = {a.x, a.y, a.z, a.w, b.x, b.y, b.z, b.w};
#pragma unroll
      for (int q = 0; q < 8; q++) {
        float2 f = h2f2(ua[q]);
        sX[(lk + 2 * q) * 64 + ln] = f.x;
        sX[(lk + 2 * q + 1) * 64 + ln] = f.y;
      }
    }
    __syncthreads();
#pragma unroll 8
    for (int k = 0; k < 64; k++) {
      float4 xv = *reinterpret_cast<const float4*>(&sX[k * 64 + tn * 4]);
      float4 wv = *reinterpret_cast<const float4*>(&sW[k * 64 + tc * 4]);
#pragma unroll
      for (int i = 0; i < 4; i++) {
        float x = (&xv.x)[i];
        acc[i][0] = fmaf(x, wv.x, acc[i][0]);
        acc[i][1] = fmaf(x, wv.y, acc[i][1]);
        acc[i][2] = fmaf(x, wv.z, acc[i][2]);
        acc[i][3] = fmaf(x, wv.w, acc[i][3]);
      }
    }
  }

  // ---- + b1, LayerNorm(64), *g + be, ReLU ----
  {
    float4 bv = *reinterpret_cast<const float4*>(b1 + tc * 4);
#pragma unroll
    for (int i = 0; i < 4; i++)
#pragma unroll
      for (int j = 0; j < 4; j++) acc[i][j] += (&bv.x)[j];

    float s[4];
#pragma unroll
    for (int i = 0; i < 4; i++) s[i] = acc[i][0] + acc[i][1] + acc[i][2] + acc[i][3];
#pragma unroll
    for (int m = 1; m < 16; m <<= 1) {
#pragma unroll
      for (int i = 0; i < 4; i++) s[i] += __shfl_xor(s[i], m, 64);
    }
    float mu[4];
#pragma unroll
    for (int i = 0; i < 4; i++) mu[i] = s[i] * (1.f / 64.f);

    float t[4];
#pragma unroll
    for (int i = 0; i < 4; i++) {
      float d0 = acc[i][0] - mu[i], d1 = acc[i][1] - mu[i];
      float d2 = acc[i][2] - mu[i], d3 = acc[i][3] - mu[i];
      t[i] = d0 * d0 + d1 * d1 + d2 * d2 + d3 * d3;
    }
#pragma unroll
    for (int m = 1; m < 16; m <<= 1) {
#pragma unroll
      for (int i = 0; i < 4; i++) t[i] += __shfl_xor(t[i], m, 64);
    }
    float rs[4];
#pragma unroll
    for (int i = 0; i < 4; i++) rs[i] = rsqrtf(t[i] * (1.f / 64.f) + 1e-5f);

    float4 gv = *reinterpret_cast<const float4*>(g + tc * 4);
    float4 bev = *reinterpret_cast<const float4*>(be + tc * 4);
#pragma unroll
    for (int i = 0; i < 4; i++)
#pragma unroll
      for (int j = 0; j < 4; j++) {
        float h = (acc[i][j] - mu[i]) * rs[i] * (&gv.x)[j] + (&bev.x)[j];
        acc[i][j] = fmaxf(h, 0.f);
      }
  }

  // ---- write H^T to LDS ----
  __syncthreads();
#pragma unroll
  for (int j = 0; j < 4; j++) {
    float4 hv = make_float4(acc[0][j], acc[1][j], acc[2][j], acc[3][j]);
    *reinterpret_cast<float4*>(&sX[(tc * 4 + j) * 64 + tn * 4]) = hv;
  }

  // ---- phase 2: OUT = H @ W2 + b2 ----
  for (int j0 = 0; j0 < CIN; j0 += 64) {
    __syncthreads();
    {
      const int c = tid >> 2;
      const int jj = (tid & 3) * 16;
      const float4* src = reinterpret_cast<const float4*>(w2 + (size_t)c * CIN + j0 + jj);
      float4* dst = reinterpret_cast<float4*>(&sW[c * 64 + jj]);
#pragma unroll
      for (int f = 0; f < 4; f++) dst[f] = src[f];
    }
    __syncthreads();

    float o[4][4];
    float4 b2v = *reinterpret_cast<const float4*>(b2 + j0 + tc * 4);
#pragma unroll
    for (int i = 0; i < 4; i++)
#pragma unroll
      for (int j = 0; j < 4; j++) o[i][j] = (&b2v.x)[j];

#pragma unroll 8
    for (int c = 0; c < 64; c++) {
      float4 hv = *reinterpret_cast<const float4*>(&sX[c * 64 + tn * 4]);
      float4 wv = *reinterpret_cast<const float4*>(&sW[c * 64 + tc * 4]);
#pragma unroll
      for (int i = 0; i < 4; i++) {
        float h = (&hv.x)[i];
        o[i][0] = fmaf(h, wv.x, o[i][0]);
        o[i][1] = fmaf(h, wv.y, o[i][1]);
        o[i][2] = fmaf(h, wv.z, o[i][2]);
        o[i][3] = fmaf(h, wv.w, o[i][3]);
      }
    }
#pragma unroll
    for (int i = 0; i < 4; i++) {
      int n = nb + tn * 4 + i;
      if (n < N) {
        uint2 pk = make_uint2(f2h2(o[i][0], o[i][1]), f2h2(o[i][2], o[i][3]));
        *reinterpret_cast<uint2*>(&xout[(size_t)n * (2 * CIN) + j0 + tc * 4]) = pk;
      }
    }
  }
}

// ---------- scatter-max as CSR gather-max on f16 rows: wave per dst node ----------
// max is monotone => max over f16-rounded values == f16(true max); result f16-exact.
template <int CIN>
__global__ __launch_bounds__(256) void k_agg(ushort_t* __restrict__ xb, const int* __restrict__ rowptr,
                                             const int* __restrict__ col, int N) {
  constexpr int CPL = CIN / 64;  // f16 elems per lane
  const int wid = (blockIdx.x * blockDim.x + threadIdx.x) >> 6;
  const int lane = threadIdx.x & 63;
  if (wid >= N) return;
  const int beg = rowptr[wid], end = rowptr[wid + 1];
  float v[CPL];
#pragma unroll
  for (int q = 0; q < CPL; q++) v[q] = -INFINITY;
  for (int e = beg; e < end; e++) {
    int s = col[e];
    const ushort_t* r = xb + (size_t)s * (2 * CIN) + lane * CPL;
    if constexpr (CPL == 1) {
      v[0] = fmaxf(v[0], h2f1(r[0]));
    } else if constexpr (CPL == 2) {
      float2 f = h2f2(*reinterpret_cast<const uint_t*>(r));
      v[0] = fmaxf(v[0], f.x); v[1] = fmaxf(v[1], f.y);
    } else {
      uint2 u = *reinterpret_cast<const uint2*>(r);
      float2 f0 = h2f2(u.x), f1 = h2f2(u.y);
      v[0] = fmaxf(v[0], f0.x); v[1] = fmaxf(v[1], f0.y);
      v[2] = fmaxf(v[2], f1.x); v[3] = fmaxf(v[3], f1.y);
    }
  }
  if (beg == end) {
#pragma unroll
    for (int q = 0; q < CPL; q++) v[q] = 0.f;
  }
  ushort_t* o = xb + (size_t)wid * (2 * CIN) + CIN + lane * CPL;
  if constexpr (CPL == 1) {
    o[0] = f2h1(v[0]);
  } else if constexpr (CPL == 2) {
    *reinterpret_cast<uint_t*>(o) = f2h2(v[0], v[1]);
  } else {
    *reinterpret_cast<uint2*>(o) = make_uint2(f2h2(v[0], v[1]), f2h2(v[2], v[3]));
  }
}

// ---------- cluster max-pool: wave per cluster, 512 f16 channels ----------
__global__ __launch_bounds__(256) void k_pool(const ushort_t* __restrict__ x3, const int* __restrict__ rowptr,
                                              const int* __restrict__ col, float* __restrict__ pooled, int NC) {
  const int wid = (blockIdx.x * blockDim.x + threadIdx.x) >> 6;
  const int lane = threadIdx.x & 63;
  if (wid >= NC) return;
  const int beg = rowptr[wid], end = rowptr[wid + 1];
  float v[8];
#pragma unroll
  for (int q = 0; q < 8; q++) v[q] = -INFINITY;
  for (int e = beg; e < end; e++) {
    int n = col[e];
    uint4 u = *reinterpret_cast<const uint4*>(x3 + (size_t)n * 512 + lane * 8);
    float2 f0 = h2f2(u.x), f1 = h2f2(u.y), f2 = h2f2(u.z), f3 = h2f2(u.w);
    v[0] = fmaxf(v[0], f0.x); v[1] = fmaxf(v[1], f0.y);
    v[2] = fmaxf(v[2], f1.x); v[3] = fmaxf(v[3], f1.y);
    v[4] = fmaxf(v[4], f2.x); v[5] = fmaxf(v[5], f2.y);
    v[6] = fmaxf(v[6], f3.x); v[7] = fmaxf(v[7], f3.y);
  }
  if (beg == end) {
#pragma unroll
    for (int q = 0; q < 8; q++) v[q] = 0.f;
  }
  float4* o = reinterpret_cast<float4*>(pooled + (size_t)wid * 512 + lane * 8);
  o[0] = make_float4(v[0], v[1], v[2], v[3]);
  o[1] = make_float4(v[4], v[5], v[6], v[7]);
}

// ---------- per-column sum of squares ----------
__global__ __launch_bounds__(256) void k_norm(const float* __restrict__ pooled, float* __restrict__ normsq, int NC) {
  const int c0 = threadIdx.x;
  const int c1 = threadIdx.x + 256;
  const int rows = (NC + gridDim.x - 1) / gridDim.x;
  float s0 = 0.f, s1 = 0.f;
  for (int rr = 0; rr < rows; rr++) {
    int r = blockIdx.x * rows + rr;
    if (r < NC) {
      float v0 = pooled[(size_t)r * 512 + c0];
      float v1 = pooled[(size_t)r * 512 + c1];
      s0 = fmaf(v0, v0, s0);
      s1 = fmaf(v1, v1, s1);
    }
  }
  atomicAdd(&normsq[c0], s0);
  atomicAdd(&normsq[c1], s1);
}

__global__ void k_final(const float* __restrict__ pooled, const float* __restrict__ normsq,
                        float* __restrict__ out, int n) {
  int i = blockIdx.x * blockDim.x + threadIdx.x;
  if (i >= n) return;
  int c = i & 511;
  out[i] = pooled[i] * rsqrtf(normsq[c]);
}

// ---------- launch ----------
extern "C" void kernel_launch(void* const* d_in, const int* in_sizes, int n_in,
                              void* d_out, int out_size, void* d_ws, size_t ws_size,
                              hipStream_t stream) {
  const int N = in_sizes[0] / 64;
  const int E = in_sizes[1] / 2;
  const int NC = out_size / 512;

  const float* x0 = (const float*)d_in[0];
  const int* ei = (const int*)d_in[1];
  const int* cluster = (const int*)d_in[2];

  const float* W[18];
  for (int k = 0; k < 18; k++) W[k] = (const float*)d_in[5 + k];

  char* p = (char*)d_ws;
  auto alloc = [&](size_t bytes) -> void* {
    void* r = (void*)p;
    p += (bytes + 255) & ~(size_t)255;
    return r;
  };
  ushort_t* x1h   = (ushort_t*)alloc((size_t)N * 128 * 2);
  ushort_t* x2h   = (ushort_t*)alloc((size_t)N * 256 * 2);
  ushort_t* x3h   = (ushort_t*)alloc((size_t)N * 512 * 2);
  float* pooled = (float*)alloc((size_t)NC * 512 * 4);
  float* normsq = (float*)alloc((size_t)512 * 4);
  int* degE     = (int*)alloc((size_t)N * 4);
  int* rowptrE  = (int*)alloc((size_t)(N + 1) * 4);
  int* cursorE  = (int*)alloc((size_t)(N + 1) * 4);
  int* colE     = (int*)alloc((size_t)E * 4);
  int* degC     = (int*)alloc((size_t)NC * 4);
  int* rowptrC  = (int*)alloc((size_t)(NC + 1) * 4);
  int* cursorC  = (int*)alloc((size_t)(NC + 1) * 4);
  int* colC     = (int*)alloc((size_t)N * 4);

  hipMemsetAsync(degE, 0, (size_t)N * 4, stream);
  hipMemsetAsync(degC, 0, (size_t)NC * 4, stream);
  hipMemsetAsync(normsq, 0, (size_t)512 * 4, stream);

  // edge CSR (grouped by dst)
  k_hist<<<(E + 255) / 256, 256, 0, stream>>>(ei + E, degE, E);
  k_scan<<<1, 1024, 0, stream>>>(degE, rowptrE, cursorE, N);
  k_scatter_e<<<(E + 255) / 256, 256, 0, stream>>>(ei, cursorE, colE, E);

  // cluster CSR
  k_hist<<<(N + 255) / 256, 256, 0, stream>>>(cluster, degC, N);
  k_scan<<<1, 1024, 0, stream>>>(degC, rowptrC, cursorC, NC);
  k_scatter_n<<<(N + 255) / 256, 256, 0, stream>>>(cluster, cursorC, colC, N);

  const int nblk = (N + 63) / 64;
  // layer 0: cin=64 (fp32 input)
  k_mlp<64, float><<<nblk, 256, 0, stream>>>(x0, W[0], W[1], W[2], W[3], W[4], W[5], x1h, N);
  k_agg<64><<<(N * 64 + 255) / 256, 256, 0, stream>>>(x1h, rowptrE, colE, N);
  // layer 1: cin=128 (f16 input)
  k_mlp<128, ushort_t><<<nblk, 256, 0, stream>>>(x1h, W[6], W[7], W[8], W[9], W[10], W[11], x2h, N);
  k_agg<128><<<(N * 64 + 255) / 256, 256, 0, stream>>>(x2h, rowptrE, colE, N);
  // layer 2: cin=256 (f16 input)
  k_mlp<256, ushort_t><<<nblk, 256, 0, stream>>>(x2h, W[12], W[13], W[14], W[15], W[16], W[17], x3h, N);
  k_agg<256><<<(N * 64 + 255) / 256, 256, 0, stream>>>(x3h, rowptrE, colE, N);

  // cluster max-pool + column L2 normalize
  k_pool<<<(NC * 64 + 255) / 256, 256, 0, stream>>>(x3h, rowptrC, colC, pooled, NC);
  k_norm<<<128, 256, 0, stream>>>(pooled, normsq, NC);
  k_final<<<(NC * 512 + 255) / 256, 256, 0, stream>>>(pooled, normsq, (float*)d_out, NC * 512);
}

// Round 5
// 527.576 us; speedup vs baseline: 1.5086x; 1.1911x over previous
//
#include <hip/hip_runtime.h>
#include <hip/hip_fp16.h>

typedef unsigned short ushort_t;
typedef unsigned int uint_t;

__device__ __forceinline__ float2 h2f2(uint_t u) {
  __half2 h = *reinterpret_cast<__half2*>(&u);
  return __half22float2(h);
}
__device__ __forceinline__ uint_t f2h2(float a, float b) {
  __half2 h = __floats2half2_rn(a, b);
  return *reinterpret_cast<uint_t*>(&h);
}

// ---------- CSR construction ----------

__global__ void k_hist(const int* __restrict__ idx, int* __restrict__ deg, int n) {
  int i = blockIdx.x * blockDim.x + threadIdx.x;
  if (i < n) atomicAdd(&deg[idx[i]], 1);
}

__global__ __launch_bounds__(1024) void k_scan(const int* __restrict__ deg, int* __restrict__ rowptr,
                                               int* __restrict__ cursor, int n) {
  __shared__ int wtot[16];
  const int tid = threadIdx.x;
  const int lane = tid & 63;
  const int w = tid >> 6;
  int carry = 0;
  if (tid == 0) { rowptr[0] = 0; cursor[0] = 0; }
  for (int base = 0; base < n; base += 1024) {
    int i = base + tid;
    int v = (i < n) ? deg[i] : 0;
    int incl = v;
#pragma unroll
    for (int off = 1; off < 64; off <<= 1) {
      int t = __shfl_up(incl, off, 64);
      if (lane >= off) incl += t;
    }
    if (lane == 63) wtot[w] = incl;
    __syncthreads();
    if (w == 0) {
      int tv = (lane < 16) ? wtot[lane] : 0;
#pragma unroll
      for (int off = 1; off < 16; off <<= 1) {
        int t = __shfl_up(tv, off, 64);
        if (lane >= off) tv += t;
      }
      if (lane < 16) wtot[lane] = tv;
    }
    __syncthreads();
    int woff = (w == 0) ? 0 : wtot[w - 1];
    int total = wtot[15];
    int out = carry + woff + incl;
    if (i < n) { rowptr[i + 1] = out; cursor[i + 1] = out; }
    carry += total;
    __syncthreads();
  }
}

__global__ void k_scatter_e(const int* __restrict__ ei, int* __restrict__ cursor,
                            int* __restrict__ col, int E) {
  int i = blockIdx.x * blockDim.x + threadIdx.x;
  if (i < E) {
    int d = ei[E + i];
    int s = ei[i];
    int pos = atomicAdd(&cursor[d], 1);
    col[pos] = s;
  }
}

__global__ void k_scatter_n(const int* __restrict__ cluster, int* __restrict__ cursor,
                            int* __restrict__ col, int N) {
  int i = blockIdx.x * blockDim.x + threadIdx.x;
  if (i < N) {
    int c = cluster[i];
    int pos = atomicAdd(&cursor[c], 1);
    col[pos] = i;
  }
}

// ---------- fused per-64-node-tile MLP (fp32 math, f16 storage out) ----------
template <int CIN, typename TIN>
__global__ __launch_bounds__(256) void k_mlp(const TIN* __restrict__ xin,
                                             const float* __restrict__ w1, const float* __restrict__ b1,
                                             const float* __restrict__ g, const float* __restrict__ be,
                                             const float* __restrict__ w2, const float* __restrict__ b2,
                                             ushort_t* __restrict__ xout, int N) {
  __shared__ float sX[64 * 64];
  __shared__ float sW[64 * 64];

  const int tid = threadIdx.x;
  const int tn = tid >> 4;
  const int tc = tid & 15;
  const int nb = blockIdx.x * 64;

  float acc[4][4];
#pragma unroll
  for (int i = 0; i < 4; i++)
#pragma unroll
    for (int j = 0; j < 4; j++) acc[i][j] = 0.f;

  const int ln = tid >> 2;
  const int lk = (tid & 3) * 16;
  int gn = nb + ln;
  if (gn >= N) gn = N - 1;
  const TIN* xrow = xin + (size_t)gn * CIN;

  // ---- phase 1: H = X @ W1 ----
  for (int k0 = 0; k0 < CIN; k0 += 64) {
    __syncthreads();
    {
      const float4* src = reinterpret_cast<const float4*>(w1 + (size_t)k0 * 64);
      float4* dst = reinterpret_cast<float4*>(sW);
#pragma unroll
      for (int r = 0; r < 4; r++) dst[tid + r * 256] = src[tid + r * 256];
    }
    if constexpr (sizeof(TIN) == 4) {
      float4 v[4];
      const float4* src = reinterpret_cast<const float4*>(xrow + k0 + lk);
#pragma unroll
      for (int f = 0; f < 4; f++) v[f] = src[f];
#pragma unroll
      for (int f = 0; f < 4; f++) {
#pragma unroll
        for (int q = 0; q < 4; q++) sX[(lk + f * 4 + q) * 64 + ln] = (&v[f].x)[q];
      }
    } else {
      uint4 a = *reinterpret_cast<const uint4*>(xrow + k0 + lk);
      uint4 b = *reinterpret_cast<const uint4*>(xrow + k0 + lk + 8);
      uint_t ua[8] = {a.x, a.y, a.z, a.w, b.x, b.y, b.z, b.w};
#pragma unroll
      for (int q = 0; q < 8; q++) {
        float2 f = h2f2(ua[q]);
        sX[(lk + 2 * q) * 64 + ln] = f.x;
        sX[(lk + 2 * q + 1) * 64 + ln] = f.y;
      }
    }
    __syncthreads();
#pragma unroll 8
    for (int k = 0; k < 64; k++) {
      float4 xv = *reinterpret_cast<const float4*>(&sX[k * 64 + tn * 4]);
      float4 wv = *reinterpret_cast<const float4*>(&sW[k * 64 + tc * 4]);
#pragma unroll
      for (int i = 0; i < 4; i++) {
        float x = (&xv.x)[i];
        acc[i][0] = fmaf(x, wv.x, acc[i][0]);
        acc[i][1] = fmaf(x, wv.y, acc[i][1]);
        acc[i][2] = fmaf(x, wv.z, acc[i][2]);
        acc[i][3] = fmaf(x, wv.w, acc[i][3]);
      }
    }
  }

  // ---- + b1, LayerNorm(64), *g + be, ReLU ----
  {
    float4 bv = *reinterpret_cast<const float4*>(b1 + tc * 4);
#pragma unroll
    for (int i = 0; i < 4; i++)
#pragma unroll
      for (int j = 0; j < 4; j++) acc[i][j] += (&bv.x)[j];

    float s[4];
#pragma unroll
    for (int i = 0; i < 4; i++) s[i] = acc[i][0] + acc[i][1] + acc[i][2] + acc[i][3];
#pragma unroll
    for (int m = 1; m < 16; m <<= 1) {
#pragma unroll
      for (int i = 0; i < 4; i++) s[i] += __shfl_xor(s[i], m, 64);
    }
    float mu[4];
#pragma unroll
    for (int i = 0; i < 4; i++) mu[i] = s[i] * (1.f / 64.f);

    float t[4];
#pragma unroll
    for (int i = 0; i < 4; i++) {
      float d0 = acc[i][0] - mu[i], d1 = acc[i][1] - mu[i];
      float d2 = acc[i][2] - mu[i], d3 = acc[i][3] - mu[i];
      t[i] = d0 * d0 + d1 * d1 + d2 * d2 + d3 * d3;
    }
#pragma unroll
    for (int m = 1; m < 16; m <<= 1) {
#pragma unroll
      for (int i = 0; i < 4; i++) t[i] += __shfl_xor(t[i], m, 64);
    }
    float rs[4];
#pragma unroll
    for (int i = 0; i < 4; i++) rs[i] = rsqrtf(t[i] * (1.f / 64.f) + 1e-5f);

    float4 gv = *reinterpret_cast<const float4*>(g + tc * 4);
    float4 bev = *reinterpret_cast<const float4*>(be + tc * 4);
#pragma unroll
    for (int i = 0; i < 4; i++)
#pragma unroll
      for (int j = 0; j < 4; j++) {
        float h = (acc[i][j] - mu[i]) * rs[i] * (&gv.x)[j] + (&bev.x)[j];
        acc[i][j] = fmaxf(h, 0.f);
      }
  }

  // ---- write H^T to LDS ----
  __syncthreads();
#pragma unroll
  for (int j = 0; j < 4; j++) {
    float4 hv = make_float4(acc[0][j], acc[1][j], acc[2][j], acc[3][j]);
    *reinterpret_cast<float4*>(&sX[(tc * 4 + j) * 64 + tn * 4]) = hv;
  }

  // ---- phase 2: OUT = H @ W2 + b2 ----
  for (int j0 = 0; j0 < CIN; j0 += 64) {
    __syncthreads();
    {
      const int c = tid >> 2;
      const int jj = (tid & 3) * 16;
      const float4* src = reinterpret_cast<const float4*>(w2 + (size_t)c * CIN + j0 + jj);
      float4* dst = reinterpret_cast<float4*>(&sW[c * 64 + jj]);
#pragma unroll
      for (int f = 0; f < 4; f++) dst[f] = src[f];
    }
    __syncthreads();

    float o[4][4];
    float4 b2v = *reinterpret_cast<const float4*>(b2 + j0 + tc * 4);
#pragma unroll
    for (int i = 0; i < 4; i++)
#pragma unroll
      for (int j = 0; j < 4; j++) o[i][j] = (&b2v.x)[j];

#pragma unroll 8
    for (int c = 0; c < 64; c++) {
      float4 hv = *reinterpret_cast<const float4*>(&sX[c * 64 + tn * 4]);
      float4 wv = *reinterpret_cast<const float4*>(&sW[c * 64 + tc * 4]);
#pragma unroll
      for (int i = 0; i < 4; i++) {
        float h = (&hv.x)[i];
        o[i][0] = fmaf(h, wv.x, o[i][0]);
        o[i][1] = fmaf(h, wv.y, o[i][1]);
        o[i][2] = fmaf(h, wv.z, o[i][2]);
        o[i][3] = fmaf(h, wv.w, o[i][3]);
      }
    }
#pragma unroll
    for (int i = 0; i < 4; i++) {
      int n = nb + tn * 4 + i;
      if (n < N) {
        uint2 pk = make_uint2(f2h2(o[i][0], o[i][1]), f2h2(o[i][2], o[i][3]));
        *reinterpret_cast<uint2*>(&xout[(size_t)n * (2 * CIN) + j0 + tc * 4]) = pk;
      }
    }
  }
}

// ---------- scatter-max as CSR gather-max, MLP-optimized ----------
// Always 8 B/lane (f16x4). LPR = lanes per row; RPW = rows (nodes) per wave.
// Edge loop unrolled x4 with duplicate-clamp (duplicates are no-ops under max)
// => 4*RPW independent row-loads in flight per wave.
template <int CIN>
__global__ __launch_bounds__(256) void k_agg(ushort_t* __restrict__ xb, const int* __restrict__ rowptr,
                                             const int* __restrict__ col, int N) {
  constexpr int LPR = CIN / 4;
  constexpr int RPW = 64 / LPR;
  const int wid = (blockIdx.x * blockDim.x + threadIdx.x) >> 6;
  const int lane = threadIdx.x & 63;
  const int sub = lane / LPR;
  const int ll = lane % LPR;
  const int node = wid * RPW + sub;
  if (node >= N) return;
  const int beg = rowptr[node], end = rowptr[node + 1];
  float v0 = -INFINITY, v1 = -INFINITY, v2 = -INFINITY, v3 = -INFINITY;
  for (int e = beg; e < end; e += 4) {
    int idx[4];
#pragma unroll
    for (int u = 0; u < 4; u++) { int t = e + u; idx[u] = col[t < end ? t : e]; }
    uint2 r[4];
#pragma unroll
    for (int u = 0; u < 4; u++)
      r[u] = *reinterpret_cast<const uint2*>(xb + (size_t)idx[u] * (2 * CIN) + ll * 4);
#pragma unroll
    for (int u = 0; u < 4; u++) {
      float2 f0 = h2f2(r[u].x), f1 = h2f2(r[u].y);
      v0 = fmaxf(v0, f0.x); v1 = fmaxf(v1, f0.y);
      v2 = fmaxf(v2, f1.x); v3 = fmaxf(v3, f1.y);
    }
  }
  if (beg == end) { v0 = v1 = v2 = v3 = 0.f; }
  *reinterpret_cast<uint2*>(xb + (size_t)node * (2 * CIN) + CIN + ll * 4) =
      make_uint2(f2h2(v0, v1), f2h2(v2, v3));
}

// ---------- cluster max-pool: wave per cluster, 512 f16 channels, unrolled x4 ----------
__global__ __launch_bounds__(256) void k_pool(const ushort_t* __restrict__ x3, const int* __restrict__ rowptr,
                                              const int* __restrict__ col, float* __restrict__ pooled, int NC) {
  const int wid = (blockIdx.x * blockDim.x + threadIdx.x) >> 6;
  const int lane = threadIdx.x & 63;
  if (wid >= NC) return;
  const int beg = rowptr[wid], end = rowptr[wid + 1];
  float v[8];
#pragma unroll
  for (int q = 0; q < 8; q++) v[q] = -INFINITY;
  for (int e = beg; e < end; e += 4) {
    int idx[4];
#pragma unroll
    for (int u = 0; u < 4; u++) { int t = e + u; idx[u] = col[t < end ? t : e]; }
    uint4 r[4];
#pragma unroll
    for (int u = 0; u < 4; u++)
      r[u] = *reinterpret_cast<const uint4*>(x3 + (size_t)idx[u] * 512 + lane * 8);
#pragma unroll
    for (int u = 0; u < 4; u++) {
      float2 f0 = h2f2(r[u].x), f1 = h2f2(r[u].y), f2 = h2f2(r[u].z), f3 = h2f2(r[u].w);
      v[0] = fmaxf(v[0], f0.x); v[1] = fmaxf(v[1], f0.y);
      v[2] = fmaxf(v[2], f1.x); v[3] = fmaxf(v[3], f1.y);
      v[4] = fmaxf(v[4], f2.x); v[5] = fmaxf(v[5], f2.y);
      v[6] = fmaxf(v[6], f3.x); v[7] = fmaxf(v[7], f3.y);
    }
  }
  if (beg == end) {
#pragma unroll
    for (int q = 0; q < 8; q++) v[q] = 0.f;
  }
  float4* o = reinterpret_cast<float4*>(pooled + (size_t)wid * 512 + lane * 8);
  o[0] = make_float4(v[0], v[1], v[2], v[3]);
  o[1] = make_float4(v[4], v[5], v[6], v[7]);
}

// ---------- per-column sum of squares ----------
__global__ __launch_bounds__(256) void k_norm(const float* __restrict__ pooled, float* __restrict__ normsq, int NC) {
  const int c0 = threadIdx.x;
  const int c1 = threadIdx.x + 256;
  const int rows = (NC + gridDim.x - 1) / gridDim.x;
  float s0 = 0.f, s1 = 0.f;
  for (int rr = 0; rr < rows; rr++) {
    int r = blockIdx.x * rows + rr;
    if (r < NC) {
      float v0 = pooled[(size_t)r * 512 + c0];
      float v1 = pooled[(size_t)r * 512 + c1];
      s0 = fmaf(v0, v0, s0);
      s1 = fmaf(v1, v1, s1);
    }
  }
  atomicAdd(&normsq[c0], s0);
  atomicAdd(&normsq[c1], s1);
}

__global__ void k_final(const float* __restrict__ pooled, const float* __restrict__ normsq,
                        float* __restrict__ out, int n) {
  int i = blockIdx.x * blockDim.x + threadIdx.x;
  if (i >= n) return;
  int c = i & 511;
  out[i] = pooled[i] * rsqrtf(normsq[c]);
}

// ---------- launch ----------
extern "C" void kernel_launch(void* const* d_in, const int* in_sizes, int n_in,
                              void* d_out, int out_size, void* d_ws, size_t ws_size,
                              hipStream_t stream) {
  const int N = in_sizes[0] / 64;
  const int E = in_sizes[1] / 2;
  const int NC = out_size / 512;

  const float* x0 = (const float*)d_in[0];
  const int* ei = (const int*)d_in[1];
  const int* cluster = (const int*)d_in[2];

  const float* W[18];
  for (int k = 0; k < 18; k++) W[k] = (const float*)d_in[5 + k];

  char* p = (char*)d_ws;
  auto alloc = [&](size_t bytes) -> void* {
    void* r = (void*)p;
    p += (bytes + 255) & ~(size_t)255;
    return r;
  };
  ushort_t* x1h = (ushort_t*)alloc((size_t)N * 128 * 2);
  ushort_t* x2h = (ushort_t*)alloc((size_t)N * 256 * 2);
  ushort_t* x3h = (ushort_t*)alloc((size_t)N * 512 * 2);
  float* pooled = (float*)alloc((size_t)NC * 512 * 4);
  float* normsq = (float*)alloc((size_t)512 * 4);
  int* degE     = (int*)alloc((size_t)N * 4);
  int* rowptrE  = (int*)alloc((size_t)(N + 1) * 4);
  int* cursorE  = (int*)alloc((size_t)(N + 1) * 4);
  int* colE     = (int*)alloc((size_t)E * 4);
  int* degC     = (int*)alloc((size_t)NC * 4);
  int* rowptrC  = (int*)alloc((size_t)(NC + 1) * 4);
  int* cursorC  = (int*)alloc((size_t)(NC + 1) * 4);
  int* colC     = (int*)alloc((size_t)N * 4);

  hipMemsetAsync(degE, 0, (size_t)N * 4, stream);
  hipMemsetAsync(degC, 0, (size_t)NC * 4, stream);
  hipMemsetAsync(normsq, 0, (size_t)512 * 4, stream);

  // edge CSR (grouped by dst)
  k_hist<<<(E + 255) / 256, 256, 0, stream>>>(ei + E, degE, E);
  k_scan<<<1, 1024, 0, stream>>>(degE, rowptrE, cursorE, N);
  k_scatter_e<<<(E + 255) / 256, 256, 0, stream>>>(ei, cursorE, colE, E);

  // cluster CSR
  k_hist<<<(N + 255) / 256, 256, 0, stream>>>(cluster, degC, N);
  k_scan<<<1, 1024, 0, stream>>>(degC, rowptrC, cursorC, NC);
  k_scatter_n<<<(N + 255) / 256, 256, 0, stream>>>(cluster, cursorC, colC, N);

  const int nblk = (N + 63) / 64;
  // layer 0: cin=64 (fp32 input); agg: RPW=4
  k_mlp<64, float><<<nblk, 256, 0, stream>>>(x0, W[0], W[1], W[2], W[3], W[4], W[5], x1h, N);
  { int waves = (N + 3) / 4; k_agg<64><<<(waves * 64 + 255) / 256, 256, 0, stream>>>(x1h, rowptrE, colE, N); }
  // layer 1: cin=128; agg: RPW=2
  k_mlp<128, ushort_t><<<nblk, 256, 0, stream>>>(x1h, W[6], W[7], W[8], W[9], W[10], W[11], x2h, N);
  { int waves = (N + 1) / 2; k_agg<128><<<(waves * 64 + 255) / 256, 256, 0, stream>>>(x2h, rowptrE, colE, N); }
  // layer 2: cin=256; agg: RPW=1
  k_mlp<256, ushort_t><<<nblk, 256, 0, stream>>>(x2h, W[12], W[13], W[14], W[15], W[16], W[17], x3h, N);
  { int waves = N; k_agg<256><<<(waves * 64 + 255) / 256, 256, 0, stream>>>(x3h, rowptrE, colE, N); }

  // cluster max-pool + column L2 normalize
  k_pool<<<(NC * 64 + 255) / 256, 256, 0, stream>>>(x3h, rowptrC, colC, pooled, NC);
  k_norm<<<128, 256, 0, stream>>>(pooled, normsq, NC);
  k_final<<<(NC * 512 + 255) / 256, 256, 0, stream>>>(pooled, normsq, (float*)d_out, NC * 512);
}

// Round 6
// 519.643 us; speedup vs baseline: 1.5316x; 1.0153x over previous
//
#include <hip/hip_runtime.h>
#include <hip/hip_fp16.h>

typedef unsigned short ushort_t;
typedef unsigned int uint_t;
typedef _Float16 f16_t;
typedef __attribute__((ext_vector_type(8))) _Float16 f16x8;
typedef __attribute__((ext_vector_type(4))) float f32x4;

__device__ __forceinline__ float2 h2f2(uint_t u) {
  __half2 h = *reinterpret_cast<__half2*>(&u);
  return __half22float2(h);
}
__device__ __forceinline__ uint_t f2h2(float a, float b) {
  __half2 h = __floats2half2_rn(a, b);
  return *reinterpret_cast<uint_t*>(&h);
}

// ---------- CSR construction ----------

__global__ void k_hist(const int* __restrict__ idx, int* __restrict__ deg, int n) {
  int i = blockIdx.x * blockDim.x + threadIdx.x;
  if (i < n) atomicAdd(&deg[idx[i]], 1);
}

__global__ __launch_bounds__(1024) void k_scan(const int* __restrict__ deg, int* __restrict__ rowptr,
                                               int* __restrict__ cursor, int n) {
  __shared__ int wtot[16];
  const int tid = threadIdx.x;
  const int lane = tid & 63;
  const int w = tid >> 6;
  int carry = 0;
  if (tid == 0) { rowptr[0] = 0; cursor[0] = 0; }
  for (int base = 0; base < n; base += 1024) {
    int i = base + tid;
    int v = (i < n) ? deg[i] : 0;
    int incl = v;
#pragma unroll
    for (int off = 1; off < 64; off <<= 1) {
      int t = __shfl_up(incl, off, 64);
      if (lane >= off) incl += t;
    }
    if (lane == 63) wtot[w] = incl;
    __syncthreads();
    if (w == 0) {
      int tv = (lane < 16) ? wtot[lane] : 0;
#pragma unroll
      for (int off = 1; off < 16; off <<= 1) {
        int t = __shfl_up(tv, off, 64);
        if (lane >= off) tv += t;
      }
      if (lane < 16) wtot[lane] = tv;
    }
    __syncthreads();
    int woff = (w == 0) ? 0 : wtot[w - 1];
    int total = wtot[15];
    int out = carry + woff + incl;
    if (i < n) { rowptr[i + 1] = out; cursor[i + 1] = out; }
    carry += total;
    __syncthreads();
  }
}

__global__ void k_scatter_e(const int* __restrict__ ei, int* __restrict__ cursor,
                            int* __restrict__ col, int E) {
  int i = blockIdx.x * blockDim.x + threadIdx.x;
  if (i < E) {
    int d = ei[E + i];
    int s = ei[i];
    int pos = atomicAdd(&cursor[d], 1);
    col[pos] = s;
  }
}

__global__ void k_scatter_n(const int* __restrict__ cluster, int* __restrict__ cursor,
                            int* __restrict__ col, int N) {
  int i = blockIdx.x * blockDim.x + threadIdx.x;
  if (i < N) {
    int c = cluster[i];
    int pos = atomicAdd(&cursor[c], 1);
    col[pos] = i;
  }
}

// ---------- weight prep: transpose + f16 hi/lo split ----------
// w1 (CIN,64) row-major -> w1t[c*CIN + k]; w2 (64,CIN) row-major -> w2t[j*64 + c]
template <int CIN>
__global__ void k_prep(const float* __restrict__ w1, const float* __restrict__ w2,
                       f16_t* __restrict__ w1t_hi, f16_t* __restrict__ w1t_lo,
                       f16_t* __restrict__ w2t_hi, f16_t* __restrict__ w2t_lo) {
  int i = blockIdx.x * blockDim.x + threadIdx.x;
  const int n1 = CIN * 64;
  if (i < n1) {
    int k = i >> 6, c = i & 63;
    float v = w1[i];
    f16_t hi = (f16_t)v;
    w1t_hi[(size_t)c * CIN + k] = hi;
    w1t_lo[(size_t)c * CIN + k] = (f16_t)(v - (float)hi);
  } else if (i < 2 * n1) {
    int i2 = i - n1;
    int c = i2 / CIN, j = i2 & (CIN - 1);
    float v = w2[i2];
    f16_t hi = (f16_t)v;
    w2t_hi[(size_t)j * 64 + c] = hi;
    w2t_lo[(size_t)j * 64 + c] = (f16_t)(v - (float)hi);
  }
}

// ---------- MFMA MLP: Linear(CIN->64) -> LN -> ReLU -> Linear(64->CIN) ----------
// block = 256 threads = 4 waves; wave handles 16 nodes. No __syncthreads at all.
// A-frag: A[m=lane&15][k=quad*8+j]  B-frag: B[k=quad*8+j][n=lane&15]
// D: row=quad*4+reg, col=lane&15.
template <int CIN, typename TIN>
__global__ __launch_bounds__(256) void k_mlp(const TIN* __restrict__ xin,
                                             const f16_t* __restrict__ w1t_hi, const f16_t* __restrict__ w1t_lo,
                                             const float* __restrict__ b1, const float* __restrict__ g,
                                             const float* __restrict__ be,
                                             const f16_t* __restrict__ w2t_hi, const f16_t* __restrict__ w2t_lo,
                                             const float* __restrict__ b2,
                                             ushort_t* __restrict__ xout, int N) {
  constexpr int CT2 = CIN / 16;
  __shared__ __align__(16) f16_t sH[4][2][16 * 72];  // [wave][hi/lo][row][72-padded]

  const int tid = threadIdx.x;
  const int wave = tid >> 6, lane = tid & 63;
  const int b = lane & 15, q = lane >> 4;
  const int nbW = blockIdx.x * 64 + wave * 16;

  // ---- GEMM1: H = X @ W1 (rows = 16 nodes, cols = 64) ----
  int nodeA = nbW + b;
  if (nodeA >= N) nodeA = N - 1;
  const TIN* xrow = xin + (size_t)nodeA * CIN;

  f32x4 acc1[4] = {};
  for (int kt = 0; kt < CIN / 32; kt++) {
    const int k0 = kt * 32 + q * 8;
    f16x8 a, al;
    if constexpr (sizeof(TIN) == 4) {
      float f[8];
      *reinterpret_cast<float4*>(&f[0]) = *reinterpret_cast<const float4*>(&xrow[k0]);
      *reinterpret_cast<float4*>(&f[4]) = *reinterpret_cast<const float4*>(&xrow[k0 + 4]);
#pragma unroll
      for (int j = 0; j < 8; j++) {
        f16_t h = (f16_t)f[j];
        a[j] = h;
        al[j] = (f16_t)(f[j] - (float)h);
      }
    } else {
      a = *reinterpret_cast<const f16x8*>(&xrow[k0]);
    }
#pragma unroll
    for (int t = 0; t < 4; t++) {
      const int col = t * 16 + b;
      f16x8 bh = *reinterpret_cast<const f16x8*>(&w1t_hi[(size_t)col * CIN + k0]);
      f16x8 bl = *reinterpret_cast<const f16x8*>(&w1t_lo[(size_t)col * CIN + k0]);
      acc1[t] = __builtin_amdgcn_mfma_f32_16x16x32_f16(a, bh, acc1[t], 0, 0, 0);
      acc1[t] = __builtin_amdgcn_mfma_f32_16x16x32_f16(a, bl, acc1[t], 0, 0, 0);
      if constexpr (sizeof(TIN) == 4)
        acc1[t] = __builtin_amdgcn_mfma_f32_16x16x32_f16(al, bh, acc1[t], 0, 0, 0);
    }
  }

  // ---- + b1, LayerNorm(64), *g + be, ReLU (fp32, shfl butterflies) ----
  float b1v[4], gv[4], bev[4];
#pragma unroll
  for (int t = 0; t < 4; t++) {
    b1v[t] = b1[t * 16 + b];
    gv[t] = g[t * 16 + b];
    bev[t] = be[t * 16 + b];
  }
#pragma unroll
  for (int t = 0; t < 4; t++)
#pragma unroll
    for (int r = 0; r < 4; r++) acc1[t][r] += b1v[t];

  float mu[4], vv[4], rs[4];
#pragma unroll
  for (int r = 0; r < 4; r++) mu[r] = acc1[0][r] + acc1[1][r] + acc1[2][r] + acc1[3][r];
#pragma unroll
  for (int m = 1; m < 16; m <<= 1) {
#pragma unroll
    for (int r = 0; r < 4; r++) mu[r] += __shfl_xor(mu[r], m, 64);
  }
#pragma unroll
  for (int r = 0; r < 4; r++) mu[r] *= (1.f / 64.f);
#pragma unroll
  for (int r = 0; r < 4; r++) {
    float d0 = acc1[0][r] - mu[r], d1 = acc1[1][r] - mu[r];
    float d2 = acc1[2][r] - mu[r], d3 = acc1[3][r] - mu[r];
    vv[r] = d0 * d0 + d1 * d1 + d2 * d2 + d3 * d3;
  }
#pragma unroll
  for (int m = 1; m < 16; m <<= 1) {
#pragma unroll
    for (int r = 0; r < 4; r++) vv[r] += __shfl_xor(vv[r], m, 64);
  }
#pragma unroll
  for (int r = 0; r < 4; r++) rs[r] = rsqrtf(vv[r] * (1.f / 64.f) + 1e-5f);

  // ---- h -> f16 hi/lo into per-wave LDS (A-layout rows) ----
  f16_t* shi = &sH[wave][0][0];
  f16_t* slo = &sH[wave][1][0];
#pragma unroll
  for (int t = 0; t < 4; t++)
#pragma unroll
    for (int r = 0; r < 4; r++) {
      float h = (acc1[t][r] - mu[r]) * rs[r] * gv[t] + bev[t];
      h = fmaxf(h, 0.f);
      f16_t hh = (f16_t)h;
      int row = q * 4 + r, col = t * 16 + b;
      shi[row * 72 + col] = hh;
      slo[row * 72 + col] = (f16_t)(h - (float)hh);
    }

  // ---- GEMM2: OUT = H @ W2 + b2 (rows = 16 nodes, cols = CIN) ----
  f16x8 ahi[2], alo[2];
#pragma unroll
  for (int kt = 0; kt < 2; kt++) {
    ahi[kt] = *reinterpret_cast<const f16x8*>(&shi[b * 72 + kt * 32 + q * 8]);
    alo[kt] = *reinterpret_cast<const f16x8*>(&slo[b * 72 + kt * 32 + q * 8]);
  }

#pragma unroll
  for (int t2 = 0; t2 < CT2; t2++) {
    const int col = t2 * 16 + b;
    f32x4 acc = {};
#pragma unroll
    for (int kt = 0; kt < 2; kt++) {
      const int k0 = kt * 32 + q * 8;
      f16x8 bh = *reinterpret_cast<const f16x8*>(&w2t_hi[(size_t)col * 64 + k0]);
      f16x8 bl = *reinterpret_cast<const f16x8*>(&w2t_lo[(size_t)col * 64 + k0]);
      acc = __builtin_amdgcn_mfma_f32_16x16x32_f16(ahi[kt], bh, acc, 0, 0, 0);
      acc = __builtin_amdgcn_mfma_f32_16x16x32_f16(ahi[kt], bl, acc, 0, 0, 0);
      acc = __builtin_amdgcn_mfma_f32_16x16x32_f16(alo[kt], bh, acc, 0, 0, 0);
    }
    float b2v = b2[col];
#pragma unroll
    for (int r = 0; r < 4; r++) {
      int node = nbW + q * 4 + r;
      if (node < N) {
        __half hv = __float2half_rn(acc[r] + b2v);
        xout[(size_t)node * (2 * CIN) + col] = *reinterpret_cast<ushort_t*>(&hv);
      }
    }
  }
}

// ---------- scatter-max as CSR gather-max (8 B/lane, x4 unroll) ----------
template <int CIN>
__global__ __launch_bounds__(256) void k_agg(ushort_t* __restrict__ xb, const int* __restrict__ rowptr,
                                             const int* __restrict__ col, int N) {
  constexpr int LPR = CIN / 4;
  constexpr int RPW = 64 / LPR;
  const int wid = (blockIdx.x * blockDim.x + threadIdx.x) >> 6;
  const int lane = threadIdx.x & 63;
  const int sub = lane / LPR;
  const int ll = lane % LPR;
  const int node = wid * RPW + sub;
  if (node >= N) return;
  const int beg = rowptr[node], end = rowptr[node + 1];
  float v0 = -INFINITY, v1 = -INFINITY, v2 = -INFINITY, v3 = -INFINITY;
  for (int e = beg; e < end; e += 4) {
    int idx[4];
#pragma unroll
    for (int u = 0; u < 4; u++) { int t = e + u; idx[u] = col[t < end ? t : e]; }
    uint2 r[4];
#pragma unroll
    for (int u = 0; u < 4; u++)
      r[u] = *reinterpret_cast<const uint2*>(xb + (size_t)idx[u] * (2 * CIN) + ll * 4);
#pragma unroll
    for (int u = 0; u < 4; u++) {
      float2 f0 = h2f2(r[u].x), f1 = h2f2(r[u].y);
      v0 = fmaxf(v0, f0.x); v1 = fmaxf(v1, f0.y);
      v2 = fmaxf(v2, f1.x); v3 = fmaxf(v3, f1.y);
    }
  }
  if (beg == end) { v0 = v1 = v2 = v3 = 0.f; }
  *reinterpret_cast<uint2*>(xb + (size_t)node * (2 * CIN) + CIN + ll * 4) =
      make_uint2(f2h2(v0, v1), f2h2(v2, v3));
}

// ---------- cluster max-pool: wave per cluster, 512 f16 channels, x4 unroll ----------
__global__ __launch_bounds__(256) void k_pool(const ushort_t* __restrict__ x3, const int* __restrict__ rowptr,
                                              const int* __restrict__ col, float* __restrict__ pooled, int NC) {
  const int wid = (blockIdx.x * blockDim.x + threadIdx.x) >> 6;
  const int lane = threadIdx.x & 63;
  if (wid >= NC) return;
  const int beg = rowptr[wid], end = rowptr[wid + 1];
  float v[8];
#pragma unroll
  for (int q = 0; q < 8; q++) v[q] = -INFINITY;
  for (int e = beg; e < end; e += 4) {
    int idx[4];
#pragma unroll
    for (int u = 0; u < 4; u++) { int t = e + u; idx[u] = col[t < end ? t : e]; }
    uint4 r[4];
#pragma unroll
    for (int u = 0; u < 4; u++)
      r[u] = *reinterpret_cast<const uint4*>(x3 + (size_t)idx[u] * 512 + lane * 8);
#pragma unroll
    for (int u = 0; u < 4; u++) {
      float2 f0 = h2f2(r[u].x), f1 = h2f2(r[u].y), f2 = h2f2(r[u].z), f3 = h2f2(r[u].w);
      v[0] = fmaxf(v[0], f0.x); v[1] = fmaxf(v[1], f0.y);
      v[2] = fmaxf(v[2], f1.x); v[3] = fmaxf(v[3], f1.y);
      v[4] = fmaxf(v[4], f2.x); v[5] = fmaxf(v[5], f2.y);
      v[6] = fmaxf(v[6], f3.x); v[7] = fmaxf(v[7], f3.y);
    }
  }
  if (beg == end) {
#pragma unroll
    for (int q = 0; q < 8; q++) v[q] = 0.f;
  }
  float4* o = reinterpret_cast<float4*>(pooled + (size_t)wid * 512 + lane * 8);
  o[0] = make_float4(v[0], v[1], v[2], v[3]);
  o[1] = make_float4(v[4], v[5], v[6], v[7]);
}

// ---------- per-column sum of squares ----------
__global__ __launch_bounds__(256) void k_norm(const float* __restrict__ pooled, float* __restrict__ normsq, int NC) {
  const int c0 = threadIdx.x;
  const int c1 = threadIdx.x + 256;
  const int rows = (NC + gridDim.x - 1) / gridDim.x;
  float s0 = 0.f, s1 = 0.f;
  for (int rr = 0; rr < rows; rr++) {
    int r = blockIdx.x * rows + rr;
    if (r < NC) {
      float v0 = pooled[(size_t)r * 512 + c0];
      float v1 = pooled[(size_t)r * 512 + c1];
      s0 = fmaf(v0, v0, s0);
      s1 = fmaf(v1, v1, s1);
    }
  }
  atomicAdd(&normsq[c0], s0);
  atomicAdd(&normsq[c1], s1);
}

__global__ void k_final(const float* __restrict__ pooled, const float* __restrict__ normsq,
                        float* __restrict__ out, int n) {
  int i = blockIdx.x * blockDim.x + threadIdx.x;
  if (i >= n) return;
  int c = i & 511;
  out[i] = pooled[i] * rsqrtf(normsq[c]);
}

// ---------- launch ----------
extern "C" void kernel_launch(void* const* d_in, const int* in_sizes, int n_in,
                              void* d_out, int out_size, void* d_ws, size_t ws_size,
                              hipStream_t stream) {
  const int N = in_sizes[0] / 64;
  const int E = in_sizes[1] / 2;
  const int NC = out_size / 512;

  const float* x0 = (const float*)d_in[0];
  const int* ei = (const int*)d_in[1];
  const int* cluster = (const int*)d_in[2];

  const float* W[18];
  for (int k = 0; k < 18; k++) W[k] = (const float*)d_in[5 + k];

  char* p = (char*)d_ws;
  auto alloc = [&](size_t bytes) -> void* {
    void* r = (void*)p;
    p += (bytes + 255) & ~(size_t)255;
    return r;
  };
  ushort_t* x1h = (ushort_t*)alloc((size_t)N * 128 * 2);
  ushort_t* x2h = (ushort_t*)alloc((size_t)N * 256 * 2);
  ushort_t* x3h = (ushort_t*)alloc((size_t)N * 512 * 2);
  float* pooled = (float*)alloc((size_t)NC * 512 * 4);
  float* normsq = (float*)alloc((size_t)512 * 4);
  int* degE     = (int*)alloc((size_t)N * 4);
  int* rowptrE  = (int*)alloc((size_t)(N + 1) * 4);
  int* cursorE  = (int*)alloc((size_t)(N + 1) * 4);
  int* colE     = (int*)alloc((size_t)E * 4);
  int* degC     = (int*)alloc((size_t)NC * 4);
  int* rowptrC  = (int*)alloc((size_t)(NC + 1) * 4);
  int* cursorC  = (int*)alloc((size_t)(NC + 1) * 4);
  int* colC     = (int*)alloc((size_t)N * 4);
  // f16 hi/lo transposed weights per layer
  f16_t* wt[3][4];
  for (int L = 0; L < 3; L++) {
    int cin = 64 << L;
    for (int j = 0; j < 4; j++) wt[L][j] = (f16_t*)alloc((size_t)cin * 64 * 2);
  }

  hipMemsetAsync(degE, 0, (size_t)N * 4, stream);
  hipMemsetAsync(degC, 0, (size_t)NC * 4, stream);
  hipMemsetAsync(normsq, 0, (size_t)512 * 4, stream);

  // weight prep
  k_prep<64><<<(2 * 64 * 64 + 255) / 256, 256, 0, stream>>>(W[0], W[4], wt[0][0], wt[0][1], wt[0][2], wt[0][3]);
  k_prep<128><<<(2 * 128 * 64 + 255) / 256, 256, 0, stream>>>(W[6], W[10], wt[1][0], wt[1][1], wt[1][2], wt[1][3]);
  k_prep<256><<<(2 * 256 * 64 + 255) / 256, 256, 0, stream>>>(W[12], W[16], wt[2][0], wt[2][1], wt[2][2], wt[2][3]);

  // edge CSR (grouped by dst)
  k_hist<<<(E + 255) / 256, 256, 0, stream>>>(ei + E, degE, E);
  k_scan<<<1, 1024, 0, stream>>>(degE, rowptrE, cursorE, N);
  k_scatter_e<<<(E + 255) / 256, 256, 0, stream>>>(ei, cursorE, colE, E);

  // cluster CSR
  k_hist<<<(N + 255) / 256, 256, 0, stream>>>(cluster, degC, N);
  k_scan<<<1, 1024, 0, stream>>>(degC, rowptrC, cursorC, NC);
  k_scatter_n<<<(N + 255) / 256, 256, 0, stream>>>(cluster, cursorC, colC, N);

  const int nblk = (N + 63) / 64;
  // layer 0: cin=64 (fp32 input, A split)
  k_mlp<64, float><<<nblk, 256, 0, stream>>>(x0, wt[0][0], wt[0][1], W[1], W[2], W[3],
                                             wt[0][2], wt[0][3], W[5], x1h, N);
  { int waves = (N + 3) / 4; k_agg<64><<<(waves * 64 + 255) / 256, 256, 0, stream>>>(x1h, rowptrE, colE, N); }
  // layer 1: cin=128
  k_mlp<128, ushort_t><<<nblk, 256, 0, stream>>>(x1h, wt[1][0], wt[1][1], W[7], W[8], W[9],
                                                 wt[1][2], wt[1][3], W[11], x2h, N);
  { int waves = (N + 1) / 2; k_agg<128><<<(waves * 64 + 255) / 256, 256, 0, stream>>>(x2h, rowptrE, colE, N); }
  // layer 2: cin=256
  k_mlp<256, ushort_t><<<nblk, 256, 0, stream>>>(x2h, wt[2][0], wt[2][1], W[13], W[14], W[15],
                                                 wt[2][2], wt[2][3], W[17], x3h, N);
  { int waves = N; k_agg<256><<<(waves * 64 + 255) / 256, 256, 0, stream>>>(x3h, rowptrE, colE, N); }

  // cluster max-pool + column L2 normalize
  k_pool<<<(NC * 64 + 255) / 256, 256, 0, stream>>>(x3h, rowptrC, colC, pooled, NC);
  k_norm<<<128, 256, 0, stream>>>(pooled, normsq, NC);
  k_final<<<(NC * 512 + 255) / 256, 256, 0, stream>>>(pooled, normsq, (float*)d_out, NC * 512);
}

// Round 7
// 464.662 us; speedup vs baseline: 1.7128x; 1.1183x over previous
//
#include <hip/hip_runtime.h>
#include <hip/hip_fp16.h>

typedef unsigned short ushort_t;
typedef unsigned int uint_t;
typedef _Float16 f16_t;
typedef __attribute__((ext_vector_type(8))) _Float16 f16x8;
typedef __attribute__((ext_vector_type(4))) float f32x4;

__device__ __forceinline__ float2 h2f2(uint_t u) {
  __half2 h = *reinterpret_cast<__half2*>(&u);
  return __half22float2(h);
}
__device__ __forceinline__ uint_t f2h2(float a, float b) {
  __half2 h = __floats2half2_rn(a, b);
  return *reinterpret_cast<uint_t*>(&h);
}

// ---------- CSR construction ----------

__global__ void k_hist(const int* __restrict__ idx, int* __restrict__ deg, int n) {
  int i = blockIdx.x * blockDim.x + threadIdx.x;
  if (i < n) atomicAdd(&deg[idx[i]], 1);
}

__global__ __launch_bounds__(1024) void k_scan(const int* __restrict__ deg, int* __restrict__ rowptr,
                                               int* __restrict__ cursor, int n) {
  __shared__ int wtot[16];
  const int tid = threadIdx.x;
  const int lane = tid & 63;
  const int w = tid >> 6;
  int carry = 0;
  if (tid == 0) { rowptr[0] = 0; cursor[0] = 0; }
  for (int base = 0; base < n; base += 1024) {
    int i = base + tid;
    int v = (i < n) ? deg[i] : 0;
    int incl = v;
#pragma unroll
    for (int off = 1; off < 64; off <<= 1) {
      int t = __shfl_up(incl, off, 64);
      if (lane >= off) incl += t;
    }
    if (lane == 63) wtot[w] = incl;
    __syncthreads();
    if (w == 0) {
      int tv = (lane < 16) ? wtot[lane] : 0;
#pragma unroll
      for (int off = 1; off < 16; off <<= 1) {
        int t = __shfl_up(tv, off, 64);
        if (lane >= off) tv += t;
      }
      if (lane < 16) wtot[lane] = tv;
    }
    __syncthreads();
    int woff = (w == 0) ? 0 : wtot[w - 1];
    int total = wtot[15];
    int out = carry + woff + incl;
    if (i < n) { rowptr[i + 1] = out; cursor[i + 1] = out; }
    carry += total;
    __syncthreads();
  }
}

__global__ void k_scatter_e(const int* __restrict__ ei, int* __restrict__ cursor,
                            int* __restrict__ col, int E) {
  int i = blockIdx.x * blockDim.x + threadIdx.x;
  if (i < E) {
    int d = ei[E + i];
    int s = ei[i];
    int pos = atomicAdd(&cursor[d], 1);
    col[pos] = s;
  }
}

__global__ void k_scatter_n(const int* __restrict__ cluster, int* __restrict__ cursor,
                            int* __restrict__ col, int N) {
  int i = blockIdx.x * blockDim.x + threadIdx.x;
  if (i < N) {
    int c = cluster[i];
    int pos = atomicAdd(&cursor[c], 1);
    col[pos] = i;
  }
}

// ---------- weight prep: transpose + f16 hi/lo split ----------
// w1 (CIN,64) row-major -> w1t[c*CIN + k]; w2 (64,CIN) row-major -> w2t[j*64 + c]
template <int CIN>
__global__ void k_prep(const float* __restrict__ w1, const float* __restrict__ w2,
                       f16_t* __restrict__ w1t_hi, f16_t* __restrict__ w1t_lo,
                       f16_t* __restrict__ w2t_hi, f16_t* __restrict__ w2t_lo) {
  int i = blockIdx.x * blockDim.x + threadIdx.x;
  const int n1 = CIN * 64;
  if (i < n1) {
    int k = i >> 6, c = i & 63;
    float v = w1[i];
    f16_t hi = (f16_t)v;
    w1t_hi[(size_t)c * CIN + k] = hi;
    w1t_lo[(size_t)c * CIN + k] = (f16_t)(v - (float)hi);
  } else if (i < 2 * n1) {
    int i2 = i - n1;
    int c = i2 / CIN, j = i2 & (CIN - 1);
    float v = w2[i2];
    f16_t hi = (f16_t)v;
    w2t_hi[(size_t)j * 64 + c] = hi;
    w2t_lo[(size_t)j * 64 + c] = (f16_t)(v - (float)hi);
  }
}

// ---------- MFMA MLP v3: LDS-staged fragments (m97-style chunked K-loop) ----------
// block = 256 threads = 4 waves, 64 nodes (wave w owns nodes blk*64+w*16 .. +16).
// All global traffic is cooperative + coalesced; fragments are read from LDS in
// fragment-major layout (lane-contiguous ds_read_b128, zero conflicts).
// A-frag: A[m=lane&15][k=(lane>>4)*8+j]; D: row=(lane>>4)*4+reg, col=lane&15.
template <int CIN, typename TIN>
__global__ __launch_bounds__(256) void k_mlp(const TIN* __restrict__ xin,
                                             const f16_t* __restrict__ w1t_hi, const f16_t* __restrict__ w1t_lo,
                                             const float* __restrict__ b1, const float* __restrict__ g,
                                             const float* __restrict__ be,
                                             const f16_t* __restrict__ w2t_hi, const f16_t* __restrict__ w2t_lo,
                                             const float* __restrict__ b2,
                                             ushort_t* __restrict__ xout, int N) {
  constexpr int KC = CIN / 64;  // 64-wide chunks for GEMM1-K and GEMM2-J
  __shared__ __align__(16) f16_t sB[2][4096];  // weight chunk frags [hi/lo], 16 KB
  __shared__ __align__(16) f16_t sX[2][4096];  // X chunk frags [hi/lo(layer0)], 16 KB
  __shared__ __align__(16) f16_t sH[2][4096];  // H frags [hi/lo], per-wave regions, 16 KB

  const int tid = threadIdx.x;
  const int wave = tid >> 6, lane = tid & 63;
  const int b = lane & 15, q = lane >> 4;
  const int nb = blockIdx.x * 64;
  const int nbW = nb + wave * 16;

  f32x4 acc1[4] = {};

  // ================= phase 1: H = X @ W1 =================
  for (int kc = 0; kc < KC; kc++) {
    __syncthreads();
    // ---- stage W1 chunk (cols 0..63, k in [kc*64, kc*64+64)), frag-major ----
#pragma unroll
    for (int half = 0; half < 2; half++) {
      int i = tid * 8 + half * 2048;
      int c = i >> 6, kk = i & 63;
      int t = c >> 4, bb = c & 15, kt = kk >> 5, qq = (kk >> 3) & 3;
      int dst = ((t * 2 + kt) * 64 + qq * 16 + bb) * 8;
      size_t src = (size_t)c * CIN + kc * 64 + kk;
      *reinterpret_cast<f16x8*>(&sB[0][dst]) = *reinterpret_cast<const f16x8*>(&w1t_hi[src]);
      *reinterpret_cast<f16x8*>(&sB[1][dst]) = *reinterpret_cast<const f16x8*>(&w1t_lo[src]);
    }
    // ---- stage X chunk (64 nodes, same k range), frag-major ----
#pragma unroll
    for (int half = 0; half < 2; half++) {
      int i = tid * 8 + half * 2048;
      int n = i >> 6, kk = i & 63;
      int w = n >> 4, bb = n & 15, kt = kk >> 5, qq = (kk >> 3) & 3;
      int dst = ((w * 2 + kt) * 64 + qq * 16 + bb) * 8;
      int gn = nb + n;
      if (gn >= N) gn = N - 1;
      if constexpr (sizeof(TIN) == 4) {
        float f[8];
        *reinterpret_cast<float4*>(&f[0]) = *reinterpret_cast<const float4*>(&xin[(size_t)gn * CIN + kc * 64 + kk]);
        *reinterpret_cast<float4*>(&f[4]) = *reinterpret_cast<const float4*>(&xin[(size_t)gn * CIN + kc * 64 + kk + 4]);
        f16x8 vh, vl;
#pragma unroll
        for (int j = 0; j < 8; j++) {
          f16_t hi = (f16_t)f[j];
          vh[j] = hi;
          vl[j] = (f16_t)(f[j] - (float)hi);
        }
        *reinterpret_cast<f16x8*>(&sX[0][dst]) = vh;
        *reinterpret_cast<f16x8*>(&sX[1][dst]) = vl;
      } else {
        *reinterpret_cast<f16x8*>(&sX[0][dst]) =
            *reinterpret_cast<const f16x8*>(&xin[(size_t)gn * CIN + kc * 64 + kk]);
      }
    }
    __syncthreads();
    // ---- compute: 2 kt-steps x 4 col-tiles ----
#pragma unroll
    for (int kt = 0; kt < 2; kt++) {
      f16x8 a = *reinterpret_cast<const f16x8*>(&sX[0][((wave * 2 + kt) * 64 + lane) * 8]);
      f16x8 al;
      if constexpr (sizeof(TIN) == 4)
        al = *reinterpret_cast<const f16x8*>(&sX[1][((wave * 2 + kt) * 64 + lane) * 8]);
#pragma unroll
      for (int t = 0; t < 4; t++) {
        f16x8 bh = *reinterpret_cast<const f16x8*>(&sB[0][((t * 2 + kt) * 64 + lane) * 8]);
        f16x8 bl = *reinterpret_cast<const f16x8*>(&sB[1][((t * 2 + kt) * 64 + lane) * 8]);
        acc1[t] = __builtin_amdgcn_mfma_f32_16x16x32_f16(a, bh, acc1[t], 0, 0, 0);
        acc1[t] = __builtin_amdgcn_mfma_f32_16x16x32_f16(a, bl, acc1[t], 0, 0, 0);
        if constexpr (sizeof(TIN) == 4)
          acc1[t] = __builtin_amdgcn_mfma_f32_16x16x32_f16(al, bh, acc1[t], 0, 0, 0);
      }
    }
  }

  // ---- + b1, LayerNorm(64), *g + be, ReLU (fp32, shfl butterflies) ----
  float b1v[4], gv[4], bev[4];
#pragma unroll
  for (int t = 0; t < 4; t++) {
    b1v[t] = b1[t * 16 + b];
    gv[t] = g[t * 16 + b];
    bev[t] = be[t * 16 + b];
  }
#pragma unroll
  for (int t = 0; t < 4; t++)
#pragma unroll
    for (int r = 0; r < 4; r++) acc1[t][r] += b1v[t];

  float mu[4], vv[4], rs[4];
#pragma unroll
  for (int r = 0; r < 4; r++) mu[r] = acc1[0][r] + acc1[1][r] + acc1[2][r] + acc1[3][r];
#pragma unroll
  for (int m = 1; m < 16; m <<= 1) {
#pragma unroll
    for (int r = 0; r < 4; r++) mu[r] += __shfl_xor(mu[r], m, 64);
  }
#pragma unroll
  for (int r = 0; r < 4; r++) mu[r] *= (1.f / 64.f);
#pragma unroll
  for (int r = 0; r < 4; r++) {
    float d0 = acc1[0][r] - mu[r], d1 = acc1[1][r] - mu[r];
    float d2 = acc1[2][r] - mu[r], d3 = acc1[3][r] - mu[r];
    vv[r] = d0 * d0 + d1 * d1 + d2 * d2 + d3 * d3;
  }
#pragma unroll
  for (int m = 1; m < 16; m <<= 1) {
#pragma unroll
    for (int r = 0; r < 4; r++) vv[r] += __shfl_xor(vv[r], m, 64);
  }
#pragma unroll
  for (int r = 0; r < 4; r++) rs[r] = rsqrtf(vv[r] * (1.f / 64.f) + 1e-5f);

  // ---- H -> per-wave LDS frags (hi/lo), A-layout; no barrier needed ----
#pragma unroll
  for (int t = 0; t < 4; t++) {
    const int kt = t >> 1;
    const int qq = (t & 1) * 2 + (b >> 3);
    const int jj = b & 7;
#pragma unroll
    for (int r = 0; r < 4; r++) {
      float h = (acc1[t][r] - mu[r]) * rs[r] * gv[t] + bev[t];
      h = fmaxf(h, 0.f);
      f16_t hh = (f16_t)h;
      int m = q * 4 + r;
      int dst = ((wave * 2 + kt) * 64 + qq * 16 + m) * 8 + jj;
      sH[0][dst] = hh;
      sH[1][dst] = (f16_t)(h - (float)hh);
    }
  }

  f16x8 ahi[2], alo[2];
#pragma unroll
  for (int kt = 0; kt < 2; kt++) {
    ahi[kt] = *reinterpret_cast<const f16x8*>(&sH[0][((wave * 2 + kt) * 64 + lane) * 8]);
    alo[kt] = *reinterpret_cast<const f16x8*>(&sH[1][((wave * 2 + kt) * 64 + lane) * 8]);
  }

  // ================= phase 2: OUT = H @ W2 + b2 =================
  for (int jc = 0; jc < KC; jc++) {
    __syncthreads();
    // ---- stage W2 chunk (cols jc*64..+64, c 0..63), frag-major ----
#pragma unroll
    for (int half = 0; half < 2; half++) {
      int i = tid * 8 + half * 2048;
      int jjn = i >> 6, cc = i & 63;
      int t2 = jjn >> 4, bb = jjn & 15, kt = cc >> 5, qq = (cc >> 3) & 3;
      int dst = ((t2 * 2 + kt) * 64 + qq * 16 + bb) * 8;
      size_t src = (size_t)(jc * 64 + jjn) * 64 + cc;
      *reinterpret_cast<f16x8*>(&sB[0][dst]) = *reinterpret_cast<const f16x8*>(&w2t_hi[src]);
      *reinterpret_cast<f16x8*>(&sB[1][dst]) = *reinterpret_cast<const f16x8*>(&w2t_lo[src]);
    }
    __syncthreads();
#pragma unroll
    for (int t2 = 0; t2 < 4; t2++) {
      f32x4 acc = {};
#pragma unroll
      for (int kt = 0; kt < 2; kt++) {
        f16x8 bh = *reinterpret_cast<const f16x8*>(&sB[0][((t2 * 2 + kt) * 64 + lane) * 8]);
        f16x8 bl = *reinterpret_cast<const f16x8*>(&sB[1][((t2 * 2 + kt) * 64 + lane) * 8]);
        acc = __builtin_amdgcn_mfma_f32_16x16x32_f16(ahi[kt], bh, acc, 0, 0, 0);
        acc = __builtin_amdgcn_mfma_f32_16x16x32_f16(ahi[kt], bl, acc, 0, 0, 0);
        acc = __builtin_amdgcn_mfma_f32_16x16x32_f16(alo[kt], bh, acc, 0, 0, 0);
      }
      int col = jc * 64 + t2 * 16 + b;
      float b2v = b2[col];
#pragma unroll
      for (int r = 0; r < 4; r++) {
        int node = nbW + q * 4 + r;
        if (node < N) {
          __half hv = __float2half_rn(acc[r] + b2v);
          xout[(size_t)node * (2 * CIN) + col] = *reinterpret_cast<ushort_t*>(&hv);
        }
      }
    }
  }
}

// ---------- scatter-max as CSR gather-max (16 B/lane, UNR-deep MLP) ----------
template <int CIN, int UNR>
__global__ __launch_bounds__(256) void k_agg(ushort_t* __restrict__ xb, const int* __restrict__ rowptr,
                                             const int* __restrict__ col, int N) {
  constexpr int LPR = CIN / 8;   // lanes per row (8 f16 = 16 B per lane)
  constexpr int RPW = 64 / LPR;  // rows per wave
  const int wid = (blockIdx.x * blockDim.x + threadIdx.x) >> 6;
  const int lane = threadIdx.x & 63;
  const int sub = lane / LPR;
  const int ll = lane % LPR;
  const int node = wid * RPW + sub;
  if (node >= N) return;
  const int beg = rowptr[node], end = rowptr[node + 1];
  float v[8];
#pragma unroll
  for (int p = 0; p < 8; p++) v[p] = -INFINITY;
  for (int e = beg; e < end; e += UNR) {
    int idx[UNR];
#pragma unroll
    for (int u = 0; u < UNR; u++) { int t = e + u; idx[u] = col[t < end ? t : e]; }
    uint4 r[UNR];
#pragma unroll
    for (int u = 0; u < UNR; u++)
      r[u] = *reinterpret_cast<const uint4*>(xb + (size_t)idx[u] * (2 * CIN) + ll * 8);
#pragma unroll
    for (int u = 0; u < UNR; u++) {
      float2 f0 = h2f2(r[u].x), f1 = h2f2(r[u].y), f2 = h2f2(r[u].z), f3 = h2f2(r[u].w);
      v[0] = fmaxf(v[0], f0.x); v[1] = fmaxf(v[1], f0.y);
      v[2] = fmaxf(v[2], f1.x); v[3] = fmaxf(v[3], f1.y);
      v[4] = fmaxf(v[4], f2.x); v[5] = fmaxf(v[5], f2.y);
      v[6] = fmaxf(v[6], f3.x); v[7] = fmaxf(v[7], f3.y);
    }
  }
  if (beg == end) {
#pragma unroll
    for (int p = 0; p < 8; p++) v[p] = 0.f;
  }
  *reinterpret_cast<uint4*>(xb + (size_t)node * (2 * CIN) + CIN + ll * 8) =
      make_uint4(f2h2(v[0], v[1]), f2h2(v[2], v[3]), f2h2(v[4], v[5]), f2h2(v[6], v[7]));
}

// ---------- cluster max-pool: wave per cluster, 512 f16 channels, x4 unroll ----------
__global__ __launch_bounds__(256) void k_pool(const ushort_t* __restrict__ x3, const int* __restrict__ rowptr,
                                              const int* __restrict__ col, float* __restrict__ pooled, int NC) {
  const int wid = (blockIdx.x * blockDim.x + threadIdx.x) >> 6;
  const int lane = threadIdx.x & 63;
  if (wid >= NC) return;
  const int beg = rowptr[wid], end = rowptr[wid + 1];
  float v[8];
#pragma unroll
  for (int p = 0; p < 8; p++) v[p] = -INFINITY;
  for (int e = beg; e < end; e += 4) {
    int idx[4];
#pragma unroll
    for (int u = 0; u < 4; u++) { int t = e + u; idx[u] = col[t < end ? t : e]; }
    uint4 r[4];
#pragma unroll
    for (int u = 0; u < 4; u++)
      r[u] = *reinterpret_cast<const uint4*>(x3 + (size_t)idx[u] * 512 + lane * 8);
#pragma unroll
    for (int u = 0; u < 4; u++) {
      float2 f0 = h2f2(r[u].x), f1 = h2f2(r[u].y), f2 = h2f2(r[u].z), f3 = h2f2(r[u].w);
      v[0] = fmaxf(v[0], f0.x); v[1] = fmaxf(v[1], f0.y);
      v[2] = fmaxf(v[2], f1.x); v[3] = fmaxf(v[3], f1.y);
      v[4] = fmaxf(v[4], f2.x); v[5] = fmaxf(v[5], f2.y);
      v[6] = fmaxf(v[6], f3.x); v[7] = fmaxf(v[7], f3.y);
    }
  }
  if (beg == end) {
#pragma unroll
    for (int p = 0; p < 8; p++) v[p] = 0.f;
  }
  float4* o = reinterpret_cast<float4*>(pooled + (size_t)wid * 512 + lane * 8);
  o[0] = make_float4(v[0], v[1], v[2], v[3]);
  o[1] = make_float4(v[4], v[5], v[6], v[7]);
}

// ---------- per-column sum of squares ----------
__global__ __launch_bounds__(256) void k_norm(const float* __restrict__ pooled, float* __restrict__ normsq, int NC) {
  const int c0 = threadIdx.x;
  const int c1 = threadIdx.x + 256;
  const int rows = (NC + gridDim.x - 1) / gridDim.x;
  float s0 = 0.f, s1 = 0.f;
  for (int rr = 0; rr < rows; rr++) {
    int r = blockIdx.x * rows + rr;
    if (r < NC) {
      float v0 = pooled[(size_t)r * 512 + c0];
      float v1 = pooled[(size_t)r * 512 + c1];
      s0 = fmaf(v0, v0, s0);
      s1 = fmaf(v1, v1, s1);
    }
  }
  atomicAdd(&normsq[c0], s0);
  atomicAdd(&normsq[c1], s1);
}

__global__ void k_final(const float* __restrict__ pooled, const float* __restrict__ normsq,
                        float* __restrict__ out, int n) {
  int i = blockIdx.x * blockDim.x + threadIdx.x;
  if (i >= n) return;
  int c = i & 511;
  out[i] = pooled[i] * rsqrtf(normsq[c]);
}

// ---------- launch ----------
extern "C" void kernel_launch(void* const* d_in, const int* in_sizes, int n_in,
                              void* d_out, int out_size, void* d_ws, size_t ws_size,
                              hipStream_t stream) {
  const int N = in_sizes[0] / 64;
  const int E = in_sizes[1] / 2;
  const int NC = out_size / 512;

  const float* x0 = (const float*)d_in[0];
  const int* ei = (const int*)d_in[1];
  const int* cluster = (const int*)d_in[2];

  const float* W[18];
  for (int k = 0; k < 18; k++) W[k] = (const float*)d_in[5 + k];

  char* p = (char*)d_ws;
  auto alloc = [&](size_t bytes) -> void* {
    void* r = (void*)p;
    p += (bytes + 255) & ~(size_t)255;
    return r;
  };
  ushort_t* x1h = (ushort_t*)alloc((size_t)N * 128 * 2);
  ushort_t* x2h = (ushort_t*)alloc((size_t)N * 256 * 2);
  ushort_t* x3h = (ushort_t*)alloc((size_t)N * 512 * 2);
  float* pooled = (float*)alloc((size_t)NC * 512 * 4);
  float* normsq = (float*)alloc((size_t)512 * 4);
  int* degE     = (int*)alloc((size_t)N * 4);
  int* rowptrE  = (int*)alloc((size_t)(N + 1) * 4);
  int* cursorE  = (int*)alloc((size_t)(N + 1) * 4);
  int* colE     = (int*)alloc((size_t)E * 4);
  int* degC     = (int*)alloc((size_t)NC * 4);
  int* rowptrC  = (int*)alloc((size_t)(NC + 1) * 4);
  int* cursorC  = (int*)alloc((size_t)(NC + 1) * 4);
  int* colC     = (int*)alloc((size_t)N * 4);
  // f16 hi/lo transposed weights per layer
  f16_t* wt[3][4];
  for (int L = 0; L < 3; L++) {
    int cin = 64 << L;
    for (int j = 0; j < 4; j++) wt[L][j] = (f16_t*)alloc((size_t)cin * 64 * 2);
  }

  hipMemsetAsync(degE, 0, (size_t)N * 4, stream);
  hipMemsetAsync(degC, 0, (size_t)NC * 4, stream);
  hipMemsetAsync(normsq, 0, (size_t)512 * 4, stream);

  // weight prep
  k_prep<64><<<(2 * 64 * 64 + 255) / 256, 256, 0, stream>>>(W[0], W[4], wt[0][0], wt[0][1], wt[0][2], wt[0][3]);
  k_prep<128><<<(2 * 128 * 64 + 255) / 256, 256, 0, stream>>>(W[6], W[10], wt[1][0], wt[1][1], wt[1][2], wt[1][3]);
  k_prep<256><<<(2 * 256 * 64 + 255) / 256, 256, 0, stream>>>(W[12], W[16], wt[2][0], wt[2][1], wt[2][2], wt[2][3]);

  // edge CSR (grouped by dst)
  k_hist<<<(E + 255) / 256, 256, 0, stream>>>(ei + E, degE, E);
  k_scan<<<1, 1024, 0, stream>>>(degE, rowptrE, cursorE, N);
  k_scatter_e<<<(E + 255) / 256, 256, 0, stream>>>(ei, cursorE, colE, E);

  // cluster CSR
  k_hist<<<(N + 255) / 256, 256, 0, stream>>>(cluster, degC, N);
  k_scan<<<1, 1024, 0, stream>>>(degC, rowptrC, cursorC, NC);
  k_scatter_n<<<(N + 255) / 256, 256, 0, stream>>>(cluster, cursorC, colC, N);

  const int nblk = (N + 63) / 64;
  // layer 0: cin=64 (fp32 input, X split hi/lo); agg RPW=8
  k_mlp<64, float><<<nblk, 256, 0, stream>>>(x0, wt[0][0], wt[0][1], W[1], W[2], W[3],
                                             wt[0][2], wt[0][3], W[5], x1h, N);
  { int waves = (N + 7) / 8; k_agg<64, 2><<<(waves * 64 + 255) / 256, 256, 0, stream>>>(x1h, rowptrE, colE, N); }
  // layer 1: cin=128; agg RPW=4
  k_mlp<128, ushort_t><<<nblk, 256, 0, stream>>>(x1h, wt[1][0], wt[1][1], W[7], W[8], W[9],
                                                 wt[1][2], wt[1][3], W[11], x2h, N);
  { int waves = (N + 3) / 4; k_agg<128, 4><<<(waves * 64 + 255) / 256, 256, 0, stream>>>(x2h, rowptrE, colE, N); }
  // layer 2: cin=256; agg RPW=2
  k_mlp<256, ushort_t><<<nblk, 256, 0, stream>>>(x2h, wt[2][0], wt[2][1], W[13], W[14], W[15],
                                                 wt[2][2], wt[2][3], W[17], x3h, N);
  { int waves = (N + 1) / 2; k_agg<256, 4><<<(waves * 64 + 255) / 256, 256, 0, stream>>>(x3h, rowptrE, colE, N); }

  // cluster max-pool + column L2 normalize
  k_pool<<<(NC * 64 + 255) / 256, 256, 0, stream>>>(x3h, rowptrC, colC, pooled, NC);
  k_norm<<<128, 256, 0, stream>>>(pooled, normsq, NC);
  k_final<<<(NC * 512 + 255) / 256, 256, 0, stream>>>(pooled, normsq, (float*)d_out, NC * 512);
}

// Round 8
// 455.202 us; speedup vs baseline: 1.7484x; 1.0208x over previous
//
#include <hip/hip_runtime.h>
#include <hip/hip_fp16.h>

typedef unsigned short ushort_t;
typedef unsigned int uint_t;
typedef _Float16 f16_t;
typedef __attribute__((ext_vector_type(8))) _Float16 f16x8;
typedef __attribute__((ext_vector_type(4))) float f32x4;

__device__ __forceinline__ float2 h2f2(uint_t u) {
  __half2 h = *reinterpret_cast<__half2*>(&u);
  return __half22float2(h);
}
__device__ __forceinline__ uint_t f2h2(float a, float b) {
  __half2 h = __floats2half2_rn(a, b);
  return *reinterpret_cast<uint_t*>(&h);
}

// ---------- CSR construction ----------

__global__ void k_hist(const int* __restrict__ idx, int* __restrict__ deg, int n) {
  int i = blockIdx.x * blockDim.x + threadIdx.x;
  if (i < n) atomicAdd(&deg[idx[i]], 1);
}

// hierarchical scan, pass 1: per-block (1024) inclusive scan -> rowptr[i+1]; block total -> blksum
__global__ __launch_bounds__(1024) void k_scan1(const int* __restrict__ deg, int* __restrict__ rowptr,
                                                int* __restrict__ blksum, int n) {
  __shared__ int wtot[16];
  const int tid = threadIdx.x, lane = tid & 63, w = tid >> 6;
  const int i = blockIdx.x * 1024 + tid;
  int v = (i < n) ? deg[i] : 0;
  int incl = v;
#pragma unroll
  for (int off = 1; off < 64; off <<= 1) {
    int t = __shfl_up(incl, off, 64);
    if (lane >= off) incl += t;
  }
  if (lane == 63) wtot[w] = incl;
  __syncthreads();
  if (w == 0) {
    int tv = (lane < 16) ? wtot[lane] : 0;
#pragma unroll
    for (int off = 1; off < 16; off <<= 1) {
      int t = __shfl_up(tv, off, 64);
      if (lane >= off) tv += t;
    }
    if (lane < 16) wtot[lane] = tv;
  }
  __syncthreads();
  int out = (w ? wtot[w - 1] : 0) + incl;
  if (i < n) rowptr[i + 1] = out;
  if (tid == 1023) blksum[blockIdx.x] = out;
}

// pass 2: single wave exclusive-scans block sums in place (nb <= 64)
__global__ __launch_bounds__(64) void k_scan2(int* __restrict__ blksum, int nb) {
  const int lane = threadIdx.x;
  int v = (lane < nb) ? blksum[lane] : 0;
  int incl = v;
#pragma unroll
  for (int off = 1; off < 64; off <<= 1) {
    int t = __shfl_up(incl, off, 64);
    if (lane >= off) incl += t;
  }
  if (lane < nb) blksum[lane] = incl - v;
}

// pass 3: add block offsets; mirror into cursor; set element 0
__global__ __launch_bounds__(1024) void k_scan3(int* __restrict__ rowptr, int* __restrict__ cursor,
                                                const int* __restrict__ blkoff, int n) {
  const int i = blockIdx.x * 1024 + threadIdx.x;
  if (i == 0) { rowptr[0] = 0; cursor[0] = 0; }
  if (i < n) {
    int v = rowptr[i + 1] + blkoff[blockIdx.x];
    rowptr[i + 1] = v;
    cursor[i + 1] = v;
  }
}

// scatter with atomicExch for the col write: device-scope atomics resolve memory-side
// (single owner), avoiding the 16x per-XCD dirty-line write amplification of plain stores.
__global__ void k_scatter_e(const int* __restrict__ ei, int* __restrict__ cursor,
                            int* __restrict__ col, int E) {
  int i = blockIdx.x * blockDim.x + threadIdx.x;
  if (i < E) {
    int d = ei[E + i];
    int s = ei[i];
    int pos = atomicAdd(&cursor[d], 1);
    atomicExch(&col[pos], s);
  }
}

__global__ void k_scatter_n(const int* __restrict__ cluster, int* __restrict__ cursor,
                            int* __restrict__ col, int N) {
  int i = blockIdx.x * blockDim.x + threadIdx.x;
  if (i < N) {
    int c = cluster[i];
    int pos = atomicAdd(&cursor[c], 1);
    atomicExch(&col[pos], i);
  }
}

// ---------- weight prep: transpose + f16 hi/lo split ----------
template <int CIN>
__global__ void k_prep(const float* __restrict__ w1, const float* __restrict__ w2,
                       f16_t* __restrict__ w1t_hi, f16_t* __restrict__ w1t_lo,
                       f16_t* __restrict__ w2t_hi, f16_t* __restrict__ w2t_lo) {
  int i = blockIdx.x * blockDim.x + threadIdx.x;
  const int n1 = CIN * 64;
  if (i < n1) {
    int k = i >> 6, c = i & 63;
    float v = w1[i];
    f16_t hi = (f16_t)v;
    w1t_hi[(size_t)c * CIN + k] = hi;
    w1t_lo[(size_t)c * CIN + k] = (f16_t)(v - (float)hi);
  } else if (i < 2 * n1) {
    int i2 = i - n1;
    int c = i2 / CIN, j = i2 & (CIN - 1);
    float v = w2[i2];
    f16_t hi = (f16_t)v;
    w2t_hi[(size_t)j * 64 + c] = hi;
    w2t_lo[(size_t)j * 64 + c] = (f16_t)(v - (float)hi);
  }
}

// ---------- MFMA MLP v3: LDS-staged fragments ----------
template <int CIN, typename TIN>
__global__ __launch_bounds__(256) void k_mlp(const TIN* __restrict__ xin,
                                             const f16_t* __restrict__ w1t_hi, const f16_t* __restrict__ w1t_lo,
                                             const float* __restrict__ b1, const float* __restrict__ g,
                                             const float* __restrict__ be,
                                             const f16_t* __restrict__ w2t_hi, const f16_t* __restrict__ w2t_lo,
                                             const float* __restrict__ b2,
                                             ushort_t* __restrict__ xout, int N) {
  constexpr int KC = CIN / 64;
  __shared__ __align__(16) f16_t sB[2][4096];
  __shared__ __align__(16) f16_t sX[2][4096];
  __shared__ __align__(16) f16_t sH[2][4096];

  const int tid = threadIdx.x;
  const int wave = tid >> 6, lane = tid & 63;
  const int b = lane & 15, q = lane >> 4;
  const int nb = blockIdx.x * 64;
  const int nbW = nb + wave * 16;

  f32x4 acc1[4] = {};

  // ================= phase 1: H = X @ W1 =================
  for (int kc = 0; kc < KC; kc++) {
    __syncthreads();
#pragma unroll
    for (int half = 0; half < 2; half++) {
      int i = tid * 8 + half * 2048;
      int c = i >> 6, kk = i & 63;
      int t = c >> 4, bb = c & 15, kt = kk >> 5, qq = (kk >> 3) & 3;
      int dst = ((t * 2 + kt) * 64 + qq * 16 + bb) * 8;
      size_t src = (size_t)c * CIN + kc * 64 + kk;
      *reinterpret_cast<f16x8*>(&sB[0][dst]) = *reinterpret_cast<const f16x8*>(&w1t_hi[src]);
      *reinterpret_cast<f16x8*>(&sB[1][dst]) = *reinterpret_cast<const f16x8*>(&w1t_lo[src]);
    }
#pragma unroll
    for (int half = 0; half < 2; half++) {
      int i = tid * 8 + half * 2048;
      int n = i >> 6, kk = i & 63;
      int w = n >> 4, bb = n & 15, kt = kk >> 5, qq = (kk >> 3) & 3;
      int dst = ((w * 2 + kt) * 64 + qq * 16 + bb) * 8;
      int gn = nb + n;
      if (gn >= N) gn = N - 1;
      if constexpr (sizeof(TIN) == 4) {
        float f[8];
        *reinterpret_cast<float4*>(&f[0]) = *reinterpret_cast<const float4*>(&xin[(size_t)gn * CIN + kc * 64 + kk]);
        *reinterpret_cast<float4*>(&f[4]) = *reinterpret_cast<const float4*>(&xin[(size_t)gn * CIN + kc * 64 + kk + 4]);
        f16x8 vh, vl;
#pragma unroll
        for (int j = 0; j < 8; j++) {
          f16_t hi = (f16_t)f[j];
          vh[j] = hi;
          vl[j] = (f16_t)(f[j] - (float)hi);
        }
        *reinterpret_cast<f16x8*>(&sX[0][dst]) = vh;
        *reinterpret_cast<f16x8*>(&sX[1][dst]) = vl;
      } else {
        *reinterpret_cast<f16x8*>(&sX[0][dst]) =
            *reinterpret_cast<const f16x8*>(&xin[(size_t)gn * CIN + kc * 64 + kk]);
      }
    }
    __syncthreads();
#pragma unroll
    for (int kt = 0; kt < 2; kt++) {
      f16x8 a = *reinterpret_cast<const f16x8*>(&sX[0][((wave * 2 + kt) * 64 + lane) * 8]);
      f16x8 al;
      if constexpr (sizeof(TIN) == 4)
        al = *reinterpret_cast<const f16x8*>(&sX[1][((wave * 2 + kt) * 64 + lane) * 8]);
#pragma unroll
      for (int t = 0; t < 4; t++) {
        f16x8 bh = *reinterpret_cast<const f16x8*>(&sB[0][((t * 2 + kt) * 64 + lane) * 8]);
        f16x8 bl = *reinterpret_cast<const f16x8*>(&sB[1][((t * 2 + kt) * 64 + lane) * 8]);
        acc1[t] = __builtin_amdgcn_mfma_f32_16x16x32_f16(a, bh, acc1[t], 0, 0, 0);
        acc1[t] = __builtin_amdgcn_mfma_f32_16x16x32_f16(a, bl, acc1[t], 0, 0, 0);
        if constexpr (sizeof(TIN) == 4)
          acc1[t] = __builtin_amdgcn_mfma_f32_16x16x32_f16(al, bh, acc1[t], 0, 0, 0);
      }
    }
  }

  // ---- + b1, LayerNorm(64), *g + be, ReLU ----
  float b1v[4], gv[4], bev[4];
#pragma unroll
  for (int t = 0; t < 4; t++) {
    b1v[t] = b1[t * 16 + b];
    gv[t] = g[t * 16 + b];
    bev[t] = be[t * 16 + b];
  }
#pragma unroll
  for (int t = 0; t < 4; t++)
#pragma unroll
    for (int r = 0; r < 4; r++) acc1[t][r] += b1v[t];

  float mu[4], vv[4], rs[4];
#pragma unroll
  for (int r = 0; r < 4; r++) mu[r] = acc1[0][r] + acc1[1][r] + acc1[2][r] + acc1[3][r];
#pragma unroll
  for (int m = 1; m < 16; m <<= 1) {
#pragma unroll
    for (int r = 0; r < 4; r++) mu[r] += __shfl_xor(mu[r], m, 64);
  }
#pragma unroll
  for (int r = 0; r < 4; r++) mu[r] *= (1.f / 64.f);
#pragma unroll
  for (int r = 0; r < 4; r++) {
    float d0 = acc1[0][r] - mu[r], d1 = acc1[1][r] - mu[r];
    float d2 = acc1[2][r] - mu[r], d3 = acc1[3][r] - mu[r];
    vv[r] = d0 * d0 + d1 * d1 + d2 * d2 + d3 * d3;
  }
#pragma unroll
  for (int m = 1; m < 16; m <<= 1) {
#pragma unroll
    for (int r = 0; r < 4; r++) vv[r] += __shfl_xor(vv[r], m, 64);
  }
#pragma unroll
  for (int r = 0; r < 4; r++) rs[r] = rsqrtf(vv[r] * (1.f / 64.f) + 1e-5f);

  // ---- H -> per-wave LDS frags (hi/lo), A-layout; no barrier needed ----
#pragma unroll
  for (int t = 0; t < 4; t++) {
    const int kt = t >> 1;
    const int qq = (t & 1) * 2 + (b >> 3);
    const int jj = b & 7;
#pragma unroll
    for (int r = 0; r < 4; r++) {
      float h = (acc1[t][r] - mu[r]) * rs[r] * gv[t] + bev[t];
      h = fmaxf(h, 0.f);
      f16_t hh = (f16_t)h;
      int m = q * 4 + r;
      int dst = ((wave * 2 + kt) * 64 + qq * 16 + m) * 8 + jj;
      sH[0][dst] = hh;
      sH[1][dst] = (f16_t)(h - (float)hh);
    }
  }

  f16x8 ahi[2], alo[2];
#pragma unroll
  for (int kt = 0; kt < 2; kt++) {
    ahi[kt] = *reinterpret_cast<const f16x8*>(&sH[0][((wave * 2 + kt) * 64 + lane) * 8]);
    alo[kt] = *reinterpret_cast<const f16x8*>(&sH[1][((wave * 2 + kt) * 64 + lane) * 8]);
  }

  // ================= phase 2: OUT = H @ W2 + b2 =================
  for (int jc = 0; jc < KC; jc++) {
    __syncthreads();
#pragma unroll
    for (int half = 0; half < 2; half++) {
      int i = tid * 8 + half * 2048;
      int jjn = i >> 6, cc = i & 63;
      int t2 = jjn >> 4, bb = jjn & 15, kt = cc >> 5, qq = (cc >> 3) & 3;
      int dst = ((t2 * 2 + kt) * 64 + qq * 16 + bb) * 8;
      size_t src = (size_t)(jc * 64 + jjn) * 64 + cc;
      *reinterpret_cast<f16x8*>(&sB[0][dst]) = *reinterpret_cast<const f16x8*>(&w2t_hi[src]);
      *reinterpret_cast<f16x8*>(&sB[1][dst]) = *reinterpret_cast<const f16x8*>(&w2t_lo[src]);
    }
    __syncthreads();
#pragma unroll
    for (int t2 = 0; t2 < 4; t2++) {
      f32x4 acc = {};
#pragma unroll
      for (int kt = 0; kt < 2; kt++) {
        f16x8 bh = *reinterpret_cast<const f16x8*>(&sB[0][((t2 * 2 + kt) * 64 + lane) * 8]);
        f16x8 bl = *reinterpret_cast<const f16x8*>(&sB[1][((t2 * 2 + kt) * 64 + lane) * 8]);
        acc = __builtin_amdgcn_mfma_f32_16x16x32_f16(ahi[kt], bh, acc, 0, 0, 0);
        acc = __builtin_amdgcn_mfma_f32_16x16x32_f16(ahi[kt], bl, acc, 0, 0, 0);
        acc = __builtin_amdgcn_mfma_f32_16x16x32_f16(alo[kt], bh, acc, 0, 0, 0);
      }
      int col = jc * 64 + t2 * 16 + b;
      float b2v = b2[col];
#pragma unroll
      for (int r = 0; r < 4; r++) {
        int node = nbW + q * 4 + r;
        if (node < N) {
          __half hv = __float2half_rn(acc[r] + b2v);
          xout[(size_t)node * (2 * CIN) + col] = *reinterpret_cast<ushort_t*>(&hv);
        }
      }
    }
  }
}

// ---------- scatter-max as CSR gather-max (16 B/lane, UNR loads in flight/thread) ----------
template <int CIN, int UNR>
__global__ __launch_bounds__(256) void k_agg(ushort_t* __restrict__ xb, const int* __restrict__ rowptr,
                                             const int* __restrict__ col, int N) {
  constexpr int LPR = CIN / 8;
  constexpr int RPW = 64 / LPR;
  const int wid = (blockIdx.x * blockDim.x + threadIdx.x) >> 6;
  const int lane = threadIdx.x & 63;
  const int sub = lane / LPR;
  const int ll = lane % LPR;
  const int node = wid * RPW + sub;
  if (node >= N) return;
  const int beg = rowptr[node], end = rowptr[node + 1];
  float v[8];
#pragma unroll
  for (int p = 0; p < 8; p++) v[p] = -INFINITY;
  for (int e = beg; e < end; e += UNR) {
    int idx[UNR];
#pragma unroll
    for (int u = 0; u < UNR; u++) { int t = e + u; idx[u] = col[t < end ? t : e]; }
    uint4 r[UNR];
#pragma unroll
    for (int u = 0; u < UNR; u++)
      r[u] = *reinterpret_cast<const uint4*>(xb + (size_t)idx[u] * (2 * CIN) + ll * 8);
#pragma unroll
    for (int u = 0; u < UNR; u++) {
      float2 f0 = h2f2(r[u].x), f1 = h2f2(r[u].y), f2 = h2f2(r[u].z), f3 = h2f2(r[u].w);
      v[0] = fmaxf(v[0], f0.x); v[1] = fmaxf(v[1], f0.y);
      v[2] = fmaxf(v[2], f1.x); v[3] = fmaxf(v[3], f1.y);
      v[4] = fmaxf(v[4], f2.x); v[5] = fmaxf(v[5], f2.y);
      v[6] = fmaxf(v[6], f3.x); v[7] = fmaxf(v[7], f3.y);
    }
  }
  if (beg == end) {
#pragma unroll
    for (int p = 0; p < 8; p++) v[p] = 0.f;
  }
  *reinterpret_cast<uint4*>(xb + (size_t)node * (2 * CIN) + CIN + ll * 8) =
      make_uint4(f2h2(v[0], v[1]), f2h2(v[2], v[3]), f2h2(v[4], v[5]), f2h2(v[6], v[7]));
}

// ---------- cluster max-pool: wave per cluster, 512 f16 channels, x4 unroll ----------
__global__ __launch_bounds__(256) void k_pool(const ushort_t* __restrict__ x3, const int* __restrict__ rowptr,
                                              const int* __restrict__ col, float* __restrict__ pooled, int NC) {
  const int wid = (blockIdx.x * blockDim.x + threadIdx.x) >> 6;
  const int lane = threadIdx.x & 63;
  if (wid >= NC) return;
  const int beg = rowptr[wid], end = rowptr[wid + 1];
  float v[8];
#pragma unroll
  for (int p = 0; p < 8; p++) v[p] = -INFINITY;
  for (int e = beg; e < end; e += 4) {
    int idx[4];
#pragma unroll
    for (int u = 0; u < 4; u++) { int t = e + u; idx[u] = col[t < end ? t : e]; }
    uint4 r[4];
#pragma unroll
    for (int u = 0; u < 4; u++)
      r[u] = *reinterpret_cast<const uint4*>(x3 + (size_t)idx[u] * 512 + lane * 8);
#pragma unroll
    for (int u = 0; u < 4; u++) {
      float2 f0 = h2f2(r[u].x), f1 = h2f2(r[u].y), f2 = h2f2(r[u].z), f3 = h2f2(r[u].w);
      v[0] = fmaxf(v[0], f0.x); v[1] = fmaxf(v[1], f0.y);
      v[2] = fmaxf(v[2], f1.x); v[3] = fmaxf(v[3], f1.y);
      v[4] = fmaxf(v[4], f2.x); v[5] = fmaxf(v[5], f2.y);
      v[6] = fmaxf(v[6], f3.x); v[7] = fmaxf(v[7], f3.y);
    }
  }
  if (beg == end) {
#pragma unroll
    for (int p = 0; p < 8; p++) v[p] = 0.f;
  }
  float4* o = reinterpret_cast<float4*>(pooled + (size_t)wid * 512 + lane * 8);
  o[0] = make_float4(v[0], v[1], v[2], v[3]);
  o[1] = make_float4(v[4], v[5], v[6], v[7]);
}

// ---------- per-column sum of squares ----------
__global__ __launch_bounds__(256) void k_norm(const float* __restrict__ pooled, float* __restrict__ normsq, int NC) {
  const int c0 = threadIdx.x;
  const int c1 = threadIdx.x + 256;
  const int rows = (NC + gridDim.x - 1) / gridDim.x;
  float s0 = 0.f, s1 = 0.f;
  for (int rr = 0; rr < rows; rr++) {
    int r = blockIdx.x * rows + rr;
    if (r < NC) {
      float v0 = pooled[(size_t)r * 512 + c0];
      float v1 = pooled[(size_t)r * 512 + c1];
      s0 = fmaf(v0, v0, s0);
      s1 = fmaf(v1, v1, s1);
    }
  }
  atomicAdd(&normsq[c0], s0);
  atomicAdd(&normsq[c1], s1);
}

__global__ void k_final(const float* __restrict__ pooled, const float* __restrict__ normsq,
                        float* __restrict__ out, int n) {
  int i = blockIdx.x * blockDim.x + threadIdx.x;
  if (i >= n) return;
  int c = i & 511;
  out[i] = pooled[i] * rsqrtf(normsq[c]);
}

// ---------- launch ----------
extern "C" void kernel_launch(void* const* d_in, const int* in_sizes, int n_in,
                              void* d_out, int out_size, void* d_ws, size_t ws_size,
                              hipStream_t stream) {
  const int N = in_sizes[0] / 64;
  const int E = in_sizes[1] / 2;
  const int NC = out_size / 512;

  const float* x0 = (const float*)d_in[0];
  const int* ei = (const int*)d_in[1];
  const int* cluster = (const int*)d_in[2];

  const float* W[18];
  for (int k = 0; k < 18; k++) W[k] = (const float*)d_in[5 + k];

  char* p = (char*)d_ws;
  auto alloc = [&](size_t bytes) -> void* {
    void* r = (void*)p;
    p += (bytes + 255) & ~(size_t)255;
    return r;
  };
  ushort_t* x1h = (ushort_t*)alloc((size_t)N * 128 * 2);
  ushort_t* x2h = (ushort_t*)alloc((size_t)N * 256 * 2);
  ushort_t* x3h = (ushort_t*)alloc((size_t)N * 512 * 2);
  float* pooled = (float*)alloc((size_t)NC * 512 * 4);
  float* normsq = (float*)alloc((size_t)512 * 4);
  int* degE     = (int*)alloc((size_t)N * 4);
  int* rowptrE  = (int*)alloc((size_t)(N + 1) * 4);
  int* cursorE  = (int*)alloc((size_t)(N + 1) * 4);
  int* colE     = (int*)alloc((size_t)E * 4);
  int* degC     = (int*)alloc((size_t)NC * 4);
  int* rowptrC  = (int*)alloc((size_t)(NC + 1) * 4);
  int* cursorC  = (int*)alloc((size_t)(NC + 1) * 4);
  int* colC     = (int*)alloc((size_t)N * 4);
  int* blkE     = (int*)alloc(64 * 4);
  int* blkC     = (int*)alloc(64 * 4);
  // f16 hi/lo transposed weights per layer
  f16_t* wt[3][4];
  for (int L = 0; L < 3; L++) {
    int cin = 64 << L;
    for (int j = 0; j < 4; j++) wt[L][j] = (f16_t*)alloc((size_t)cin * 64 * 2);
  }

  hipMemsetAsync(degE, 0, (size_t)N * 4, stream);
  hipMemsetAsync(degC, 0, (size_t)NC * 4, stream);
  hipMemsetAsync(normsq, 0, (size_t)512 * 4, stream);

  // weight prep
  k_prep<64><<<(2 * 64 * 64 + 255) / 256, 256, 0, stream>>>(W[0], W[4], wt[0][0], wt[0][1], wt[0][2], wt[0][3]);
  k_prep<128><<<(2 * 128 * 64 + 255) / 256, 256, 0, stream>>>(W[6], W[10], wt[1][0], wt[1][1], wt[1][2], wt[1][3]);
  k_prep<256><<<(2 * 256 * 64 + 255) / 256, 256, 0, stream>>>(W[12], W[16], wt[2][0], wt[2][1], wt[2][2], wt[2][3]);

  const int nbE = (N + 1023) / 1024;
  const int nbC = (NC + 1023) / 1024;

  // edge CSR (grouped by dst)
  k_hist<<<(E + 255) / 256, 256, 0, stream>>>(ei + E, degE, E);
  k_scan1<<<nbE, 1024, 0, stream>>>(degE, rowptrE, blkE, N);
  k_scan2<<<1, 64, 0, stream>>>(blkE, nbE);
  k_scan3<<<nbE, 1024, 0, stream>>>(rowptrE, cursorE, blkE, N);
  k_scatter_e<<<(E + 255) / 256, 256, 0, stream>>>(ei, cursorE, colE, E);

  // cluster CSR
  k_hist<<<(N + 255) / 256, 256, 0, stream>>>(cluster, degC, N);
  k_scan1<<<nbC, 1024, 0, stream>>>(degC, rowptrC, blkC, NC);
  k_scan2<<<1, 64, 0, stream>>>(blkC, nbC);
  k_scan3<<<nbC, 1024, 0, stream>>>(rowptrC, cursorC, blkC, NC);
  k_scatter_n<<<(N + 255) / 256, 256, 0, stream>>>(cluster, cursorC, colC, N);

  const int nblk = (N + 63) / 64;
  // layer 0: cin=64 (fp32 input, X split hi/lo); agg RPW=8
  k_mlp<64, float><<<nblk, 256, 0, stream>>>(x0, wt[0][0], wt[0][1], W[1], W[2], W[3],
                                             wt[0][2], wt[0][3], W[5], x1h, N);
  { int waves = (N + 7) / 8; k_agg<64, 4><<<(waves * 64 + 255) / 256, 256, 0, stream>>>(x1h, rowptrE, colE, N); }
  // layer 1: cin=128; agg RPW=4
  k_mlp<128, ushort_t><<<nblk, 256, 0, stream>>>(x1h, wt[1][0], wt[1][1], W[7], W[8], W[9],
                                                 wt[1][2], wt[1][3], W[11], x2h, N);
  { int waves = (N + 3) / 4; k_agg<128, 8><<<(waves * 64 + 255) / 256, 256, 0, stream>>>(x2h, rowptrE, colE, N); }
  // layer 2: cin=256; agg RPW=2
  k_mlp<256, ushort_t><<<nblk, 256, 0, stream>>>(x2h, wt[2][0], wt[2][1], W[13], W[14], W[15],
                                                 wt[2][2], wt[2][3], W[17], x3h, N);
  { int waves = (N + 1) / 2; k_agg<256, 8><<<(waves * 64 + 255) / 256, 256, 0, stream>>>(x3h, rowptrE, colE, N); }

  // cluster max-pool + column L2 normalize
  k_pool<<<(NC * 64 + 255) / 256, 256, 0, stream>>>(x3h, rowptrC, colC, pooled, NC);
  k_norm<<<128, 256, 0, stream>>>(pooled, normsq, NC);
  k_final<<<(NC * 512 + 255) / 256, 256, 0, stream>>>(pooled, normsq, (float*)d_out, NC * 512);
}

// Round 9
// 447.402 us; speedup vs baseline: 1.7789x; 1.0174x over previous
//
#include <hip/hip_runtime.h>
#include <hip/hip_fp16.h>

typedef unsigned short ushort_t;
typedef unsigned int uint_t;
typedef _Float16 f16_t;
typedef __attribute__((ext_vector_type(8))) _Float16 f16x8;
typedef __attribute__((ext_vector_type(4))) float f32x4;

__device__ __forceinline__ float2 h2f2(uint_t u) {
  __half2 h = *reinterpret_cast<__half2*>(&u);
  return __half22float2(h);
}
__device__ __forceinline__ uint_t f2h2(float a, float b) {
  __half2 h = __floats2half2_rn(a, b);
  return *reinterpret_cast<uint_t*>(&h);
}

// ---------- CSR construction (no global atomics: LDS-privatized counting sort) ----------
// Blocks = nslice x NR. Block (s,r) histograms keys of slice s falling in bin-range r
// into LDS, then dumps counts to cnt[s][bin] (coalesced).
template <int RSIZE, int NR>
__global__ __launch_bounds__(256) void k_cnt(const int* __restrict__ key, int* __restrict__ cnt,
                                             int n, int slen) {
  __shared__ int h[RSIZE];
  const int s = blockIdx.x / NR, r = blockIdx.x % NR;
  const int base = r * RSIZE;
  for (int i = threadIdx.x; i < RSIZE; i += 256) h[i] = 0;
  __syncthreads();
  const int i0 = s * slen, i1 = min(n, i0 + slen);
  for (int i = i0 + threadIdx.x; i < i1; i += 256) {
    int d = key[i] - base;
    if ((unsigned)d < (unsigned)RSIZE) atomicAdd(&h[d], 1);
  }
  __syncthreads();
  const int NB = RSIZE * NR;
  for (int i = threadIdx.x; i < RSIZE; i += 256) cnt[(size_t)s * NB + base + i] = h[i];
}

// per-bin exclusive scan over slices: cnt[s][d] -> #keys==d in slices<s; deg[d] = total
__global__ void k_combine(int* __restrict__ cnt, int* __restrict__ deg, int nb, int nslice) {
  int d = blockIdx.x * 256 + threadIdx.x;
  if (d >= nb) return;
  int acc = 0;
  for (int s = 0; s < nslice; s++) {
    int c = cnt[(size_t)s * nb + d];
    cnt[(size_t)s * nb + d] = acc;
    acc += c;
  }
  deg[d] = acc;
}

// hierarchical scan, pass 1: per-block (1024) inclusive scan -> rowptr[i+1]; block total -> blksum
__global__ __launch_bounds__(1024) void k_scan1(const int* __restrict__ deg, int* __restrict__ rowptr,
                                                int* __restrict__ blksum, int n) {
  __shared__ int wtot[16];
  const int tid = threadIdx.x, lane = tid & 63, w = tid >> 6;
  const int i = blockIdx.x * 1024 + tid;
  int v = (i < n) ? deg[i] : 0;
  int incl = v;
#pragma unroll
  for (int off = 1; off < 64; off <<= 1) {
    int t = __shfl_up(incl, off, 64);
    if (lane >= off) incl += t;
  }
  if (lane == 63) wtot[w] = incl;
  __syncthreads();
  if (w == 0) {
    int tv = (lane < 16) ? wtot[lane] : 0;
#pragma unroll
    for (int off = 1; off < 16; off <<= 1) {
      int t = __shfl_up(tv, off, 64);
      if (lane >= off) tv += t;
    }
    if (lane < 16) wtot[lane] = tv;
  }
  __syncthreads();
  int out = (w ? wtot[w - 1] : 0) + incl;
  if (i < n) rowptr[i + 1] = out;
  if (tid == 1023) blksum[blockIdx.x] = out;
}

// pass 2: single wave exclusive-scans block sums in place (nb <= 64)
__global__ __launch_bounds__(64) void k_scan2(int* __restrict__ blksum, int nb) {
  const int lane = threadIdx.x;
  int v = (lane < nb) ? blksum[lane] : 0;
  int incl = v;
#pragma unroll
  for (int off = 1; off < 64; off <<= 1) {
    int t = __shfl_up(incl, off, 64);
    if (lane >= off) incl += t;
  }
  if (lane < nb) blksum[lane] = incl - v;
}

// pass 3: add block offsets; set element 0
__global__ __launch_bounds__(1024) void k_scan3(int* __restrict__ rowptr, const int* __restrict__ blkoff, int n) {
  const int i = blockIdx.x * 1024 + threadIdx.x;
  if (i == 0) rowptr[0] = 0;
  if (i < n) rowptr[i + 1] += blkoff[blockIdx.x];
}

// scatter pass: re-rank via fresh LDS histogram (rank order arbitrary — max is
// order-invariant), one plain store per key. Zero global atomics.
template <int RSIZE, int NR, bool IDENT>
__global__ __launch_bounds__(256) void k_scat(const int* __restrict__ key, const int* __restrict__ val,
                                              const int* __restrict__ rowptr, const int* __restrict__ cnt,
                                              int* __restrict__ col, int n, int slen) {
  __shared__ int h[RSIZE];
  const int s = blockIdx.x / NR, r = blockIdx.x % NR;
  const int base = r * RSIZE;
  for (int i = threadIdx.x; i < RSIZE; i += 256) h[i] = 0;
  __syncthreads();
  const int NB = RSIZE * NR;
  const int i0 = s * slen, i1 = min(n, i0 + slen);
  for (int i = i0 + threadIdx.x; i < i1; i += 256) {
    int d = key[i];
    int dr = d - base;
    if ((unsigned)dr < (unsigned)RSIZE) {
      int lr = atomicAdd(&h[dr], 1);
      int pos = rowptr[d] + cnt[(size_t)s * NB + d] + lr;
      col[pos] = IDENT ? i : val[i];
    }
  }
}

// ---------- weight prep: transpose + f16 hi/lo split ----------
template <int CIN>
__global__ void k_prep(const float* __restrict__ w1, const float* __restrict__ w2,
                       f16_t* __restrict__ w1t_hi, f16_t* __restrict__ w1t_lo,
                       f16_t* __restrict__ w2t_hi, f16_t* __restrict__ w2t_lo) {
  int i = blockIdx.x * blockDim.x + threadIdx.x;
  const int n1 = CIN * 64;
  if (i < n1) {
    int k = i >> 6, c = i & 63;
    float v = w1[i];
    f16_t hi = (f16_t)v;
    w1t_hi[(size_t)c * CIN + k] = hi;
    w1t_lo[(size_t)c * CIN + k] = (f16_t)(v - (float)hi);
  } else if (i < 2 * n1) {
    int i2 = i - n1;
    int c = i2 / CIN, j = i2 & (CIN - 1);
    float v = w2[i2];
    f16_t hi = (f16_t)v;
    w2t_hi[(size_t)j * 64 + c] = hi;
    w2t_lo[(size_t)j * 64 + c] = (f16_t)(v - (float)hi);
  }
}

// ---------- MFMA MLP v3: LDS-staged fragments ----------
template <int CIN, typename TIN>
__global__ __launch_bounds__(256) void k_mlp(const TIN* __restrict__ xin,
                                             const f16_t* __restrict__ w1t_hi, const f16_t* __restrict__ w1t_lo,
                                             const float* __restrict__ b1, const float* __restrict__ g,
                                             const float* __restrict__ be,
                                             const f16_t* __restrict__ w2t_hi, const f16_t* __restrict__ w2t_lo,
                                             const float* __restrict__ b2,
                                             ushort_t* __restrict__ xout, int N) {
  constexpr int KC = CIN / 64;
  __shared__ __align__(16) f16_t sB[2][4096];
  __shared__ __align__(16) f16_t sX[2][4096];
  __shared__ __align__(16) f16_t sH[2][4096];

  const int tid = threadIdx.x;
  const int wave = tid >> 6, lane = tid & 63;
  const int b = lane & 15, q = lane >> 4;
  const int nb = blockIdx.x * 64;
  const int nbW = nb + wave * 16;

  f32x4 acc1[4] = {};

  // ================= phase 1: H = X @ W1 =================
  for (int kc = 0; kc < KC; kc++) {
    __syncthreads();
#pragma unroll
    for (int half = 0; half < 2; half++) {
      int i = tid * 8 + half * 2048;
      int c = i >> 6, kk = i & 63;
      int t = c >> 4, bb = c & 15, kt = kk >> 5, qq = (kk >> 3) & 3;
      int dst = ((t * 2 + kt) * 64 + qq * 16 + bb) * 8;
      size_t src = (size_t)c * CIN + kc * 64 + kk;
      *reinterpret_cast<f16x8*>(&sB[0][dst]) = *reinterpret_cast<const f16x8*>(&w1t_hi[src]);
      *reinterpret_cast<f16x8*>(&sB[1][dst]) = *reinterpret_cast<const f16x8*>(&w1t_lo[src]);
    }
#pragma unroll
    for (int half = 0; half < 2; half++) {
      int i = tid * 8 + half * 2048;
      int n = i >> 6, kk = i & 63;
      int w = n >> 4, bb = n & 15, kt = kk >> 5, qq = (kk >> 3) & 3;
      int dst = ((w * 2 + kt) * 64 + qq * 16 + bb) * 8;
      int gn = nb + n;
      if (gn >= N) gn = N - 1;
      if constexpr (sizeof(TIN) == 4) {
        float f[8];
        *reinterpret_cast<float4*>(&f[0]) = *reinterpret_cast<const float4*>(&xin[(size_t)gn * CIN + kc * 64 + kk]);
        *reinterpret_cast<float4*>(&f[4]) = *reinterpret_cast<const float4*>(&xin[(size_t)gn * CIN + kc * 64 + kk + 4]);
        f16x8 vh, vl;
#pragma unroll
        for (int j = 0; j < 8; j++) {
          f16_t hi = (f16_t)f[j];
          vh[j] = hi;
          vl[j] = (f16_t)(f[j] - (float)hi);
        }
        *reinterpret_cast<f16x8*>(&sX[0][dst]) = vh;
        *reinterpret_cast<f16x8*>(&sX[1][dst]) = vl;
      } else {
        *reinterpret_cast<f16x8*>(&sX[0][dst]) =
            *reinterpret_cast<const f16x8*>(&xin[(size_t)gn * CIN + kc * 64 + kk]);
      }
    }
    __syncthreads();
#pragma unroll
    for (int kt = 0; kt < 2; kt++) {
      f16x8 a = *reinterpret_cast<const f16x8*>(&sX[0][((wave * 2 + kt) * 64 + lane) * 8]);
      f16x8 al;
      if constexpr (sizeof(TIN) == 4)
        al = *reinterpret_cast<const f16x8*>(&sX[1][((wave * 2 + kt) * 64 + lane) * 8]);
#pragma unroll
      for (int t = 0; t < 4; t++) {
        f16x8 bh = *reinterpret_cast<const f16x8*>(&sB[0][((t * 2 + kt) * 64 + lane) * 8]);
        f16x8 bl = *reinterpret_cast<const f16x8*>(&sB[1][((t * 2 + kt) * 64 + lane) * 8]);
        acc1[t] = __builtin_amdgcn_mfma_f32_16x16x32_f16(a, bh, acc1[t], 0, 0, 0);
        acc1[t] = __builtin_amdgcn_mfma_f32_16x16x32_f16(a, bl, acc1[t], 0, 0, 0);
        if constexpr (sizeof(TIN) == 4)
          acc1[t] = __builtin_amdgcn_mfma_f32_16x16x32_f16(al, bh, acc1[t], 0, 0, 0);
      }
    }
  }

  // ---- + b1, LayerNorm(64), *g + be, ReLU ----
  float b1v[4], gv[4], bev[4];
#pragma unroll
  for (int t = 0; t < 4; t++) {
    b1v[t] = b1[t * 16 + b];
    gv[t] = g[t * 16 + b];
    bev[t] = be[t * 16 + b];
  }
#pragma unroll
  for (int t = 0; t < 4; t++)
#pragma unroll
    for (int r = 0; r < 4; r++) acc1[t][r] += b1v[t];

  float mu[4], vv[4], rs[4];
#pragma unroll
  for (int r = 0; r < 4; r++) mu[r] = acc1[0][r] + acc1[1][r] + acc1[2][r] + acc1[3][r];
#pragma unroll
  for (int m = 1; m < 16; m <<= 1) {
#pragma unroll
    for (int r = 0; r < 4; r++) mu[r] += __shfl_xor(mu[r], m, 64);
  }
#pragma unroll
  for (int r = 0; r < 4; r++) mu[r] *= (1.f / 64.f);
#pragma unroll
  for (int r = 0; r < 4; r++) {
    float d0 = acc1[0][r] - mu[r], d1 = acc1[1][r] - mu[r];
    float d2 = acc1[2][r] - mu[r], d3 = acc1[3][r] - mu[r];
    vv[r] = d0 * d0 + d1 * d1 + d2 * d2 + d3 * d3;
  }
#pragma unroll
  for (int m = 1; m < 16; m <<= 1) {
#pragma unroll
    for (int r = 0; r < 4; r++) vv[r] += __shfl_xor(vv[r], m, 64);
  }
#pragma unroll
  for (int r = 0; r < 4; r++) rs[r] = rsqrtf(vv[r] * (1.f / 64.f) + 1e-5f);

  // ---- H -> per-wave LDS frags (hi/lo), A-layout; no barrier needed ----
#pragma unroll
  for (int t = 0; t < 4; t++) {
    const int kt = t >> 1;
    const int qq = (t & 1) * 2 + (b >> 3);
    const int jj = b & 7;
#pragma unroll
    for (int r = 0; r < 4; r++) {
      float h = (acc1[t][r] - mu[r]) * rs[r] * gv[t] + bev[t];
      h = fmaxf(h, 0.f);
      f16_t hh = (f16_t)h;
      int m = q * 4 + r;
      int dst = ((wave * 2 + kt) * 64 + qq * 16 + m) * 8 + jj;
      sH[0][dst] = hh;
      sH[1][dst] = (f16_t)(h - (float)hh);
    }
  }

  f16x8 ahi[2], alo[2];
#pragma unroll
  for (int kt = 0; kt < 2; kt++) {
    ahi[kt] = *reinterpret_cast<const f16x8*>(&sH[0][((wave * 2 + kt) * 64 + lane) * 8]);
    alo[kt] = *reinterpret_cast<const f16x8*>(&sH[1][((wave * 2 + kt) * 64 + lane) * 8]);
  }

  // ================= phase 2: OUT = H @ W2 + b2 =================
  for (int jc = 0; jc < KC; jc++) {
    __syncthreads();
#pragma unroll
    for (int half = 0; half < 2; half++) {
      int i = tid * 8 + half * 2048;
      int jjn = i >> 6, cc = i & 63;
      int t2 = jjn >> 4, bb = jjn & 15, kt = cc >> 5, qq = (cc >> 3) & 3;
      int dst = ((t2 * 2 + kt) * 64 + qq * 16 + bb) * 8;
      size_t src = (size_t)(jc * 64 + jjn) * 64 + cc;
      *reinterpret_cast<f16x8*>(&sB[0][dst]) = *reinterpret_cast<const f16x8*>(&w2t_hi[src]);
      *reinterpret_cast<f16x8*>(&sB[1][dst]) = *reinterpret_cast<const f16x8*>(&w2t_lo[src]);
    }
    __syncthreads();
#pragma unroll
    for (int t2 = 0; t2 < 4; t2++) {
      f32x4 acc = {};
#pragma unroll
      for (int kt = 0; kt < 2; kt++) {
        f16x8 bh = *reinterpret_cast<const f16x8*>(&sB[0][((t2 * 2 + kt) * 64 + lane) * 8]);
        f16x8 bl = *reinterpret_cast<const f16x8*>(&sB[1][((t2 * 2 + kt) * 64 + lane) * 8]);
        acc = __builtin_amdgcn_mfma_f32_16x16x32_f16(ahi[kt], bh, acc, 0, 0, 0);
        acc = __builtin_amdgcn_mfma_f32_16x16x32_f16(ahi[kt], bl, acc, 0, 0, 0);
        acc = __builtin_amdgcn_mfma_f32_16x16x32_f16(alo[kt], bh, acc, 0, 0, 0);
      }
      int col = jc * 64 + t2 * 16 + b;
      float b2v = b2[col];
#pragma unroll
      for (int r = 0; r < 4; r++) {
        int node = nbW + q * 4 + r;
        if (node < N) {
          __half hv = __float2half_rn(acc[r] + b2v);
          xout[(size_t)node * (2 * CIN) + col] = *reinterpret_cast<ushort_t*>(&hv);
        }
      }
    }
  }
}

// ---------- scatter-max as CSR gather-max (16 B/lane, UNR loads in flight/thread) ----------
template <int CIN, int UNR>
__global__ __launch_bounds__(256) void k_agg(ushort_t* __restrict__ xb, const int* __restrict__ rowptr,
                                             const int* __restrict__ col, int N) {
  constexpr int LPR = CIN / 8;
  constexpr int RPW = 64 / LPR;
  const int wid = (blockIdx.x * blockDim.x + threadIdx.x) >> 6;
  const int lane = threadIdx.x & 63;
  const int sub = lane / LPR;
  const int ll = lane % LPR;
  const int node = wid * RPW + sub;
  if (node >= N) return;
  const int beg = rowptr[node], end = rowptr[node + 1];
  float v[8];
#pragma unroll
  for (int p = 0; p < 8; p++) v[p] = -INFINITY;
  for (int e = beg; e < end; e += UNR) {
    int idx[UNR];
#pragma unroll
    for (int u = 0; u < UNR; u++) { int t = e + u; idx[u] = col[t < end ? t : e]; }
    uint4 r[UNR];
#pragma unroll
    for (int u = 0; u < UNR; u++)
      r[u] = *reinterpret_cast<const uint4*>(xb + (size_t)idx[u] * (2 * CIN) + ll * 8);
#pragma unroll
    for (int u = 0; u < UNR; u++) {
      float2 f0 = h2f2(r[u].x), f1 = h2f2(r[u].y), f2 = h2f2(r[u].z), f3 = h2f2(r[u].w);
      v[0] = fmaxf(v[0], f0.x); v[1] = fmaxf(v[1], f0.y);
      v[2] = fmaxf(v[2], f1.x); v[3] = fmaxf(v[3], f1.y);
      v[4] = fmaxf(v[4], f2.x); v[5] = fmaxf(v[5], f2.y);
      v[6] = fmaxf(v[6], f3.x); v[7] = fmaxf(v[7], f3.y);
    }
  }
  if (beg == end) {
#pragma unroll
    for (int p = 0; p < 8; p++) v[p] = 0.f;
  }
  *reinterpret_cast<uint4*>(xb + (size_t)node * (2 * CIN) + CIN + ll * 8) =
      make_uint4(f2h2(v[0], v[1]), f2h2(v[2], v[3]), f2h2(v[4], v[5]), f2h2(v[6], v[7]));
}

// ---------- cluster max-pool: wave per cluster, 512 f16 channels, x4 unroll ----------
__global__ __launch_bounds__(256) void k_pool(const ushort_t* __restrict__ x3, const int* __restrict__ rowptr,
                                              const int* __restrict__ col, float* __restrict__ pooled, int NC) {
  const int wid = (blockIdx.x * blockDim.x + threadIdx.x) >> 6;
  const int lane = threadIdx.x & 63;
  if (wid >= NC) return;
  const int beg = rowptr[wid], end = rowptr[wid + 1];
  float v[8];
#pragma unroll
  for (int p = 0; p < 8; p++) v[p] = -INFINITY;
  for (int e = beg; e < end; e += 4) {
    int idx[4];
#pragma unroll
    for (int u = 0; u < 4; u++) { int t = e + u; idx[u] = col[t < end ? t : e]; }
    uint4 r[4];
#pragma unroll
    for (int u = 0; u < 4; u++)
      r[u] = *reinterpret_cast<const uint4*>(x3 + (size_t)idx[u] * 512 + lane * 8);
#pragma unroll
    for (int u = 0; u < 4; u++) {
      float2 f0 = h2f2(r[u].x), f1 = h2f2(r[u].y), f2 = h2f2(r[u].z), f3 = h2f2(r[u].w);
      v[0] = fmaxf(v[0], f0.x); v[1] = fmaxf(v[1], f0.y);
      v[2] = fmaxf(v[2], f1.x); v[3] = fmaxf(v[3], f1.y);
      v[4] = fmaxf(v[4], f2.x); v[5] = fmaxf(v[5], f2.y);
      v[6] = fmaxf(v[6], f3.x); v[7] = fmaxf(v[7], f3.y);
    }
  }
  if (beg == end) {
#pragma unroll
    for (int p = 0; p < 8; p++) v[p] = 0.f;
  }
  float4* o = reinterpret_cast<float4*>(pooled + (size_t)wid * 512 + lane * 8);
  o[0] = make_float4(v[0], v[1], v[2], v[3]);
  o[1] = make_float4(v[4], v[5], v[6], v[7]);
}

// ---------- per-column sum of squares ----------
__global__ __launch_bounds__(256) void k_norm(const float* __restrict__ pooled, float* __restrict__ normsq, int NC) {
  const int c0 = threadIdx.x;
  const int c1 = threadIdx.x + 256;
  const int rows = (NC + gridDim.x - 1) / gridDim.x;
  float s0 = 0.f, s1 = 0.f;
  for (int rr = 0; rr < rows; rr++) {
    int r = blockIdx.x * rows + rr;
    if (r < NC) {
      float v0 = pooled[(size_t)r * 512 + c0];
      float v1 = pooled[(size_t)r * 512 + c1];
      s0 = fmaf(v0, v0, s0);
      s1 = fmaf(v1, v1, s1);
    }
  }
  atomicAdd(&normsq[c0], s0);
  atomicAdd(&normsq[c1], s1);
}

__global__ void k_final(const float* __restrict__ pooled, const float* __restrict__ normsq,
                        float* __restrict__ out, int n) {
  int i = blockIdx.x * blockDim.x + threadIdx.x;
  if (i >= n) return;
  int c = i & 511;
  out[i] = pooled[i] * rsqrtf(normsq[c]);
}

// ---------- launch ----------
extern "C" void kernel_launch(void* const* d_in, const int* in_sizes, int n_in,
                              void* d_out, int out_size, void* d_ws, size_t ws_size,
                              hipStream_t stream) {
  const int N = in_sizes[0] / 64;
  const int E = in_sizes[1] / 2;
  const int NC = out_size / 512;

  const float* x0 = (const float*)d_in[0];
  const int* ei = (const int*)d_in[1];
  const int* cluster = (const int*)d_in[2];

  const float* W[18];
  for (int k = 0; k < 18; k++) W[k] = (const float*)d_in[5 + k];

  // CSR counting-sort geometry
  constexpr int RSZ_E = 12544, NR_E = 4, NSL = 32;
  constexpr int RSZ_C = 5120, NR_C = 1;
  const int NB_E = RSZ_E * NR_E;          // 50176 padded node bins
  const int NB_C = RSZ_C * NR_C;          // 5120 padded cluster bins
  const int slenE = (E + NSL - 1) / NSL;
  const int slenC = (N + NSL - 1) / NSL;

  char* p = (char*)d_ws;
  auto alloc = [&](size_t bytes) -> void* {
    void* r = (void*)p;
    p += (bytes + 255) & ~(size_t)255;
    return r;
  };
  ushort_t* x1h = (ushort_t*)alloc((size_t)N * 128 * 2);
  ushort_t* x2h = (ushort_t*)alloc((size_t)N * 256 * 2);
  ushort_t* x3h = (ushort_t*)alloc((size_t)N * 512 * 2);
  float* pooled = (float*)alloc((size_t)NC * 512 * 4);
  float* normsq = (float*)alloc((size_t)512 * 4);
  int* degE     = (int*)alloc((size_t)NB_E * 4);
  int* rowptrE  = (int*)alloc((size_t)(NB_E + 1) * 4);
  int* colE     = (int*)alloc((size_t)E * 4);
  int* cntE     = (int*)alloc((size_t)NSL * NB_E * 4);
  int* degC     = (int*)alloc((size_t)NB_C * 4);
  int* rowptrC  = (int*)alloc((size_t)(NB_C + 1) * 4);
  int* colC     = (int*)alloc((size_t)N * 4);
  int* cntC     = (int*)alloc((size_t)NSL * NB_C * 4);
  int* blkE     = (int*)alloc(64 * 4);
  int* blkC     = (int*)alloc(64 * 4);
  // f16 hi/lo transposed weights per layer
  f16_t* wt[3][4];
  for (int L = 0; L < 3; L++) {
    int cin = 64 << L;
    for (int j = 0; j < 4; j++) wt[L][j] = (f16_t*)alloc((size_t)cin * 64 * 2);
  }

  hipMemsetAsync(normsq, 0, (size_t)512 * 4, stream);

  // weight prep
  k_prep<64><<<(2 * 64 * 64 + 255) / 256, 256, 0, stream>>>(W[0], W[4], wt[0][0], wt[0][1], wt[0][2], wt[0][3]);
  k_prep<128><<<(2 * 128 * 64 + 255) / 256, 256, 0, stream>>>(W[6], W[10], wt[1][0], wt[1][1], wt[1][2], wt[1][3]);
  k_prep<256><<<(2 * 256 * 64 + 255) / 256, 256, 0, stream>>>(W[12], W[16], wt[2][0], wt[2][1], wt[2][2], wt[2][3]);

  // ---- edge CSR (grouped by dst), atomic-free counting sort ----
  k_cnt<RSZ_E, NR_E><<<NSL * NR_E, 256, 0, stream>>>(ei + E, cntE, E, slenE);
  k_combine<<<(NB_E + 255) / 256, 256, 0, stream>>>(cntE, degE, NB_E, NSL);
  { int nbk = (NB_E + 1023) / 1024;
    k_scan1<<<nbk, 1024, 0, stream>>>(degE, rowptrE, blkE, NB_E);
    k_scan2<<<1, 64, 0, stream>>>(blkE, nbk);
    k_scan3<<<nbk, 1024, 0, stream>>>(rowptrE, blkE, NB_E); }
  k_scat<RSZ_E, NR_E, false><<<NSL * NR_E, 256, 0, stream>>>(ei + E, ei, rowptrE, cntE, colE, E, slenE);

  // ---- cluster CSR ----
  k_cnt<RSZ_C, NR_C><<<NSL * NR_C, 256, 0, stream>>>(cluster, cntC, N, slenC);
  k_combine<<<(NB_C + 255) / 256, 256, 0, stream>>>(cntC, degC, NB_C, NSL);
  { int nbk = (NB_C + 1023) / 1024;
    k_scan1<<<nbk, 1024, 0, stream>>>(degC, rowptrC, blkC, NB_C);
    k_scan2<<<1, 64, 0, stream>>>(blkC, nbk);
    k_scan3<<<nbk, 1024, 0, stream>>>(rowptrC, blkC, NB_C); }
  k_scat<RSZ_C, NR_C, true><<<NSL * NR_C, 256, 0, stream>>>(cluster, nullptr, rowptrC, cntC, colC, N, slenC);

  const int nblk = (N + 63) / 64;
  // layer 0: cin=64 (fp32 input, X split hi/lo); agg RPW=8
  k_mlp<64, float><<<nblk, 256, 0, stream>>>(x0, wt[0][0], wt[0][1], W[1], W[2], W[3],
                                             wt[0][2], wt[0][3], W[5], x1h, N);
  { int waves = (N + 7) / 8; k_agg<64, 4><<<(waves * 64 + 255) / 256, 256, 0, stream>>>(x1h, rowptrE, colE, N); }
  // layer 1: cin=128; agg RPW=4
  k_mlp<128, ushort_t><<<nblk, 256, 0, stream>>>(x1h, wt[1][0], wt[1][1], W[7], W[8], W[9],
                                                 wt[1][2], wt[1][3], W[11], x2h, N);
  { int waves = (N + 3) / 4; k_agg<128, 8><<<(waves * 64 + 255) / 256, 256, 0, stream>>>(x2h, rowptrE, colE, N); }
  // layer 2: cin=256; agg RPW=2
  k_mlp<256, ushort_t><<<nblk, 256, 0, stream>>>(x2h, wt[2][0], wt[2][1], W[13], W[14], W[15],
                                                 wt[2][2], wt[2][3], W[17], x3h, N);
  { int waves = (N + 1) / 2; k_agg<256, 8><<<(waves * 64 + 255) / 256, 256, 0, stream>>>(x3h, rowptrE, colE, N); }

  // cluster max-pool + column L2 normalize
  k_pool<<<(NC * 64 + 255) / 256, 256, 0, stream>>>(x3h, rowptrC, colC, pooled, NC);
  k_norm<<<128, 256, 0, stream>>>(pooled, normsq, NC);
  k_final<<<(NC * 512 + 255) / 256, 256, 0, stream>>>(pooled, normsq, (float*)d_out, NC * 512);
}

// Round 10
// 409.964 us; speedup vs baseline: 1.9413x; 1.0913x over previous
//
#include <hip/hip_runtime.h>
#include <hip/hip_fp16.h>

typedef unsigned short ushort_t;
typedef unsigned int uint_t;
typedef _Float16 f16_t;
typedef __attribute__((ext_vector_type(8))) _Float16 f16x8;
typedef __attribute__((ext_vector_type(4))) float f32x4;

__device__ __forceinline__ float2 h2f2(uint_t u) {
  __half2 h = *reinterpret_cast<__half2*>(&u);
  return __half22float2(h);
}
__device__ __forceinline__ uint_t f2h2(float a, float b) {
  __half2 h = __floats2half2_rn(a, b);
  return *reinterpret_cast<uint_t*>(&h);
}

// ---------- CSR construction (no global atomics: LDS-privatized counting sort) ----------
// Blocks = nslice x NR. Block (s,r) histograms keys of slice s falling in bin-range r.
// slen must be a multiple of 4 (16 B aligned int4 loads).
template <int RSIZE, int NR>
__global__ __launch_bounds__(256) void k_cnt(const int* __restrict__ key, int* __restrict__ cnt,
                                             int n, int slen) {
  __shared__ int h[RSIZE];
  const int s = blockIdx.x / NR, r = blockIdx.x % NR;
  const int base = r * RSIZE;
  for (int i = threadIdx.x; i < RSIZE; i += 256) h[i] = 0;
  __syncthreads();
  const int i0 = s * slen, i1 = min(n, i0 + slen);
  for (int i = i0 + threadIdx.x * 4; i < i1; i += 1024) {
    int4 k4;
    if (i + 3 < i1) {
      k4 = *reinterpret_cast<const int4*>(&key[i]);
    } else {
      k4.x = key[i];
      k4.y = (i + 1 < i1) ? key[i + 1] : -1;
      k4.z = (i + 2 < i1) ? key[i + 2] : -1;
      k4.w = (i + 3 < i1) ? key[i + 3] : -1;
    }
    int d;
    d = k4.x - base; if ((unsigned)d < (unsigned)RSIZE) atomicAdd(&h[d], 1);
    d = k4.y - base; if ((unsigned)d < (unsigned)RSIZE) atomicAdd(&h[d], 1);
    d = k4.z - base; if ((unsigned)d < (unsigned)RSIZE) atomicAdd(&h[d], 1);
    d = k4.w - base; if ((unsigned)d < (unsigned)RSIZE) atomicAdd(&h[d], 1);
  }
  __syncthreads();
  const int NB = RSIZE * NR;
  for (int i = threadIdx.x; i < RSIZE; i += 256) cnt[(size_t)s * NB + base + i] = h[i];
}

// per-bin exclusive scan over slices: cnt[s][d] -> #keys==d in slices<s; deg[d] = total
__global__ void k_combine(int* __restrict__ cnt, int* __restrict__ deg, int nb, int nslice) {
  int d = blockIdx.x * 256 + threadIdx.x;
  if (d >= nb) return;
  int acc = 0;
  for (int s = 0; s < nslice; s++) {
    int c = cnt[(size_t)s * nb + d];
    cnt[(size_t)s * nb + d] = acc;
    acc += c;
  }
  deg[d] = acc;
}

// hierarchical scan, pass 1
__global__ __launch_bounds__(1024) void k_scan1(const int* __restrict__ deg, int* __restrict__ rowptr,
                                                int* __restrict__ blksum, int n) {
  __shared__ int wtot[16];
  const int tid = threadIdx.x, lane = tid & 63, w = tid >> 6;
  const int i = blockIdx.x * 1024 + tid;
  int v = (i < n) ? deg[i] : 0;
  int incl = v;
#pragma unroll
  for (int off = 1; off < 64; off <<= 1) {
    int t = __shfl_up(incl, off, 64);
    if (lane >= off) incl += t;
  }
  if (lane == 63) wtot[w] = incl;
  __syncthreads();
  if (w == 0) {
    int tv = (lane < 16) ? wtot[lane] : 0;
#pragma unroll
    for (int off = 1; off < 16; off <<= 1) {
      int t = __shfl_up(tv, off, 64);
      if (lane >= off) tv += t;
    }
    if (lane < 16) wtot[lane] = tv;
  }
  __syncthreads();
  int out = (w ? wtot[w - 1] : 0) + incl;
  if (i < n) rowptr[i + 1] = out;
  if (tid == 1023) blksum[blockIdx.x] = out;
}

// pass 2: single wave exclusive-scans block sums in place (nb <= 64)
__global__ __launch_bounds__(64) void k_scan2(int* __restrict__ blksum, int nb) {
  const int lane = threadIdx.x;
  int v = (lane < nb) ? blksum[lane] : 0;
  int incl = v;
#pragma unroll
  for (int off = 1; off < 64; off <<= 1) {
    int t = __shfl_up(incl, off, 64);
    if (lane >= off) incl += t;
  }
  if (lane < nb) blksum[lane] = incl - v;
}

// pass 3: add block offsets; set element 0
__global__ __launch_bounds__(1024) void k_scan3(int* __restrict__ rowptr, const int* __restrict__ blkoff, int n) {
  const int i = blockIdx.x * 1024 + threadIdx.x;
  if (i == 0) rowptr[0] = 0;
  if (i < n) rowptr[i + 1] += blkoff[blockIdx.x];
}

// scatter pass: re-rank via fresh LDS histogram (rank order arbitrary — max is
// order-invariant), one plain store per key. int4 key/val loads (4 chains in flight).
template <int RSIZE, int NR, bool IDENT>
__global__ __launch_bounds__(256) void k_scat(const int* __restrict__ key, const int* __restrict__ val,
                                              const int* __restrict__ rowptr, const int* __restrict__ cnt,
                                              int* __restrict__ col, int n, int slen) {
  __shared__ int h[RSIZE];
  const int s = blockIdx.x / NR, r = blockIdx.x % NR;
  const int base = r * RSIZE;
  for (int i = threadIdx.x; i < RSIZE; i += 256) h[i] = 0;
  __syncthreads();
  const int NB = RSIZE * NR;
  const int i0 = s * slen, i1 = min(n, i0 + slen);
  for (int i = i0 + threadIdx.x * 4; i < i1; i += 1024) {
    int4 k4, v4;
    if (i + 3 < i1) {
      k4 = *reinterpret_cast<const int4*>(&key[i]);
      if (!IDENT) v4 = *reinterpret_cast<const int4*>(&val[i]);
    } else {
      k4.x = key[i];
      k4.y = (i + 1 < i1) ? key[i + 1] : -1;
      k4.z = (i + 2 < i1) ? key[i + 2] : -1;
      k4.w = (i + 3 < i1) ? key[i + 3] : -1;
      if (!IDENT) {
        v4.x = val[i];
        v4.y = (i + 1 < i1) ? val[i + 1] : 0;
        v4.z = (i + 2 < i1) ? val[i + 2] : 0;
        v4.w = (i + 3 < i1) ? val[i + 3] : 0;
      }
    }
    const int ks[4] = {k4.x, k4.y, k4.z, k4.w};
    const int vs[4] = {IDENT ? i : v4.x, IDENT ? i + 1 : v4.y, IDENT ? i + 2 : v4.z, IDENT ? i + 3 : v4.w};
#pragma unroll
    for (int u = 0; u < 4; u++) {
      int d = ks[u];
      int dr = d - base;
      if ((unsigned)dr < (unsigned)RSIZE) {
        int lr = atomicAdd(&h[dr], 1);
        int pos = rowptr[d] + cnt[(size_t)s * NB + d] + lr;
        col[pos] = vs[u];
      }
    }
  }
}

// ---------- weight prep: transpose + f16 hi/lo split ----------
template <int CIN>
__global__ void k_prep(const float* __restrict__ w1, const float* __restrict__ w2,
                       f16_t* __restrict__ w1t_hi, f16_t* __restrict__ w1t_lo,
                       f16_t* __restrict__ w2t_hi, f16_t* __restrict__ w2t_lo) {
  int i = blockIdx.x * blockDim.x + threadIdx.x;
  const int n1 = CIN * 64;
  if (i < n1) {
    int k = i >> 6, c = i & 63;
    float v = w1[i];
    f16_t hi = (f16_t)v;
    w1t_hi[(size_t)c * CIN + k] = hi;
    w1t_lo[(size_t)c * CIN + k] = (f16_t)(v - (float)hi);
  } else if (i < 2 * n1) {
    int i2 = i - n1;
    int c = i2 / CIN, j = i2 & (CIN - 1);
    float v = w2[i2];
    f16_t hi = (f16_t)v;
    w2t_hi[(size_t)j * 64 + c] = hi;
    w2t_lo[(size_t)j * 64 + c] = (f16_t)(v - (float)hi);
  }
}

// ---------- MFMA MLP v3: LDS-staged fragments ----------
template <int CIN, typename TIN>
__global__ __launch_bounds__(256) void k_mlp(const TIN* __restrict__ xin,
                                             const f16_t* __restrict__ w1t_hi, const f16_t* __restrict__ w1t_lo,
                                             const float* __restrict__ b1, const float* __restrict__ g,
                                             const float* __restrict__ be,
                                             const f16_t* __restrict__ w2t_hi, const f16_t* __restrict__ w2t_lo,
                                             const float* __restrict__ b2,
                                             ushort_t* __restrict__ xout, int N) {
  constexpr int KC = CIN / 64;
  __shared__ __align__(16) f16_t sB[2][4096];
  __shared__ __align__(16) f16_t sX[2][4096];
  __shared__ __align__(16) f16_t sH[2][4096];

  const int tid = threadIdx.x;
  const int wave = tid >> 6, lane = tid & 63;
  const int b = lane & 15, q = lane >> 4;
  const int nb = blockIdx.x * 64;
  const int nbW = nb + wave * 16;

  f32x4 acc1[4] = {};

  // ================= phase 1: H = X @ W1 =================
  for (int kc = 0; kc < KC; kc++) {
    __syncthreads();
#pragma unroll
    for (int half = 0; half < 2; half++) {
      int i = tid * 8 + half * 2048;
      int c = i >> 6, kk = i & 63;
      int t = c >> 4, bb = c & 15, kt = kk >> 5, qq = (kk >> 3) & 3;
      int dst = ((t * 2 + kt) * 64 + qq * 16 + bb) * 8;
      size_t src = (size_t)c * CIN + kc * 64 + kk;
      *reinterpret_cast<f16x8*>(&sB[0][dst]) = *reinterpret_cast<const f16x8*>(&w1t_hi[src]);
      *reinterpret_cast<f16x8*>(&sB[1][dst]) = *reinterpret_cast<const f16x8*>(&w1t_lo[src]);
    }
#pragma unroll
    for (int half = 0; half < 2; half++) {
      int i = tid * 8 + half * 2048;
      int n = i >> 6, kk = i & 63;
      int w = n >> 4, bb = n & 15, kt = kk >> 5, qq = (kk >> 3) & 3;
      int dst = ((w * 2 + kt) * 64 + qq * 16 + bb) * 8;
      int gn = nb + n;
      if (gn >= N) gn = N - 1;
      if constexpr (sizeof(TIN) == 4) {
        float f[8];
        *reinterpret_cast<float4*>(&f[0]) = *reinterpret_cast<const float4*>(&xin[(size_t)gn * CIN + kc * 64 + kk]);
        *reinterpret_cast<float4*>(&f[4]) = *reinterpret_cast<const float4*>(&xin[(size_t)gn * CIN + kc * 64 + kk + 4]);
        f16x8 vh, vl;
#pragma unroll
        for (int j = 0; j < 8; j++) {
          f16_t hi = (f16_t)f[j];
          vh[j] = hi;
          vl[j] = (f16_t)(f[j] - (float)hi);
        }
        *reinterpret_cast<f16x8*>(&sX[0][dst]) = vh;
        *reinterpret_cast<f16x8*>(&sX[1][dst]) = vl;
      } else {
        *reinterpret_cast<f16x8*>(&sX[0][dst]) =
            *reinterpret_cast<const f16x8*>(&xin[(size_t)gn * CIN + kc * 64 + kk]);
      }
    }
    __syncthreads();
#pragma unroll
    for (int kt = 0; kt < 2; kt++) {
      f16x8 a = *reinterpret_cast<const f16x8*>(&sX[0][((wave * 2 + kt) * 64 + lane) * 8]);
      f16x8 al;
      if constexpr (sizeof(TIN) == 4)
        al = *reinterpret_cast<const f16x8*>(&sX[1][((wave * 2 + kt) * 64 + lane) * 8]);
#pragma unroll
      for (int t = 0; t < 4; t++) {
        f16x8 bh = *reinterpret_cast<const f16x8*>(&sB[0][((t * 2 + kt) * 64 + lane) * 8]);
        f16x8 bl = *reinterpret_cast<const f16x8*>(&sB[1][((t * 2 + kt) * 64 + lane) * 8]);
        acc1[t] = __builtin_amdgcn_mfma_f32_16x16x32_f16(a, bh, acc1[t], 0, 0, 0);
        acc1[t] = __builtin_amdgcn_mfma_f32_16x16x32_f16(a, bl, acc1[t], 0, 0, 0);
        if constexpr (sizeof(TIN) == 4)
          acc1[t] = __builtin_amdgcn_mfma_f32_16x16x32_f16(al, bh, acc1[t], 0, 0, 0);
      }
    }
  }

  // ---- + b1, LayerNorm(64), *g + be, ReLU ----
  float b1v[4], gv[4], bev[4];
#pragma unroll
  for (int t = 0; t < 4; t++) {
    b1v[t] = b1[t * 16 + b];
    gv[t] = g[t * 16 + b];
    bev[t] = be[t * 16 + b];
  }
#pragma unroll
  for (int t = 0; t < 4; t++)
#pragma unroll
    for (int r = 0; r < 4; r++) acc1[t][r] += b1v[t];

  float mu[4], vv[4], rs[4];
#pragma unroll
  for (int r = 0; r < 4; r++) mu[r] = acc1[0][r] + acc1[1][r] + acc1[2][r] + acc1[3][r];
#pragma unroll
  for (int m = 1; m < 16; m <<= 1) {
#pragma unroll
    for (int r = 0; r < 4; r++) mu[r] += __shfl_xor(mu[r], m, 64);
  }
#pragma unroll
  for (int r = 0; r < 4; r++) mu[r] *= (1.f / 64.f);
#pragma unroll
  for (int r = 0; r < 4; r++) {
    float d0 = acc1[0][r] - mu[r], d1 = acc1[1][r] - mu[r];
    float d2 = acc1[2][r] - mu[r], d3 = acc1[3][r] - mu[r];
    vv[r] = d0 * d0 + d1 * d1 + d2 * d2 + d3 * d3;
  }
#pragma unroll
  for (int m = 1; m < 16; m <<= 1) {
#pragma unroll
    for (int r = 0; r < 4; r++) vv[r] += __shfl_xor(vv[r], m, 64);
  }
#pragma unroll
  for (int r = 0; r < 4; r++) rs[r] = rsqrtf(vv[r] * (1.f / 64.f) + 1e-5f);

  // ---- H -> per-wave LDS frags (hi/lo), A-layout; no barrier needed ----
#pragma unroll
  for (int t = 0; t < 4; t++) {
    const int kt = t >> 1;
    const int qq = (t & 1) * 2 + (b >> 3);
    const int jj = b & 7;
#pragma unroll
    for (int r = 0; r < 4; r++) {
      float h = (acc1[t][r] - mu[r]) * rs[r] * gv[t] + bev[t];
      h = fmaxf(h, 0.f);
      f16_t hh = (f16_t)h;
      int m = q * 4 + r;
      int dst = ((wave * 2 + kt) * 64 + qq * 16 + m) * 8 + jj;
      sH[0][dst] = hh;
      sH[1][dst] = (f16_t)(h - (float)hh);
    }
  }

  f16x8 ahi[2], alo[2];
#pragma unroll
  for (int kt = 0; kt < 2; kt++) {
    ahi[kt] = *reinterpret_cast<const f16x8*>(&sH[0][((wave * 2 + kt) * 64 + lane) * 8]);
    alo[kt] = *reinterpret_cast<const f16x8*>(&sH[1][((wave * 2 + kt) * 64 + lane) * 8]);
  }

  // ================= phase 2: OUT = H @ W2 + b2 =================
  for (int jc = 0; jc < KC; jc++) {
    __syncthreads();
#pragma unroll
    for (int half = 0; half < 2; half++) {
      int i = tid * 8 + half * 2048;
      int jjn = i >> 6, cc = i & 63;
      int t2 = jjn >> 4, bb = jjn & 15, kt = cc >> 5, qq = (cc >> 3) & 3;
      int dst = ((t2 * 2 + kt) * 64 + qq * 16 + bb) * 8;
      size_t src = (size_t)(jc * 64 + jjn) * 64 + cc;
      *reinterpret_cast<f16x8*>(&sB[0][dst]) = *reinterpret_cast<const f16x8*>(&w2t_hi[src]);
      *reinterpret_cast<f16x8*>(&sB[1][dst]) = *reinterpret_cast<const f16x8*>(&w2t_lo[src]);
    }
    __syncthreads();
#pragma unroll
    for (int t2 = 0; t2 < 4; t2++) {
      f32x4 acc = {};
#pragma unroll
      for (int kt = 0; kt < 2; kt++) {
        f16x8 bh = *reinterpret_cast<const f16x8*>(&sB[0][((t2 * 2 + kt) * 64 + lane) * 8]);
        f16x8 bl = *reinterpret_cast<const f16x8*>(&sB[1][((t2 * 2 + kt) * 64 + lane) * 8]);
        acc = __builtin_amdgcn_mfma_f32_16x16x32_f16(ahi[kt], bh, acc, 0, 0, 0);
        acc = __builtin_amdgcn_mfma_f32_16x16x32_f16(ahi[kt], bl, acc, 0, 0, 0);
        acc = __builtin_amdgcn_mfma_f32_16x16x32_f16(alo[kt], bh, acc, 0, 0, 0);
      }
      int col = jc * 64 + t2 * 16 + b;
      float b2v = b2[col];
#pragma unroll
      for (int r = 0; r < 4; r++) {
        int node = nbW + q * 4 + r;
        if (node < N) {
          __half hv = __float2half_rn(acc[r] + b2v);
          xout[(size_t)node * (2 * CIN) + col] = *reinterpret_cast<ushort_t*>(&hv);
        }
      }
    }
  }
}

// ---------- scatter-max as CSR gather-max (16 B/lane, UNR loads in flight/thread) ----------
template <int CIN, int UNR>
__global__ __launch_bounds__(256) void k_agg(ushort_t* __restrict__ xb, const int* __restrict__ rowptr,
                                             const int* __restrict__ col, int N) {
  constexpr int LPR = CIN / 8;
  constexpr int RPW = 64 / LPR;
  const int wid = (blockIdx.x * blockDim.x + threadIdx.x) >> 6;
  const int lane = threadIdx.x & 63;
  const int sub = lane / LPR;
  const int ll = lane % LPR;
  const int node = wid * RPW + sub;
  if (node >= N) return;
  const int beg = rowptr[node], end = rowptr[node + 1];
  float v[8];
#pragma unroll
  for (int p = 0; p < 8; p++) v[p] = -INFINITY;
  for (int e = beg; e < end; e += UNR) {
    int idx[UNR];
#pragma unroll
    for (int u = 0; u < UNR; u++) { int t = e + u; idx[u] = col[t < end ? t : e]; }
    uint4 r[UNR];
#pragma unroll
    for (int u = 0; u < UNR; u++)
      r[u] = *reinterpret_cast<const uint4*>(xb + (size_t)idx[u] * (2 * CIN) + ll * 8);
#pragma unroll
    for (int u = 0; u < UNR; u++) {
      float2 f0 = h2f2(r[u].x), f1 = h2f2(r[u].y), f2 = h2f2(r[u].z), f3 = h2f2(r[u].w);
      v[0] = fmaxf(v[0], f0.x); v[1] = fmaxf(v[1], f0.y);
      v[2] = fmaxf(v[2], f1.x); v[3] = fmaxf(v[3], f1.y);
      v[4] = fmaxf(v[4], f2.x); v[5] = fmaxf(v[5], f2.y);
      v[6] = fmaxf(v[6], f3.x); v[7] = fmaxf(v[7], f3.y);
    }
  }
  if (beg == end) {
#pragma unroll
    for (int p = 0; p < 8; p++) v[p] = 0.f;
  }
  *reinterpret_cast<uint4*>(xb + (size_t)node * (2 * CIN) + CIN + ll * 8) =
      make_uint4(f2h2(v[0], v[1]), f2h2(v[2], v[3]), f2h2(v[4], v[5]), f2h2(v[6], v[7]));
}

// ---------- cluster max-pool: wave per cluster, 512 f16 channels, x4 unroll ----------
__global__ __launch_bounds__(256) void k_pool(const ushort_t* __restrict__ x3, const int* __restrict__ rowptr,
                                              const int* __restrict__ col, float* __restrict__ pooled, int NC) {
  const int wid = (blockIdx.x * blockDim.x + threadIdx.x) >> 6;
  const int lane = threadIdx.x & 63;
  if (wid >= NC) return;
  const int beg = rowptr[wid], end = rowptr[wid + 1];
  float v[8];
#pragma unroll
  for (int p = 0; p < 8; p++) v[p] = -INFINITY;
  for (int e = beg; e < end; e += 4) {
    int idx[4];
#pragma unroll
    for (int u = 0; u < 4; u++) { int t = e + u; idx[u] = col[t < end ? t : e]; }
    uint4 r[4];
#pragma unroll
    for (int u = 0; u < 4; u++)
      r[u] = *reinterpret_cast<const uint4*>(x3 + (size_t)idx[u] * 512 + lane * 8);
#pragma unroll
    for (int u = 0; u < 4; u++) {
      float2 f0 = h2f2(r[u].x), f1 = h2f2(r[u].y), f2 = h2f2(r[u].z), f3 = h2f2(r[u].w);
      v[0] = fmaxf(v[0], f0.x); v[1] = fmaxf(v[1], f0.y);
      v[2] = fmaxf(v[2], f1.x); v[3] = fmaxf(v[3], f1.y);
      v[4] = fmaxf(v[4], f2.x); v[5] = fmaxf(v[5], f2.y);
      v[6] = fmaxf(v[6], f3.x); v[7] = fmaxf(v[7], f3.y);
    }
  }
  if (beg == end) {
#pragma unroll
    for (int p = 0; p < 8; p++) v[p] = 0.f;
  }
  float4* o = reinterpret_cast<float4*>(pooled + (size_t)wid * 512 + lane * 8);
  o[0] = make_float4(v[0], v[1], v[2], v[3]);
  o[1] = make_float4(v[4], v[5], v[6], v[7]);
}

// ---------- per-column sum of squares ----------
__global__ __launch_bounds__(256) void k_norm(const float* __restrict__ pooled, float* __restrict__ normsq, int NC) {
  const int c0 = threadIdx.x;
  const int c1 = threadIdx.x + 256;
  const int rows = (NC + gridDim.x - 1) / gridDim.x;
  float s0 = 0.f, s1 = 0.f;
  for (int rr = 0; rr < rows; rr++) {
    int r = blockIdx.x * rows + rr;
    if (r < NC) {
      float v0 = pooled[(size_t)r * 512 + c0];
      float v1 = pooled[(size_t)r * 512 + c1];
      s0 = fmaf(v0, v0, s0);
      s1 = fmaf(v1, v1, s1);
    }
  }
  atomicAdd(&normsq[c0], s0);
  atomicAdd(&normsq[c1], s1);
}

__global__ void k_final(const float* __restrict__ pooled, const float* __restrict__ normsq,
                        float* __restrict__ out, int n) {
  int i = blockIdx.x * blockDim.x + threadIdx.x;
  if (i >= n) return;
  int c = i & 511;
  out[i] = pooled[i] * rsqrtf(normsq[c]);
}

// ---------- launch ----------
extern "C" void kernel_launch(void* const* d_in, const int* in_sizes, int n_in,
                              void* d_out, int out_size, void* d_ws, size_t ws_size,
                              hipStream_t stream) {
  const int N = in_sizes[0] / 64;
  const int E = in_sizes[1] / 2;
  const int NC = out_size / 512;

  const float* x0 = (const float*)d_in[0];
  const int* ei = (const int*)d_in[1];
  const int* cluster = (const int*)d_in[2];

  const float* W[18];
  for (int k = 0; k < 18; k++) W[k] = (const float*)d_in[5 + k];

  // CSR counting-sort geometry
  constexpr int RSZ_E = 12544, NR_E = 4, NSL_E = 128;
  constexpr int RSZ_C = 5120, NR_C = 1, NSL_C = 32;
  const int NB_E = RSZ_E * NR_E;  // 50176 padded node bins
  const int NB_C = RSZ_C * NR_C;  // 5120 padded cluster bins
  const int slenE = (((E + NSL_E - 1) / NSL_E) + 3) & ~3;  // x4-aligned slices
  const int slenC = (((N + NSL_C - 1) / NSL_C) + 3) & ~3;

  char* p = (char*)d_ws;
  auto alloc = [&](size_t bytes) -> void* {
    void* r = (void*)p;
    p += (bytes + 255) & ~(size_t)255;
    return r;
  };
  ushort_t* x1h = (ushort_t*)alloc((size_t)N * 128 * 2);
  ushort_t* x2h = (ushort_t*)alloc((size_t)N * 256 * 2);
  ushort_t* x3h = (ushort_t*)alloc((size_t)N * 512 * 2);
  float* pooled = (float*)alloc((size_t)NC * 512 * 4);
  float* normsq = (float*)alloc((size_t)512 * 4);
  int* degE     = (int*)alloc((size_t)NB_E * 4);
  int* rowptrE  = (int*)alloc((size_t)(NB_E + 1) * 4);
  int* colE     = (int*)alloc((size_t)E * 4);
  int* cntE     = (int*)alloc((size_t)NSL_E * NB_E * 4);
  int* degC     = (int*)alloc((size_t)NB_C * 4);
  int* rowptrC  = (int*)alloc((size_t)(NB_C + 1) * 4);
  int* colC     = (int*)alloc((size_t)N * 4);
  int* cntC     = (int*)alloc((size_t)NSL_C * NB_C * 4);
  int* blkE     = (int*)alloc(64 * 4);
  int* blkC     = (int*)alloc(64 * 4);
  // f16 hi/lo transposed weights per layer
  f16_t* wt[3][4];
  for (int L = 0; L < 3; L++) {
    int cin = 64 << L;
    for (int j = 0; j < 4; j++) wt[L][j] = (f16_t*)alloc((size_t)cin * 64 * 2);
  }

  hipMemsetAsync(normsq, 0, (size_t)512 * 4, stream);

  // weight prep
  k_prep<64><<<(2 * 64 * 64 + 255) / 256, 256, 0, stream>>>(W[0], W[4], wt[0][0], wt[0][1], wt[0][2], wt[0][3]);
  k_prep<128><<<(2 * 128 * 64 + 255) / 256, 256, 0, stream>>>(W[6], W[10], wt[1][0], wt[1][1], wt[1][2], wt[1][3]);
  k_prep<256><<<(2 * 256 * 64 + 255) / 256, 256, 0, stream>>>(W[12], W[16], wt[2][0], wt[2][1], wt[2][2], wt[2][3]);

  // ---- edge CSR (grouped by dst), atomic-free counting sort ----
  k_cnt<RSZ_E, NR_E><<<NSL_E * NR_E, 256, 0, stream>>>(ei + E, cntE, E, slenE);
  k_combine<<<(NB_E + 255) / 256, 256, 0, stream>>>(cntE, degE, NB_E, NSL_E);
  { int nbk = (NB_E + 1023) / 1024;
    k_scan1<<<nbk, 1024, 0, stream>>>(degE, rowptrE, blkE, NB_E);
    k_scan2<<<1, 64, 0, stream>>>(blkE, nbk);
    k_scan3<<<nbk, 1024, 0, stream>>>(rowptrE, blkE, NB_E); }
  k_scat<RSZ_E, NR_E, false><<<NSL_E * NR_E, 256, 0, stream>>>(ei + E, ei, rowptrE, cntE, colE, E, slenE);

  // ---- cluster CSR ----
  k_cnt<RSZ_C, NR_C><<<NSL_C * NR_C, 256, 0, stream>>>(cluster, cntC, N, slenC);
  k_combine<<<(NB_C + 255) / 256, 256, 0, stream>>>(cntC, degC, NB_C, NSL_C);
  { int nbk = (NB_C + 1023) / 1024;
    k_scan1<<<nbk, 1024, 0, stream>>>(degC, rowptrC, blkC, NB_C);
    k_scan2<<<1, 64, 0, stream>>>(blkC, nbk);
    k_scan3<<<nbk, 1024, 0, stream>>>(rowptrC, blkC, NB_C); }
  k_scat<RSZ_C, NR_C, true><<<NSL_C * NR_C, 256, 0, stream>>>(cluster, nullptr, rowptrC, cntC, colC, N, slenC);

  const int nblk = (N + 63) / 64;
  // layer 0: cin=64 (fp32 input, X split hi/lo); agg RPW=8
  k_mlp<64, float><<<nblk, 256, 0, stream>>>(x0, wt[0][0], wt[0][1], W[1], W[2], W[3],
                                             wt[0][2], wt[0][3], W[5], x1h, N);
  { int waves = (N + 7) / 8; k_agg<64, 4><<<(waves * 64 + 255) / 256, 256, 0, stream>>>(x1h, rowptrE, colE, N); }
  // layer 1: cin=128; agg RPW=4
  k_mlp<128, ushort_t><<<nblk, 256, 0, stream>>>(x1h, wt[1][0], wt[1][1], W[7], W[8], W[9],
                                                 wt[1][2], wt[1][3], W[11], x2h, N);
  { int waves = (N + 3) / 4; k_agg<128, 8><<<(waves * 64 + 255) / 256, 256, 0, stream>>>(x2h, rowptrE, colE, N); }
  // layer 2: cin=256; agg RPW=2
  k_mlp<256, ushort_t><<<nblk, 256, 0, stream>>>(x2h, wt[2][0], wt[2][1], W[13], W[14], W[15],
                                                 wt[2][2], wt[2][3], W[17], x3h, N);
  { int waves = (N + 1) / 2; k_agg<256, 8><<<(waves * 64 + 255) / 256, 256, 0, stream>>>(x3h, rowptrE, colE, N); }

  // cluster max-pool + column L2 normalize
  k_pool<<<(NC * 64 + 255) / 256, 256, 0, stream>>>(x3h, rowptrC, colC, pooled, NC);
  k_norm<<<128, 256, 0, stream>>>(pooled, normsq, NC);
  k_final<<<(NC * 512 + 255) / 256, 256, 0, stream>>>(pooled, normsq, (float*)d_out, NC * 512);
}